// Round 8
// baseline (1008.513 us; speedup 1.0000x reference)
//
#include <hip/hip_runtime.h>

#define Nn 100000
#define Ee 600000
#define Hh 128
#define NP 100096  // padded node rows: multiple of 64
#define NT (NP / 64)  // 1564 tiles

typedef short bf16x8 __attribute__((ext_vector_type(8)));
typedef float f32x4 __attribute__((ext_vector_type(4)));
typedef unsigned short u16x8 __attribute__((ext_vector_type(8)));

static __device__ __forceinline__ float sigmoidf_(float x) {
  return 1.0f / (1.0f + __expf(-x));
}
static __device__ __forceinline__ float tanh_fast(float x) {
  return 1.0f - 2.0f / (__expf(2.0f * x) + 1.0f);
}
// round-to-nearest-even fp32 -> bf16 bits
static __device__ __forceinline__ ushort f2bf(float v) {
  unsigned u = __float_as_uint(v);
  unsigned r = (u + 0x7fffu + ((u >> 16) & 1u)) >> 16;
  return (ushort)r;
}
static __device__ __forceinline__ float bf2f(ushort b) {
  return __uint_as_float(((unsigned)b) << 16);
}
static __device__ __forceinline__ f32x4 max4(f32x4 a, f32x4 b) {
  f32x4 r;
  r[0] = fmaxf(a[0], b[0]);
  r[1] = fmaxf(a[1], b[1]);
  r[2] = fmaxf(a[2], b[2]);
  r[3] = fmaxf(a[3], b[3]);
  return r;
}
// LDS fragment layout (ushort idx): [kc:4][rf:4][g:4][c16:16][j:8]
// element (local row r, dim d): rf=r>>4, c16=r&15; kc=d>>5, g=(d>>3)&3, j=d&7

__global__ void zero_kernel(int* __restrict__ a, int* __restrict__ b, int n) {
  int i = blockIdx.x * 256 + threadIdx.x;
  if (i < n) { a[i] = 0; b[i] = 0; }
}

__global__ void count_kernel(const int* __restrict__ ei, int* __restrict__ degi,
                             int* __restrict__ cnt) {
  int e = blockIdx.x * 256 + threadIdx.x;
  if (e >= Ee) return;
  int r = ei[e], c = ei[Ee + e];
  atomicAdd(&degi[r], 1);
  atomicAdd(&degi[c], 1);
  atomicAdd(&cnt[c], 1);
}

__global__ void dis_kernel(const int* __restrict__ degi, float* __restrict__ dis) {
  int i = blockIdx.x * 256 + threadIdx.x;
  if (i < Nn) dis[i] = rsqrtf((float)degi[i] + 1.0f);
}

__global__ void scan_partial(const int* __restrict__ cnt, int* __restrict__ bsum) {
  __shared__ int s[256];
  int i = blockIdx.x * 256 + threadIdx.x;
  s[threadIdx.x] = (i < Nn) ? cnt[i] : 0;
  __syncthreads();
  for (int off = 128; off > 0; off >>= 1) {
    if (threadIdx.x < off) s[threadIdx.x] += s[threadIdx.x + off];
    __syncthreads();
  }
  if (threadIdx.x == 0) bsum[blockIdx.x] = s[0];
}

__global__ void scan_bsums(const int* __restrict__ bsum, int* __restrict__ bpre, int nb) {
  __shared__ int s[512];
  int t = threadIdx.x;
  s[t] = (t < nb) ? bsum[t] : 0;
  __syncthreads();
  for (int off = 1; off < 512; off <<= 1) {
    int u = (t >= off) ? s[t - off] : 0;
    __syncthreads();
    s[t] += u;
    __syncthreads();
  }
  if (t < nb) bpre[t] = (t == 0) ? 0 : s[t - 1];
}

__global__ void scan_final(const int* __restrict__ cnt, const int* __restrict__ bpre,
                           int* __restrict__ rowptr, int* __restrict__ cursor) {
  __shared__ int s[256];
  int t = threadIdx.x;
  int i = blockIdx.x * 256 + t;
  int v = (i < Nn) ? cnt[i] : 0;
  s[t] = v;
  __syncthreads();
  for (int off = 1; off < 256; off <<= 1) {
    int u = (t >= off) ? s[t - off] : 0;
    __syncthreads();
    s[t] += u;
    __syncthreads();
  }
  int excl = s[t] - v;
  int base = bpre[blockIdx.x];
  if (i < Nn) { rowptr[i] = base + excl; cursor[i] = base + excl; }
  if (i == Nn - 1) rowptr[Nn] = base + excl + v;
}

__global__ void fill_kernel(const int* __restrict__ ei, const float* __restrict__ dis,
                            int* __restrict__ cursor, int* __restrict__ csr_src,
                            float* __restrict__ csr_w) {
  int e = blockIdx.x * 256 + threadIdx.x;
  if (e >= Ee) return;
  int r = ei[e], c = ei[Ee + e];
  int p = atomicAdd(&cursor[c], 1);
  csr_src[p] = r;
  csr_w[p] = dis[r] * dis[c];
}

// Pack GRU weights into fragment-major split-bf16:
// B[kc:8][fid:24][g][c16][j], fid = gate*8+f; k = kc*32+g*8+j, col c=(fid&7)*16+c16,
// weight row = gate*128 + c. kc<4 -> Wih, kc>=4 -> Whh.
__global__ void pack_kernel(const float* __restrict__ Wih, const float* __restrict__ Whh,
                            ushort* __restrict__ Bhi, ushort* __restrict__ Blo) {
  int t = blockIdx.x * 256 + threadIdx.x;  // 8*24*4*16 = 12288 threads
  if (t >= 8 * 24 * 4 * 16) return;
  int c16 = t & 15;
  int g = (t >> 4) & 3;
  int fid = (t >> 6) % 24;
  int kc = t / (24 * 64);
  int gate = fid >> 3, f = fid & 7;
  int c = f * 16 + c16;
  int wrow = gate * 128 + c;
  size_t base = (size_t)t * 8;
#pragma unroll
  for (int j = 0; j < 8; ++j) {
    int k = kc * 32 + g * 8 + j;
    float v = (k < 128) ? Wih[wrow * 128 + k] : Whh[wrow * 128 + (k - 128)];
    ushort hi = f2bf(v);
    Bhi[base + j] = hi;
    Blo[base + j] = f2bf(v - bf2f(hi));
  }
}

// Pack MLP W1 (64 x 128): Bm[kc][cf][g][c16][j], c = cf*16+c16, k = kc*32+g*8+j
__global__ void pack_mlp(const float* __restrict__ Wm1, ushort* __restrict__ Bh,
                         ushort* __restrict__ Bl) {
  int t = blockIdx.x * 256 + threadIdx.x;  // 4*4*4*16 = 1024
  if (t >= 1024) return;
  int c16 = t & 15;
  int g = (t >> 4) & 3;
  int cf = (t >> 6) & 3;
  int kc = t >> 8;
  int c = cf * 16 + c16;
  size_t base = (size_t)t * 8;
#pragma unroll
  for (int j = 0; j < 8; ++j) {
    int k = kc * 32 + g * 8 + j;
    float v = Wm1[c * 128 + k];
    ushort hi = f2bf(v);
    Bh[base + j] = hi;
    Bl[base + j] = f2bf(v - bf2f(hi));
  }
}

// h0: leaky_relu(X @ W0^T + b0), row-major fp32.
__global__ void h0_kernel(const float* __restrict__ X, const float* __restrict__ W0,
                          const float* __restrict__ b0, float* __restrict__ H0) {
  int t = blockIdx.x * 256 + threadIdx.x;
  int i = t >> 7, d = t & 127;
  if (i >= NP) return;
  float v = 0.0f;
  if (i < Nn) {
    float x0 = X[i * 3 + 0], x1 = X[i * 3 + 1], x2 = X[i * 3 + 2];
    v = fmaf(x0, W0[d * 3 + 0], fmaf(x1, W0[d * 3 + 1], fmaf(x2, W0[d * 3 + 2], b0[d])));
    v = v > 0.0f ? v : 0.01f * v;
  }
  H0[(size_t)i * Hh + d] = v;
}

// ---- Fused GCN-aggregate + GRU cell (row-major fp32 state) ----
// Block = 64 nodes (one tile), 256 threads = 4 waves. LDS ~33KB (time-shared).
// P0: issue own-row loads (prefetch, consumed in P3).
// P1: gather (4 thr/node x 32 contiguous dims, edge-unroll-2) -> split-bf16 S.
// P2: MFMA kc0..3 from S (aggregate half).  sync
// P3: own rows (from prefetch regs) -> S.   sync
// P4: MFMA kc4..7 from S; compute hnew in regs (hold from S). sync
// P5: scatter hnew fp32 -> S ([64][132]).   sync
// P6: coalesced row-major copy S -> Hn (full-line writes).

#define DO_GATE(GB, ACC)                                                              \
  {                                                                                   \
    bf16x8 bH[2], bL[2];                                                              \
    _Pragma("unroll") for (int cf = 0; cf < 2; ++cf) {                                \
      size_t boff = (((size_t)(kc * 24 + (GB)*8 + wave * 2 + cf) * 4 + g) * 16 + c16) * 8; \
      bH[cf] = *(const bf16x8*)(Bhi + boff);                                          \
      bL[cf] = *(const bf16x8*)(Blo + boff);                                          \
    }                                                                                 \
    _Pragma("unroll") for (int cf = 0; cf < 2; ++cf)                                  \
        _Pragma("unroll") for (int rf = 0; rf < 4; ++rf)                              \
            ACC[rf][cf] = __builtin_amdgcn_mfma_f32_16x16x32_bf16(aH[rf], bH[cf], ACC[rf][cf], 0, 0, 0); \
    _Pragma("unroll") for (int cf = 0; cf < 2; ++cf)                                  \
        _Pragma("unroll") for (int rf = 0; rf < 4; ++rf)                              \
            ACC[rf][cf] = __builtin_amdgcn_mfma_f32_16x16x32_bf16(aH[rf], bL[cf], ACC[rf][cf], 0, 0, 0); \
    _Pragma("unroll") for (int cf = 0; cf < 2; ++cf)                                  \
        _Pragma("unroll") for (int rf = 0; rf < 4; ++rf)                              \
            ACC[rf][cf] = __builtin_amdgcn_mfma_f32_16x16x32_bf16(aL[rf], bH[cf], ACC[rf][cf], 0, 0, 0); \
  }

__global__ __launch_bounds__(256, 3) void gcn_gru_fused(
    const float* __restrict__ Hp, float* __restrict__ Hn,
    const int* __restrict__ csr_src, const float* __restrict__ csr_w,
    const int* __restrict__ rowptr,
    const ushort* __restrict__ Bhi, const ushort* __restrict__ Blo,
    const float* __restrict__ bih, const float* __restrict__ bhh) {
  __shared__ ushort S[16896];  // 33 KB: SH=S[0..8191], SL=S[8192..16383]; fp32 view [64][132]
  ushort* SH = S;
  ushort* SL = S + 8192;
  float* SF = (float*)S;
  const int tid = threadIdx.x;
  const int tile = blockIdx.x;
  const long rowbase = (long)tile * 64;

  const int local = tid >> 2;   // 0..63
  const int kc4 = tid & 3;      // dim block: d = kc4*32 + 0..31
  const int rf0 = local >> 4, c16l = local & 15;
  const int lwr = kc4 * 2048 + rf0 * 512 + c16l * 8;

  // ---- Phase 0: issue own-row prefetch ----
  f32x4 own[8];
  {
    const float* prow = Hp + (size_t)(rowbase + local) * Hh + kc4 * 32;
#pragma unroll
    for (int q = 0; q < 8; ++q) own[q] = *(const f32x4*)(prow + q * 4);
  }

  // ---- Phase 1: gather (aggregate) ----
  {
    const long node = rowbase + local;
    float acc[32];
#pragma unroll
    for (int m = 0; m < 32; ++m) acc[m] = 0.0f;
    if (node < Nn) {
      const int e0 = rowptr[node], e1 = rowptr[node + 1];
      const float* hb = Hp + kc4 * 32;
      int e = e0;
      for (; e + 1 < e1; e += 2) {
        const int s0 = csr_src[e], s1 = csr_src[e + 1];
        const float w0 = csr_w[e], w1 = csr_w[e + 1];
        const float* p0 = hb + (size_t)s0 * Hh;
        const float* p1 = hb + (size_t)s1 * Hh;
        f32x4 va[8], vb[8];
#pragma unroll
        for (int q = 0; q < 8; ++q) va[q] = *(const f32x4*)(p0 + q * 4);
#pragma unroll
        for (int q = 0; q < 8; ++q) vb[q] = *(const f32x4*)(p1 + q * 4);
#pragma unroll
        for (int q = 0; q < 8; ++q)
#pragma unroll
          for (int m = 0; m < 4; ++m)
            acc[q * 4 + m] = fmaf(w1, vb[q][m], fmaf(w0, va[q][m], acc[q * 4 + m]));
      }
      if (e < e1) {
        const int s0 = csr_src[e];
        const float w0 = csr_w[e];
        const float* p0 = hb + (size_t)s0 * Hh;
        f32x4 va[8];
#pragma unroll
        for (int q = 0; q < 8; ++q) va[q] = *(const f32x4*)(p0 + q * 4);
#pragma unroll
        for (int q = 0; q < 8; ++q)
#pragma unroll
          for (int m = 0; m < 4; ++m)
            acc[q * 4 + m] = fmaf(w0, va[q][m], acc[q * 4 + m]);
      }
    }
#pragma unroll
    for (int g2 = 0; g2 < 4; ++g2) {
      u16x8 vh, vl;
#pragma unroll
      for (int j = 0; j < 8; ++j) {
        float v = acc[g2 * 8 + j];
        ushort hb2 = f2bf(v);
        vh[j] = hb2;
        vl[j] = f2bf(v - bf2f(hb2));
      }
      *(u16x8*)(SH + lwr + g2 * 128) = vh;
      *(u16x8*)(SL + lwr + g2 * 128) = vl;
    }
  }
  __syncthreads();

  // ---- Phase 2: MFMA kc0..3 (aggregate half) ----
  const int wave = tid >> 6, lane = tid & 63;
  const int g = lane >> 4, c16 = lane & 15;
  const int lbase = g * 128 + c16 * 8;

  f32x4 accR[4][2], accZ[4][2], accXN[4][2], accHN[4][2];
#pragma unroll
  for (int rf = 0; rf < 4; ++rf)
#pragma unroll
    for (int cf = 0; cf < 2; ++cf) {
      accR[rf][cf] = (f32x4){0.f, 0.f, 0.f, 0.f};
      accZ[rf][cf] = (f32x4){0.f, 0.f, 0.f, 0.f};
      accXN[rf][cf] = (f32x4){0.f, 0.f, 0.f, 0.f};
      accHN[rf][cf] = (f32x4){0.f, 0.f, 0.f, 0.f};
    }

#pragma unroll
  for (int kc = 0; kc < 4; ++kc) {
    bf16x8 aH[4], aL[4];
#pragma unroll
    for (int rf = 0; rf < 4; ++rf) {
      int off = kc * 2048 + rf * 512 + lbase;
      aH[rf] = *(const bf16x8*)(SH + off);
      aL[rf] = *(const bf16x8*)(SL + off);
    }
    DO_GATE(0, accR)
    DO_GATE(1, accZ)
    DO_GATE(2, accXN)
  }
  __syncthreads();

  // ---- Phase 3: own rows (prefetched) -> LDS ----
  {
#pragma unroll
    for (int g2 = 0; g2 < 4; ++g2) {
      u16x8 vh, vl;
#pragma unroll
      for (int m = 0; m < 4; ++m) {
        float v0 = own[g2 * 2][m], v1 = own[g2 * 2 + 1][m];
        ushort hb0 = f2bf(v0);
        vh[m] = hb0;
        vl[m] = f2bf(v0 - bf2f(hb0));
        ushort hb1 = f2bf(v1);
        vh[4 + m] = hb1;
        vl[4 + m] = f2bf(v1 - bf2f(hb1));
      }
      *(u16x8*)(SH + lwr + g2 * 128) = vh;
      *(u16x8*)(SL + lwr + g2 * 128) = vl;
    }
  }
  __syncthreads();

  // ---- Phase 4: MFMA kc4..7 (h half) + compute hnew ----
#pragma unroll
  for (int kc = 4; kc < 8; ++kc) {
    bf16x8 aH[4], aL[4];
#pragma unroll
    for (int rf = 0; rf < 4; ++rf) {
      int off = (kc - 4) * 2048 + rf * 512 + lbase;
      aH[rf] = *(const bf16x8*)(SH + off);
      aL[rf] = *(const bf16x8*)(SL + off);
    }
    DO_GATE(0, accR)
    DO_GATE(1, accZ)
    DO_GATE(2, accHN)
  }

  float hnew[2][4][4];
#pragma unroll
  for (int cf = 0; cf < 2; ++cf) {
    const int c = (wave * 2 + cf) * 16 + c16;
    const float br = bih[c] + bhh[c];
    const float bz = bih[128 + c] + bhh[128 + c];
    const float bxn = bih[256 + c];
    const float bhn = bhh[256 + c];
    const int hcol = (cf * 2 + (c16 >> 3)) * 128 + (c16 & 7);
#pragma unroll
    for (int rf = 0; rf < 4; ++rf) {
#pragma unroll
      for (int reg = 0; reg < 4; ++reg) {
        const int lr = g * 4 + reg;  // local row within 16-block
        const int hoff = wave * 2048 + rf * 512 + hcol + lr * 8;
        float hold = bf2f(SH[hoff]) + bf2f(SL[hoff]);
        float rr = sigmoidf_(accR[rf][cf][reg] + br);
        float zz = sigmoidf_(accZ[rf][cf][reg] + bz);
        float nn = tanh_fast(accXN[rf][cf][reg] + bxn + rr * (accHN[rf][cf][reg] + bhn));
        hnew[cf][rf][reg] = (1.0f - zz) * nn + zz * hold;
      }
    }
  }
  __syncthreads();

  // ---- Phase 5: scatter hnew fp32 into S as [64][132] ----
#pragma unroll
  for (int cf = 0; cf < 2; ++cf) {
    const int c = (wave * 2 + cf) * 16 + c16;
#pragma unroll
    for (int rf = 0; rf < 4; ++rf)
#pragma unroll
      for (int reg = 0; reg < 4; ++reg)
        SF[(rf * 16 + g * 4 + reg) * 132 + c] = hnew[cf][rf][reg];
  }
  __syncthreads();

  // ---- Phase 6: coalesced copy S -> Hn ----
  {
    const float* srcp = SF + local * 132 + kc4 * 32;
    float* dstp = Hn + (size_t)(rowbase + local) * Hh + kc4 * 32;
#pragma unroll
    for (int q = 0; q < 8; ++q) *(f32x4*)(dstp + q * 4) = *(const f32x4*)(srcp + q * 4);
  }
}

// ---- Fused max(h1..h5) + MLP ----
// Block = 64 nodes, 4 waves; wave w owns cols [16w, 16w+16) of hid (64 cols).
__global__ __launch_bounds__(256, 2) void mlp_max_mfma(
    const float* __restrict__ H1, const float* __restrict__ H2,
    const float* __restrict__ H3, const float* __restrict__ H4,
    const float* __restrict__ H5,
    const ushort* __restrict__ Bh, const ushort* __restrict__ Bl,
    const float* __restrict__ bm1, const float* __restrict__ Wm2,
    const float* __restrict__ bm2, float* __restrict__ out) {
  __shared__ float red[4][64];
  const int tid = threadIdx.x;
  const int wave = tid >> 6, lane = tid & 63;
  const int g = lane >> 4, c16 = lane & 15;
  const long rowbase = (long)blockIdx.x * 64;

  f32x4 acc[4];
#pragma unroll
  for (int rf = 0; rf < 4; ++rf) acc[rf] = (f32x4){0.f, 0.f, 0.f, 0.f};

#pragma unroll
  for (int kc = 0; kc < 4; ++kc) {
    bf16x8 aH[4], aL[4];
#pragma unroll
    for (int rf = 0; rf < 4; ++rf) {
      size_t o = (size_t)(rowbase + rf * 16 + c16) * Hh + kc * 32 + g * 8;
      f32x4 m0 = *(const f32x4*)(H1 + o);
      f32x4 m1 = *(const f32x4*)(H1 + o + 4);
      m0 = max4(m0, *(const f32x4*)(H2 + o));
      m1 = max4(m1, *(const f32x4*)(H2 + o + 4));
      m0 = max4(m0, *(const f32x4*)(H3 + o));
      m1 = max4(m1, *(const f32x4*)(H3 + o + 4));
      m0 = max4(m0, *(const f32x4*)(H4 + o));
      m1 = max4(m1, *(const f32x4*)(H4 + o + 4));
      m0 = max4(m0, *(const f32x4*)(H5 + o));
      m1 = max4(m1, *(const f32x4*)(H5 + o + 4));
      u16x8 vh, vl;
#pragma unroll
      for (int m = 0; m < 4; ++m) {
        ushort hb0 = f2bf(m0[m]);
        vh[m] = hb0;
        vl[m] = f2bf(m0[m] - bf2f(hb0));
        ushort hb1 = f2bf(m1[m]);
        vh[4 + m] = hb1;
        vl[4 + m] = f2bf(m1[m] - bf2f(hb1));
      }
      aH[rf] = (bf16x8)vh;
      aL[rf] = (bf16x8)vl;
    }
    size_t boff = (((size_t)(kc * 4 + wave) * 4 + g) * 16 + c16) * 8;
    bf16x8 bH = *(const bf16x8*)(Bh + boff);
    bf16x8 bL = *(const bf16x8*)(Bl + boff);
#pragma unroll
    for (int rf = 0; rf < 4; ++rf)
      acc[rf] = __builtin_amdgcn_mfma_f32_16x16x32_bf16(aH[rf], bH, acc[rf], 0, 0, 0);
#pragma unroll
    for (int rf = 0; rf < 4; ++rf)
      acc[rf] = __builtin_amdgcn_mfma_f32_16x16x32_bf16(aH[rf], bL, acc[rf], 0, 0, 0);
#pragma unroll
    for (int rf = 0; rf < 4; ++rf)
      acc[rf] = __builtin_amdgcn_mfma_f32_16x16x32_bf16(aL[rf], bH, acc[rf], 0, 0, 0);
  }

  const int c = wave * 16 + c16;
  const float b1 = bm1[c];
  const float w2 = Wm2[c];
#pragma unroll
  for (int rf = 0; rf < 4; ++rf) {
#pragma unroll
    for (int reg = 0; reg < 4; ++reg) {
      float v = acc[rf][reg] + b1;
      v = v > 0.f ? v : 0.01f * v;
      v *= w2;
#pragma unroll
      for (int off = 1; off < 16; off <<= 1) v += __shfl_xor(v, off);
      if (c16 == 0) red[wave][rf * 16 + g * 4 + reg] = v;
    }
  }
  __syncthreads();
  if (tid < 64) {
    long row = rowbase + tid;
    if (row < Nn)
      out[row] = red[0][tid] + red[1][tid] + red[2][tid] + red[3][tid] + bm2[0];
  }
}

extern "C" void kernel_launch(void* const* d_in, const int* in_sizes, int n_in,
                              void* d_out, int out_size, void* d_ws, size_t ws_size,
                              hipStream_t stream) {
  const float* X = (const float*)d_in[0];
  const int* ei = (const int*)d_in[1];
  const float* W0 = (const float*)d_in[2];
  const float* b0 = (const float*)d_in[3];
  const float* Wih = (const float*)d_in[4];
  const float* Whh = (const float*)d_in[5];
  const float* bih = (const float*)d_in[6];
  const float* bhh = (const float*)d_in[7];
  const float* Wm1 = (const float*)d_in[8];
  const float* bm1 = (const float*)d_in[9];
  const float* Wm2 = (const float*)d_in[10];
  const float* bm2 = (const float*)d_in[11];
  float* out = (float*)d_out;

  char* ws = (char*)d_ws;
  size_t off = 0;
  auto alloc = [&](size_t bytes) -> void* {
    void* p = ws + off;
    off = (off + bytes + 255) & ~(size_t)255;
    return p;
  };
  float* Hs[5];
  for (int i = 0; i < 5; ++i) Hs[i] = (float*)alloc((size_t)NP * Hh * 4);
  ushort* Bhi = (ushort*)alloc((size_t)8 * 24 * 4 * 16 * 8 * 2);
  ushort* Blo = (ushort*)alloc((size_t)8 * 24 * 4 * 16 * 8 * 2);
  ushort* Bmh = (ushort*)alloc((size_t)1024 * 8 * 2);
  ushort* Bml = (ushort*)alloc((size_t)1024 * 8 * 2);
  float* dis = (float*)alloc((size_t)Nn * 4);
  int* degi = (int*)alloc((size_t)Nn * 4);
  int* cnt = (int*)alloc((size_t)Nn * 4);
  int* rowptr = (int*)alloc((size_t)(Nn + 1) * 4);
  int* cursor = (int*)alloc((size_t)Nn * 4);
  int* bsum = (int*)alloc(512 * 4);
  int* bpre = (int*)alloc(512 * 4);
  int* csr_src = (int*)alloc((size_t)Ee * 4);
  float* csr_w = (float*)alloc((size_t)Ee * 4);
  (void)ws_size;
  (void)in_sizes;
  (void)n_in;
  (void)out_size;

  const int NB = (Nn + 255) / 256;  // 391
  const int EB = (Ee + 255) / 256;  // 2344

  zero_kernel<<<NB, 256, 0, stream>>>(degi, cnt, Nn);
  count_kernel<<<EB, 256, 0, stream>>>(ei, degi, cnt);
  dis_kernel<<<NB, 256, 0, stream>>>(degi, dis);
  scan_partial<<<NB, 256, 0, stream>>>(cnt, bsum);
  scan_bsums<<<1, 512, 0, stream>>>(bsum, bpre, NB);
  scan_final<<<NB, 256, 0, stream>>>(cnt, bpre, rowptr, cursor);
  fill_kernel<<<EB, 256, 0, stream>>>(ei, dis, cursor, csr_src, csr_w);
  pack_kernel<<<48, 256, 0, stream>>>(Wih, Whh, Bhi, Blo);
  pack_mlp<<<4, 256, 0, stream>>>(Wm1, Bmh, Bml);
  h0_kernel<<<(NP * Hh) / 256, 256, 0, stream>>>(X, W0, b0, Hs[0]);

  // iteration t: read Hs[(t-1)%5], write Hs[t%5]  (t=5 reuses slot 0; h0 is dead by then)
  for (int t = 1; t <= 5; ++t) {
    gcn_gru_fused<<<NT, 256, 0, stream>>>(Hs[(t - 1) % 5], Hs[t % 5], csr_src, csr_w,
                                          rowptr, Bhi, Blo, bih, bhh);
  }

  mlp_max_mfma<<<NT, 256, 0, stream>>>(Hs[1], Hs[2], Hs[3], Hs[4], Hs[0], Bmh, Bml,
                                       bm1, Wm2, bm2, out);
}

// Round 9
// 962.478 us; speedup vs baseline: 1.0478x; 1.0478x over previous
//
#include <hip/hip_runtime.h>

#define Nn 100000
#define Ee 600000
#define Hh 128
#define NP 100096  // padded node rows: multiple of 64
#define NT (NP / 64)  // 1564 tiles

typedef short bf16x8 __attribute__((ext_vector_type(8)));
typedef float f32x4 __attribute__((ext_vector_type(4)));
typedef unsigned short u16x8 __attribute__((ext_vector_type(8)));

static __device__ __forceinline__ float sigmoidf_(float x) {
  return 1.0f / (1.0f + __expf(-x));
}
static __device__ __forceinline__ float tanh_fast(float x) {
  return 1.0f - 2.0f / (__expf(2.0f * x) + 1.0f);
}
// round-to-nearest-even fp32 -> bf16 bits
static __device__ __forceinline__ ushort f2bf(float v) {
  unsigned u = __float_as_uint(v);
  unsigned r = (u + 0x7fffu + ((u >> 16) & 1u)) >> 16;
  return (ushort)r;
}
static __device__ __forceinline__ float bf2f(ushort b) {
  return __uint_as_float(((unsigned)b) << 16);
}
static __device__ __forceinline__ f32x4 max4(f32x4 a, f32x4 b) {
  f32x4 r;
  r[0] = fmaxf(a[0], b[0]);
  r[1] = fmaxf(a[1], b[1]);
  r[2] = fmaxf(a[2], b[2]);
  r[3] = fmaxf(a[3], b[3]);
  return r;
}
// LDS fragment layout (ushort idx): [kc:4][rf:4][g:4][c16:16][j:8]
// element (local row r, dim d): rf=r>>4, c16=r&15; kc=d>>5, g=(d>>3)&3, j=d&7

__global__ void zero_kernel(int* __restrict__ a, int* __restrict__ b, int n) {
  int i = blockIdx.x * 256 + threadIdx.x;
  if (i < n) { a[i] = 0; b[i] = 0; }
}

__global__ void count_kernel(const int* __restrict__ ei, int* __restrict__ degi,
                             int* __restrict__ cnt) {
  int e = blockIdx.x * 256 + threadIdx.x;
  if (e >= Ee) return;
  int r = ei[e], c = ei[Ee + e];
  atomicAdd(&degi[r], 1);
  atomicAdd(&degi[c], 1);
  atomicAdd(&cnt[c], 1);
}

__global__ void dis_kernel(const int* __restrict__ degi, float* __restrict__ dis) {
  int i = blockIdx.x * 256 + threadIdx.x;
  if (i < Nn) dis[i] = rsqrtf((float)degi[i] + 1.0f);
}

__global__ void scan_partial(const int* __restrict__ cnt, int* __restrict__ bsum) {
  __shared__ int s[256];
  int i = blockIdx.x * 256 + threadIdx.x;
  s[threadIdx.x] = (i < Nn) ? cnt[i] : 0;
  __syncthreads();
  for (int off = 128; off > 0; off >>= 1) {
    if (threadIdx.x < off) s[threadIdx.x] += s[threadIdx.x + off];
    __syncthreads();
  }
  if (threadIdx.x == 0) bsum[blockIdx.x] = s[0];
}

__global__ void scan_bsums(const int* __restrict__ bsum, int* __restrict__ bpre, int nb) {
  __shared__ int s[512];
  int t = threadIdx.x;
  s[t] = (t < nb) ? bsum[t] : 0;
  __syncthreads();
  for (int off = 1; off < 512; off <<= 1) {
    int u = (t >= off) ? s[t - off] : 0;
    __syncthreads();
    s[t] += u;
    __syncthreads();
  }
  if (t < nb) bpre[t] = (t == 0) ? 0 : s[t - 1];
}

__global__ void scan_final(const int* __restrict__ cnt, const int* __restrict__ bpre,
                           int* __restrict__ rowptr, int* __restrict__ cursor) {
  __shared__ int s[256];
  int t = threadIdx.x;
  int i = blockIdx.x * 256 + t;
  int v = (i < Nn) ? cnt[i] : 0;
  s[t] = v;
  __syncthreads();
  for (int off = 1; off < 256; off <<= 1) {
    int u = (t >= off) ? s[t - off] : 0;
    __syncthreads();
    s[t] += u;
    __syncthreads();
  }
  int excl = s[t] - v;
  int base = bpre[blockIdx.x];
  if (i < Nn) { rowptr[i] = base + excl; cursor[i] = base + excl; }
  if (i == Nn - 1) rowptr[Nn] = base + excl + v;
}

__global__ void fill_kernel(const int* __restrict__ ei, const float* __restrict__ dis,
                            int* __restrict__ cursor, int* __restrict__ csr_src,
                            float* __restrict__ csr_w) {
  int e = blockIdx.x * 256 + threadIdx.x;
  if (e >= Ee) return;
  int r = ei[e], c = ei[Ee + e];
  int p = atomicAdd(&cursor[c], 1);
  csr_src[p] = r;
  csr_w[p] = dis[r] * dis[c];
}

// Pack GRU weights into fragment-major split-bf16:
// B[kc:8][fid:24][g][c16][j], fid = gate*8+f; k = kc*32+g*8+j, col c=(fid&7)*16+c16,
// weight row = gate*128 + c. kc<4 -> Wih, kc>=4 -> Whh.
__global__ void pack_kernel(const float* __restrict__ Wih, const float* __restrict__ Whh,
                            ushort* __restrict__ Bhi, ushort* __restrict__ Blo) {
  int t = blockIdx.x * 256 + threadIdx.x;  // 8*24*4*16 = 12288 threads
  if (t >= 8 * 24 * 4 * 16) return;
  int c16 = t & 15;
  int g = (t >> 4) & 3;
  int fid = (t >> 6) % 24;
  int kc = t / (24 * 64);
  int gate = fid >> 3, f = fid & 7;
  int c = f * 16 + c16;
  int wrow = gate * 128 + c;
  size_t base = (size_t)t * 8;
#pragma unroll
  for (int j = 0; j < 8; ++j) {
    int k = kc * 32 + g * 8 + j;
    float v = (k < 128) ? Wih[wrow * 128 + k] : Whh[wrow * 128 + (k - 128)];
    ushort hi = f2bf(v);
    Bhi[base + j] = hi;
    Blo[base + j] = f2bf(v - bf2f(hi));
  }
}

// Pack MLP W1 (64 x 128): Bm[kc][cf][g][c16][j], c = cf*16+c16, k = kc*32+g*8+j
__global__ void pack_mlp(const float* __restrict__ Wm1, ushort* __restrict__ Bh,
                         ushort* __restrict__ Bl) {
  int t = blockIdx.x * 256 + threadIdx.x;  // 4*4*4*16 = 1024
  if (t >= 1024) return;
  int c16 = t & 15;
  int g = (t >> 4) & 3;
  int cf = (t >> 6) & 3;
  int kc = t >> 8;
  int c = cf * 16 + c16;
  size_t base = (size_t)t * 8;
#pragma unroll
  for (int j = 0; j < 8; ++j) {
    int k = kc * 32 + g * 8 + j;
    float v = Wm1[c * 128 + k];
    ushort hi = f2bf(v);
    Bh[base + j] = hi;
    Bl[base + j] = f2bf(v - bf2f(hi));
  }
}

// h0: leaky_relu(X @ W0^T + b0), row-major fp32.
__global__ void h0_kernel(const float* __restrict__ X, const float* __restrict__ W0,
                          const float* __restrict__ b0, float* __restrict__ H0) {
  int t = blockIdx.x * 256 + threadIdx.x;
  int i = t >> 7, d = t & 127;
  if (i >= NP) return;
  float v = 0.0f;
  if (i < Nn) {
    float x0 = X[i * 3 + 0], x1 = X[i * 3 + 1], x2 = X[i * 3 + 2];
    v = fmaf(x0, W0[d * 3 + 0], fmaf(x1, W0[d * 3 + 1], fmaf(x2, W0[d * 3 + 2], b0[d])));
    v = v > 0.0f ? v : 0.01f * v;
  }
  H0[(size_t)i * Hh + d] = v;
}

// ---- Fused GCN-aggregate + GRU cell (row-major fp32 state) ----
// Block = 64 nodes (one tile), 256 threads = 4 waves. LDS 64KB, 2 blocks/CU.
// P0: stage own 64 rows -> split-bf16 fragments HsH/HsL.
// P1: gather (4 thr/node x 32 contiguous dims, padded edge-unroll-4) -> AsH/AsL.
// P2: MFMA (kc0..3 from As, kc4..7 from Hs).
// P3: gate epilogue; hold from Hs (hi+lo); write Hn row-major direct.

#define DO_GATE(GB, ACC)                                                              \
  {                                                                                   \
    bf16x8 bH[2], bL[2];                                                              \
    _Pragma("unroll") for (int cf = 0; cf < 2; ++cf) {                                \
      size_t boff = (((size_t)(kc * 24 + (GB)*8 + wave * 2 + cf) * 4 + g) * 16 + c16) * 8; \
      bH[cf] = *(const bf16x8*)(Bhi + boff);                                          \
      bL[cf] = *(const bf16x8*)(Blo + boff);                                          \
    }                                                                                 \
    _Pragma("unroll") for (int cf = 0; cf < 2; ++cf)                                  \
        _Pragma("unroll") for (int rf = 0; rf < 4; ++rf)                              \
            ACC[rf][cf] = __builtin_amdgcn_mfma_f32_16x16x32_bf16(aH[rf], bH[cf], ACC[rf][cf], 0, 0, 0); \
    _Pragma("unroll") for (int cf = 0; cf < 2; ++cf)                                  \
        _Pragma("unroll") for (int rf = 0; rf < 4; ++rf)                              \
            ACC[rf][cf] = __builtin_amdgcn_mfma_f32_16x16x32_bf16(aH[rf], bL[cf], ACC[rf][cf], 0, 0, 0); \
    _Pragma("unroll") for (int cf = 0; cf < 2; ++cf)                                  \
        _Pragma("unroll") for (int rf = 0; rf < 4; ++rf)                              \
            ACC[rf][cf] = __builtin_amdgcn_mfma_f32_16x16x32_bf16(aL[rf], bH[cf], ACC[rf][cf], 0, 0, 0); \
  }

__global__ __launch_bounds__(256, 2) void gcn_gru_fused(
    const float* __restrict__ Hp, float* __restrict__ Hn,
    const int* __restrict__ csr_src, const float* __restrict__ csr_w,
    const int* __restrict__ rowptr,
    const ushort* __restrict__ Bhi, const ushort* __restrict__ Blo,
    const float* __restrict__ bih, const float* __restrict__ bhh) {
  __shared__ ushort AsH[8192];
  __shared__ ushort AsL[8192];
  __shared__ ushort HsH[8192];
  __shared__ ushort HsL[8192];
  const int tid = threadIdx.x;
  const int tile = blockIdx.x;
  const long rowbase = (long)tile * 64;

  const int local = tid >> 2;   // 0..63
  const int kc4 = tid & 3;      // dim block: d = kc4*32 + 0..31
  const int rf0 = local >> 4, c16l = local & 15;
  const int lwr = kc4 * 2048 + rf0 * 512 + c16l * 8;

  // ---- Phase 0: stage own rows ----
  {
    const float* p = Hp + (size_t)(rowbase + local) * Hh + kc4 * 32;
#pragma unroll
    for (int g2 = 0; g2 < 4; ++g2) {
      f32x4 v0 = *(const f32x4*)(p + g2 * 8);
      f32x4 v1 = *(const f32x4*)(p + g2 * 8 + 4);
      u16x8 vh, vl;
#pragma unroll
      for (int m = 0; m < 4; ++m) {
        ushort hb0 = f2bf(v0[m]);
        vh[m] = hb0;
        vl[m] = f2bf(v0[m] - bf2f(hb0));
        ushort hb1 = f2bf(v1[m]);
        vh[4 + m] = hb1;
        vl[4 + m] = f2bf(v1[m] - bf2f(hb1));
      }
      *(u16x8*)(HsH + lwr + g2 * 128) = vh;
      *(u16x8*)(HsL + lwr + g2 * 128) = vl;
    }
  }

  // ---- Phase 1: gather (padded unroll-4) ----
  {
    const long node = rowbase + local;
    float acc[32];
#pragma unroll
    for (int m = 0; m < 32; ++m) acc[m] = 0.0f;
    if (node < Nn) {
      const int e0 = rowptr[node], e1 = rowptr[node + 1];
      const float* hb = Hp + kc4 * 32;
      for (int e = e0; e < e1; e += 4) {
        int i1 = e + 1 < e1 ? e + 1 : e1 - 1;
        int i2 = e + 2 < e1 ? e + 2 : e1 - 1;
        int i3 = e + 3 < e1 ? e + 3 : e1 - 1;
        const int s0 = csr_src[e], s1 = csr_src[i1];
        const int s2 = csr_src[i2], s3 = csr_src[i3];
        const float w0 = csr_w[e];
        const float w1 = (e + 1 < e1) ? csr_w[i1] : 0.0f;
        const float w2 = (e + 2 < e1) ? csr_w[i2] : 0.0f;
        const float w3 = (e + 3 < e1) ? csr_w[i3] : 0.0f;
        const float* p0 = hb + (size_t)s0 * Hh;
        const float* p1 = hb + (size_t)s1 * Hh;
        const float* p2 = hb + (size_t)s2 * Hh;
        const float* p3 = hb + (size_t)s3 * Hh;
        f32x4 va[8], vb[8], vc[8], vd[8];
#pragma unroll
        for (int q = 0; q < 8; ++q) va[q] = *(const f32x4*)(p0 + q * 4);
#pragma unroll
        for (int q = 0; q < 8; ++q) vb[q] = *(const f32x4*)(p1 + q * 4);
#pragma unroll
        for (int q = 0; q < 8; ++q) vc[q] = *(const f32x4*)(p2 + q * 4);
#pragma unroll
        for (int q = 0; q < 8; ++q) vd[q] = *(const f32x4*)(p3 + q * 4);
#pragma unroll
        for (int q = 0; q < 8; ++q)
#pragma unroll
          for (int m = 0; m < 4; ++m)
            acc[q * 4 + m] =
                fmaf(w3, vd[q][m],
                     fmaf(w2, vc[q][m],
                          fmaf(w1, vb[q][m], fmaf(w0, va[q][m], acc[q * 4 + m]))));
      }
    }
#pragma unroll
    for (int g2 = 0; g2 < 4; ++g2) {
      u16x8 vh, vl;
#pragma unroll
      for (int j = 0; j < 8; ++j) {
        float v = acc[g2 * 8 + j];
        ushort hb2 = f2bf(v);
        vh[j] = hb2;
        vl[j] = f2bf(v - bf2f(hb2));
      }
      *(u16x8*)(AsH + lwr + g2 * 128) = vh;
      *(u16x8*)(AsL + lwr + g2 * 128) = vl;
    }
  }
  __syncthreads();

  // ---- Phase 2: MFMA ----
  const int wave = tid >> 6, lane = tid & 63;
  const int g = lane >> 4, c16 = lane & 15;
  const int lbase = g * 128 + c16 * 8;

  f32x4 accR[4][2], accZ[4][2], accXN[4][2], accHN[4][2];
#pragma unroll
  for (int rf = 0; rf < 4; ++rf)
#pragma unroll
    for (int cf = 0; cf < 2; ++cf) {
      accR[rf][cf] = (f32x4){0.f, 0.f, 0.f, 0.f};
      accZ[rf][cf] = (f32x4){0.f, 0.f, 0.f, 0.f};
      accXN[rf][cf] = (f32x4){0.f, 0.f, 0.f, 0.f};
      accHN[rf][cf] = (f32x4){0.f, 0.f, 0.f, 0.f};
    }

#pragma unroll
  for (int kc = 0; kc < 4; ++kc) {
    bf16x8 aH[4], aL[4];
#pragma unroll
    for (int rf = 0; rf < 4; ++rf) {
      int off = kc * 2048 + rf * 512 + lbase;
      aH[rf] = *(const bf16x8*)(AsH + off);
      aL[rf] = *(const bf16x8*)(AsL + off);
    }
    DO_GATE(0, accR)
    DO_GATE(1, accZ)
    DO_GATE(2, accXN)
  }
#pragma unroll
  for (int kc = 4; kc < 8; ++kc) {
    bf16x8 aH[4], aL[4];
#pragma unroll
    for (int rf = 0; rf < 4; ++rf) {
      int off = (kc - 4) * 2048 + rf * 512 + lbase;
      aH[rf] = *(const bf16x8*)(HsH + off);
      aL[rf] = *(const bf16x8*)(HsL + off);
    }
    DO_GATE(0, accR)
    DO_GATE(1, accZ)
    DO_GATE(2, accHN)
  }

  // ---- Phase 3: epilogue ----
#pragma unroll
  for (int cf = 0; cf < 2; ++cf) {
    const int c = (wave * 2 + cf) * 16 + c16;
    const float br = bih[c] + bhh[c];
    const float bz = bih[128 + c] + bhh[128 + c];
    const float bxn = bih[256 + c];
    const float bhn = bhh[256 + c];
    const int hcol = (cf * 2 + (c16 >> 3)) * 128 + (c16 & 7);
#pragma unroll
    for (int rf = 0; rf < 4; ++rf) {
#pragma unroll
      for (int reg = 0; reg < 4; ++reg) {
        const int lr = g * 4 + reg;  // local row within 16-block
        const int hoff = wave * 2048 + rf * 512 + hcol + lr * 8;
        float hold = bf2f(HsH[hoff]) + bf2f(HsL[hoff]);
        float rr = sigmoidf_(accR[rf][cf][reg] + br);
        float zz = sigmoidf_(accZ[rf][cf][reg] + bz);
        float nn = tanh_fast(accXN[rf][cf][reg] + bxn + rr * (accHN[rf][cf][reg] + bhn));
        Hn[(size_t)(rowbase + rf * 16 + lr) * Hh + c] = (1.0f - zz) * nn + zz * hold;
      }
    }
  }
}

// ---- Fused max(h1..h5) + MLP ----
// Block = 64 nodes, 4 waves; wave w owns cols [16w, 16w+16) of hid (64 cols).
__global__ __launch_bounds__(256, 2) void mlp_max_mfma(
    const float* __restrict__ H1, const float* __restrict__ H2,
    const float* __restrict__ H3, const float* __restrict__ H4,
    const float* __restrict__ H5,
    const ushort* __restrict__ Bh, const ushort* __restrict__ Bl,
    const float* __restrict__ bm1, const float* __restrict__ Wm2,
    const float* __restrict__ bm2, float* __restrict__ out) {
  __shared__ float red[4][64];
  const int tid = threadIdx.x;
  const int wave = tid >> 6, lane = tid & 63;
  const int g = lane >> 4, c16 = lane & 15;
  const long rowbase = (long)blockIdx.x * 64;

  f32x4 acc[4];
#pragma unroll
  for (int rf = 0; rf < 4; ++rf) acc[rf] = (f32x4){0.f, 0.f, 0.f, 0.f};

#pragma unroll
  for (int kc = 0; kc < 4; ++kc) {
    bf16x8 aH[4], aL[4];
#pragma unroll
    for (int rf = 0; rf < 4; ++rf) {
      size_t o = (size_t)(rowbase + rf * 16 + c16) * Hh + kc * 32 + g * 8;
      f32x4 m0 = *(const f32x4*)(H1 + o);
      f32x4 m1 = *(const f32x4*)(H1 + o + 4);
      m0 = max4(m0, *(const f32x4*)(H2 + o));
      m1 = max4(m1, *(const f32x4*)(H2 + o + 4));
      m0 = max4(m0, *(const f32x4*)(H3 + o));
      m1 = max4(m1, *(const f32x4*)(H3 + o + 4));
      m0 = max4(m0, *(const f32x4*)(H4 + o));
      m1 = max4(m1, *(const f32x4*)(H4 + o + 4));
      m0 = max4(m0, *(const f32x4*)(H5 + o));
      m1 = max4(m1, *(const f32x4*)(H5 + o + 4));
      u16x8 vh, vl;
#pragma unroll
      for (int m = 0; m < 4; ++m) {
        ushort hb0 = f2bf(m0[m]);
        vh[m] = hb0;
        vl[m] = f2bf(m0[m] - bf2f(hb0));
        ushort hb1 = f2bf(m1[m]);
        vh[4 + m] = hb1;
        vl[4 + m] = f2bf(m1[m] - bf2f(hb1));
      }
      aH[rf] = (bf16x8)vh;
      aL[rf] = (bf16x8)vl;
    }
    size_t boff = (((size_t)(kc * 4 + wave) * 4 + g) * 16 + c16) * 8;
    bf16x8 bH = *(const bf16x8*)(Bh + boff);
    bf16x8 bL = *(const bf16x8*)(Bl + boff);
#pragma unroll
    for (int rf = 0; rf < 4; ++rf)
      acc[rf] = __builtin_amdgcn_mfma_f32_16x16x32_bf16(aH[rf], bH, acc[rf], 0, 0, 0);
#pragma unroll
    for (int rf = 0; rf < 4; ++rf)
      acc[rf] = __builtin_amdgcn_mfma_f32_16x16x32_bf16(aH[rf], bL, acc[rf], 0, 0, 0);
#pragma unroll
    for (int rf = 0; rf < 4; ++rf)
      acc[rf] = __builtin_amdgcn_mfma_f32_16x16x32_bf16(aL[rf], bH, acc[rf], 0, 0, 0);
  }

  const int c = wave * 16 + c16;
  const float b1 = bm1[c];
  const float w2 = Wm2[c];
#pragma unroll
  for (int rf = 0; rf < 4; ++rf) {
#pragma unroll
    for (int reg = 0; reg < 4; ++reg) {
      float v = acc[rf][reg] + b1;
      v = v > 0.f ? v : 0.01f * v;
      v *= w2;
#pragma unroll
      for (int off = 1; off < 16; off <<= 1) v += __shfl_xor(v, off);
      if (c16 == 0) red[wave][rf * 16 + g * 4 + reg] = v;
    }
  }
  __syncthreads();
  if (tid < 64) {
    long row = rowbase + tid;
    if (row < Nn)
      out[row] = red[0][tid] + red[1][tid] + red[2][tid] + red[3][tid] + bm2[0];
  }
}

extern "C" void kernel_launch(void* const* d_in, const int* in_sizes, int n_in,
                              void* d_out, int out_size, void* d_ws, size_t ws_size,
                              hipStream_t stream) {
  const float* X = (const float*)d_in[0];
  const int* ei = (const int*)d_in[1];
  const float* W0 = (const float*)d_in[2];
  const float* b0 = (const float*)d_in[3];
  const float* Wih = (const float*)d_in[4];
  const float* Whh = (const float*)d_in[5];
  const float* bih = (const float*)d_in[6];
  const float* bhh = (const float*)d_in[7];
  const float* Wm1 = (const float*)d_in[8];
  const float* bm1 = (const float*)d_in[9];
  const float* Wm2 = (const float*)d_in[10];
  const float* bm2 = (const float*)d_in[11];
  float* out = (float*)d_out;

  char* ws = (char*)d_ws;
  size_t off = 0;
  auto alloc = [&](size_t bytes) -> void* {
    void* p = ws + off;
    off = (off + bytes + 255) & ~(size_t)255;
    return p;
  };
  float* Hs[5];
  for (int i = 0; i < 5; ++i) Hs[i] = (float*)alloc((size_t)NP * Hh * 4);
  ushort* Bhi = (ushort*)alloc((size_t)8 * 24 * 4 * 16 * 8 * 2);
  ushort* Blo = (ushort*)alloc((size_t)8 * 24 * 4 * 16 * 8 * 2);
  ushort* Bmh = (ushort*)alloc((size_t)1024 * 8 * 2);
  ushort* Bml = (ushort*)alloc((size_t)1024 * 8 * 2);
  float* dis = (float*)alloc((size_t)Nn * 4);
  int* degi = (int*)alloc((size_t)Nn * 4);
  int* cnt = (int*)alloc((size_t)Nn * 4);
  int* rowptr = (int*)alloc((size_t)(Nn + 1) * 4);
  int* cursor = (int*)alloc((size_t)Nn * 4);
  int* bsum = (int*)alloc(512 * 4);
  int* bpre = (int*)alloc(512 * 4);
  int* csr_src = (int*)alloc((size_t)Ee * 4);
  float* csr_w = (float*)alloc((size_t)Ee * 4);
  (void)ws_size;
  (void)in_sizes;
  (void)n_in;
  (void)out_size;

  const int NB = (Nn + 255) / 256;  // 391
  const int EB = (Ee + 255) / 256;  // 2344

  zero_kernel<<<NB, 256, 0, stream>>>(degi, cnt, Nn);
  count_kernel<<<EB, 256, 0, stream>>>(ei, degi, cnt);
  dis_kernel<<<NB, 256, 0, stream>>>(degi, dis);
  scan_partial<<<NB, 256, 0, stream>>>(cnt, bsum);
  scan_bsums<<<1, 512, 0, stream>>>(bsum, bpre, NB);
  scan_final<<<NB, 256, 0, stream>>>(cnt, bpre, rowptr, cursor);
  fill_kernel<<<EB, 256, 0, stream>>>(ei, dis, cursor, csr_src, csr_w);
  pack_kernel<<<48, 256, 0, stream>>>(Wih, Whh, Bhi, Blo);
  pack_mlp<<<4, 256, 0, stream>>>(Wm1, Bmh, Bml);
  h0_kernel<<<(NP * Hh) / 256, 256, 0, stream>>>(X, W0, b0, Hs[0]);

  // iteration t: read Hs[(t-1)%5], write Hs[t%5]  (t=5 reuses slot 0; h0 is dead by then)
  for (int t = 1; t <= 5; ++t) {
    gcn_gru_fused<<<NT, 256, 0, stream>>>(Hs[(t - 1) % 5], Hs[t % 5], csr_src, csr_w,
                                          rowptr, Bhi, Blo, bih, bhh);
  }

  mlp_max_mfma<<<NT, 256, 0, stream>>>(Hs[1], Hs[2], Hs[3], Hs[4], Hs[0], Bmh, Bml,
                                       bm1, Wm2, bm2, out);
}

// Round 10
// 855.286 us; speedup vs baseline: 1.1792x; 1.1253x over previous
//
#include <hip/hip_runtime.h>

#define Nn 100000
#define Ee 600000
#define Hh 128
#define NP 100096  // padded node rows: multiple of 64
#define NT (NP / 64)  // 1564 tiles

typedef short bf16x8 __attribute__((ext_vector_type(8)));
typedef float f32x4 __attribute__((ext_vector_type(4)));
typedef unsigned short u16x8 __attribute__((ext_vector_type(8)));

static __device__ __forceinline__ float sigmoidf_(float x) {
  return 1.0f / (1.0f + __expf(-x));
}
static __device__ __forceinline__ float tanh_fast(float x) {
  return 1.0f - 2.0f / (__expf(2.0f * x) + 1.0f);
}
// round-to-nearest-even fp32 -> bf16 bits
static __device__ __forceinline__ ushort f2bf(float v) {
  unsigned u = __float_as_uint(v);
  unsigned r = (u + 0x7fffu + ((u >> 16) & 1u)) >> 16;
  return (ushort)r;
}
static __device__ __forceinline__ float bf2f(ushort b) {
  return __uint_as_float(((unsigned)b) << 16);
}
static __device__ __forceinline__ f32x4 max4(f32x4 a, f32x4 b) {
  f32x4 r;
  r[0] = fmaxf(a[0], b[0]);
  r[1] = fmaxf(a[1], b[1]);
  r[2] = fmaxf(a[2], b[2]);
  r[3] = fmaxf(a[3], b[3]);
  return r;
}
// LDS fragment layout (ushort idx): [kc:4][rf:4][g:4][c16:16][j:8]
// element (local row r, dim d): rf=r>>4, c16=r&15; kc=d>>5, g=(d>>3)&3, j=d&7

__global__ void zero_kernel(int* __restrict__ a, int* __restrict__ b, int n) {
  int i = blockIdx.x * 256 + threadIdx.x;
  if (i < n) { a[i] = 0; b[i] = 0; }
}

__global__ void count_kernel(const int* __restrict__ ei, int* __restrict__ degi,
                             int* __restrict__ cnt) {
  int e = blockIdx.x * 256 + threadIdx.x;
  if (e >= Ee) return;
  int r = ei[e], c = ei[Ee + e];
  atomicAdd(&degi[r], 1);
  atomicAdd(&degi[c], 1);
  atomicAdd(&cnt[c], 1);
}

__global__ void dis_kernel(const int* __restrict__ degi, float* __restrict__ dis) {
  int i = blockIdx.x * 256 + threadIdx.x;
  if (i < Nn) dis[i] = rsqrtf((float)degi[i] + 1.0f);
}

__global__ void scan_partial(const int* __restrict__ cnt, int* __restrict__ bsum) {
  __shared__ int s[256];
  int i = blockIdx.x * 256 + threadIdx.x;
  s[threadIdx.x] = (i < Nn) ? cnt[i] : 0;
  __syncthreads();
  for (int off = 128; off > 0; off >>= 1) {
    if (threadIdx.x < off) s[threadIdx.x] += s[threadIdx.x + off];
    __syncthreads();
  }
  if (threadIdx.x == 0) bsum[blockIdx.x] = s[0];
}

__global__ void scan_bsums(const int* __restrict__ bsum, int* __restrict__ bpre, int nb) {
  __shared__ int s[512];
  int t = threadIdx.x;
  s[t] = (t < nb) ? bsum[t] : 0;
  __syncthreads();
  for (int off = 1; off < 512; off <<= 1) {
    int u = (t >= off) ? s[t - off] : 0;
    __syncthreads();
    s[t] += u;
    __syncthreads();
  }
  if (t < nb) bpre[t] = (t == 0) ? 0 : s[t - 1];
}

__global__ void scan_final(const int* __restrict__ cnt, const int* __restrict__ bpre,
                           int* __restrict__ rowptr, int* __restrict__ cursor) {
  __shared__ int s[256];
  int t = threadIdx.x;
  int i = blockIdx.x * 256 + t;
  int v = (i < Nn) ? cnt[i] : 0;
  s[t] = v;
  __syncthreads();
  for (int off = 1; off < 256; off <<= 1) {
    int u = (t >= off) ? s[t - off] : 0;
    __syncthreads();
    s[t] += u;
    __syncthreads();
  }
  int excl = s[t] - v;
  int base = bpre[blockIdx.x];
  if (i < Nn) { rowptr[i] = base + excl; cursor[i] = base + excl; }
  if (i == Nn - 1) rowptr[Nn] = base + excl + v;
}

__global__ void fill_kernel(const int* __restrict__ ei, const float* __restrict__ dis,
                            int* __restrict__ cursor, int* __restrict__ csr_src,
                            float* __restrict__ csr_w) {
  int e = blockIdx.x * 256 + threadIdx.x;
  if (e >= Ee) return;
  int r = ei[e], c = ei[Ee + e];
  int p = atomicAdd(&cursor[c], 1);
  csr_src[p] = r;
  csr_w[p] = dis[r] * dis[c];
}

// Pack GRU weights into fragment-major split-bf16:
// B[kc:8][fid:24][g][c16][j], fid = gate*8+f; k = kc*32+g*8+j, col c=(fid&7)*16+c16,
// weight row = gate*128 + c. kc<4 -> Wih, kc>=4 -> Whh.
__global__ void pack_kernel(const float* __restrict__ Wih, const float* __restrict__ Whh,
                            ushort* __restrict__ Bhi, ushort* __restrict__ Blo) {
  int t = blockIdx.x * 256 + threadIdx.x;  // 8*24*4*16 = 12288 threads
  if (t >= 8 * 24 * 4 * 16) return;
  int c16 = t & 15;
  int g = (t >> 4) & 3;
  int fid = (t >> 6) % 24;
  int kc = t / (24 * 64);
  int gate = fid >> 3, f = fid & 7;
  int c = f * 16 + c16;
  int wrow = gate * 128 + c;
  size_t base = (size_t)t * 8;
#pragma unroll
  for (int j = 0; j < 8; ++j) {
    int k = kc * 32 + g * 8 + j;
    float v = (k < 128) ? Wih[wrow * 128 + k] : Whh[wrow * 128 + (k - 128)];
    ushort hi = f2bf(v);
    Bhi[base + j] = hi;
    Blo[base + j] = f2bf(v - bf2f(hi));
  }
}

// Pack MLP W1 (64 x 128): Bm[kc][cf][g][c16][j], c = cf*16+c16, k = kc*32+g*8+j
__global__ void pack_mlp(const float* __restrict__ Wm1, ushort* __restrict__ Bh,
                         ushort* __restrict__ Bl) {
  int t = blockIdx.x * 256 + threadIdx.x;  // 4*4*4*16 = 1024
  if (t >= 1024) return;
  int c16 = t & 15;
  int g = (t >> 4) & 3;
  int cf = (t >> 6) & 3;
  int kc = t >> 8;
  int c = cf * 16 + c16;
  size_t base = (size_t)t * 8;
#pragma unroll
  for (int j = 0; j < 8; ++j) {
    int k = kc * 32 + g * 8 + j;
    float v = Wm1[c * 128 + k];
    ushort hi = f2bf(v);
    Bh[base + j] = hi;
    Bl[base + j] = f2bf(v - bf2f(hi));
  }
}

// h0: leaky_relu(X @ W0^T + b0), row-major fp32.
__global__ void h0_kernel(const float* __restrict__ X, const float* __restrict__ W0,
                          const float* __restrict__ b0, float* __restrict__ H0) {
  int t = blockIdx.x * 256 + threadIdx.x;
  int i = t >> 7, d = t & 127;
  if (i >= NP) return;
  float v = 0.0f;
  if (i < Nn) {
    float x0 = X[i * 3 + 0], x1 = X[i * 3 + 1], x2 = X[i * 3 + 2];
    v = fmaf(x0, W0[d * 3 + 0], fmaf(x1, W0[d * 3 + 1], fmaf(x2, W0[d * 3 + 2], b0[d])));
    v = v > 0.0f ? v : 0.01f * v;
  }
  H0[(size_t)i * Hh + d] = v;
}

// ---- Fused GCN-aggregate + GRU cell (row-major fp32 state) ----
// Block = 64 nodes (one tile), 512 threads = 8 waves. LDS 64KB, 2 blocks/CU
// => 16 waves/CU for latency hiding.
// P0: stage own rows -> HsH/HsL (8 thr/row, 16 dims each).
// P1: gather: 8 thr/node = 4 dim-groups x 2 edge-groups; shfl_xor combine -> AsH/AsL.
// P2: MFMA (kc0..3 from As, kc4..7 from Hs); 8 waves x 1 col-frag per gate.
// P3: epilogue; each thread owns one column; write Hn row-major direct.

#define DO_GATE8(GB, ACC)                                                             \
  {                                                                                   \
    size_t boff = (((size_t)(kc * 24 + (GB)*8 + wave) * 4 + g) * 16 + c16) * 8;       \
    bf16x8 bH = *(const bf16x8*)(Bhi + boff);                                         \
    bf16x8 bL = *(const bf16x8*)(Blo + boff);                                         \
    _Pragma("unroll") for (int rf = 0; rf < 4; ++rf)                                  \
        ACC[rf] = __builtin_amdgcn_mfma_f32_16x16x32_bf16(aH[rf], bH, ACC[rf], 0, 0, 0); \
    _Pragma("unroll") for (int rf = 0; rf < 4; ++rf)                                  \
        ACC[rf] = __builtin_amdgcn_mfma_f32_16x16x32_bf16(aH[rf], bL, ACC[rf], 0, 0, 0); \
    _Pragma("unroll") for (int rf = 0; rf < 4; ++rf)                                  \
        ACC[rf] = __builtin_amdgcn_mfma_f32_16x16x32_bf16(aL[rf], bH, ACC[rf], 0, 0, 0); \
  }

__global__ __launch_bounds__(512, 4) void gcn_gru_fused(
    const float* __restrict__ Hp, float* __restrict__ Hn,
    const int* __restrict__ csr_src, const float* __restrict__ csr_w,
    const int* __restrict__ rowptr,
    const ushort* __restrict__ Bhi, const ushort* __restrict__ Blo,
    const float* __restrict__ bih, const float* __restrict__ bhh) {
  __shared__ ushort AsH[8192];
  __shared__ ushort AsL[8192];
  __shared__ ushort HsH[8192];
  __shared__ ushort HsL[8192];
  const int tid = threadIdx.x;
  const int tile = blockIdx.x;
  const long rowbase = (long)tile * 64;

  const int local = tid >> 3;  // 0..63 node
  const int sub = tid & 7;
  const int eg = sub & 1;      // edge group
  const int dg = sub >> 1;     // dim group (32 dims)
  const int rf0 = local >> 4, c16l = local & 15;
  const int lwr = dg * 2048 + rf0 * 512 + c16l * 8;

  // ---- Phase 0: stage own rows (16 dims per thread) ----
  {
    const float* p = Hp + (size_t)(rowbase + local) * Hh + dg * 32 + eg * 16;
#pragma unroll
    for (int h2 = 0; h2 < 2; ++h2) {
      f32x4 v0 = *(const f32x4*)(p + h2 * 8);
      f32x4 v1 = *(const f32x4*)(p + h2 * 8 + 4);
      u16x8 vh, vl;
#pragma unroll
      for (int m = 0; m < 4; ++m) {
        ushort hb0 = f2bf(v0[m]);
        vh[m] = hb0;
        vl[m] = f2bf(v0[m] - bf2f(hb0));
        ushort hb1 = f2bf(v1[m]);
        vh[4 + m] = hb1;
        vl[4 + m] = f2bf(v1[m] - bf2f(hb1));
      }
      const int g2 = eg * 2 + h2;
      *(u16x8*)(HsH + lwr + g2 * 128) = vh;
      *(u16x8*)(HsL + lwr + g2 * 128) = vl;
    }
  }

  // ---- Phase 1: gather (edge-split x 2, unroll-2) ----
  {
    const long node = rowbase + local;
    float acc[32];
#pragma unroll
    for (int m = 0; m < 32; ++m) acc[m] = 0.0f;
    if (node < Nn) {
      const int eEnd = rowptr[node + 1];
      int e = rowptr[node] + eg;
      const float* hb = Hp + dg * 32;
      for (; e + 2 < eEnd; e += 4) {
        const int s0 = csr_src[e], s1 = csr_src[e + 2];
        const float w0 = csr_w[e], w1 = csr_w[e + 2];
        const float* p0 = hb + (size_t)s0 * Hh;
        const float* p1 = hb + (size_t)s1 * Hh;
        f32x4 va[8], vb[8];
#pragma unroll
        for (int q = 0; q < 8; ++q) va[q] = *(const f32x4*)(p0 + q * 4);
#pragma unroll
        for (int q = 0; q < 8; ++q) vb[q] = *(const f32x4*)(p1 + q * 4);
#pragma unroll
        for (int q = 0; q < 8; ++q)
#pragma unroll
          for (int m = 0; m < 4; ++m)
            acc[q * 4 + m] = fmaf(w1, vb[q][m], fmaf(w0, va[q][m], acc[q * 4 + m]));
      }
      if (e < eEnd) {
        const int s0 = csr_src[e];
        const float w0 = csr_w[e];
        const float* p0 = hb + (size_t)s0 * Hh;
        f32x4 va[8];
#pragma unroll
        for (int q = 0; q < 8; ++q) va[q] = *(const f32x4*)(p0 + q * 4);
#pragma unroll
        for (int q = 0; q < 8; ++q)
#pragma unroll
          for (int m = 0; m < 4; ++m)
            acc[q * 4 + m] = fmaf(w0, va[q][m], acc[q * 4 + m]);
      }
    }
    // combine edge groups (eg pairs are adjacent lanes)
#pragma unroll
    for (int m = 0; m < 32; ++m) acc[m] += __shfl_xor(acc[m], 1);
    if (eg == 0) {
#pragma unroll
      for (int g2 = 0; g2 < 4; ++g2) {
        u16x8 vh, vl;
#pragma unroll
        for (int j = 0; j < 8; ++j) {
          float v = acc[g2 * 8 + j];
          ushort hb2 = f2bf(v);
          vh[j] = hb2;
          vl[j] = f2bf(v - bf2f(hb2));
        }
        *(u16x8*)(AsH + lwr + g2 * 128) = vh;
        *(u16x8*)(AsL + lwr + g2 * 128) = vl;
      }
    }
  }
  __syncthreads();

  // ---- Phase 2: MFMA (8 waves, 1 col-fragment per gate each) ----
  const int wave = tid >> 6, lane = tid & 63;
  const int g = lane >> 4, c16 = lane & 15;
  const int lbase = g * 128 + c16 * 8;

  f32x4 accR[4], accZ[4], accXN[4], accHN[4];
#pragma unroll
  for (int rf = 0; rf < 4; ++rf) {
    accR[rf] = (f32x4){0.f, 0.f, 0.f, 0.f};
    accZ[rf] = (f32x4){0.f, 0.f, 0.f, 0.f};
    accXN[rf] = (f32x4){0.f, 0.f, 0.f, 0.f};
    accHN[rf] = (f32x4){0.f, 0.f, 0.f, 0.f};
  }

#pragma unroll
  for (int kc = 0; kc < 4; ++kc) {
    bf16x8 aH[4], aL[4];
#pragma unroll
    for (int rf = 0; rf < 4; ++rf) {
      int off = kc * 2048 + rf * 512 + lbase;
      aH[rf] = *(const bf16x8*)(AsH + off);
      aL[rf] = *(const bf16x8*)(AsL + off);
    }
    DO_GATE8(0, accR)
    DO_GATE8(1, accZ)
    DO_GATE8(2, accXN)
  }
#pragma unroll
  for (int kc = 4; kc < 8; ++kc) {
    bf16x8 aH[4], aL[4];
#pragma unroll
    for (int rf = 0; rf < 4; ++rf) {
      int off = (kc - 4) * 2048 + rf * 512 + lbase;
      aH[rf] = *(const bf16x8*)(HsH + off);
      aL[rf] = *(const bf16x8*)(HsL + off);
    }
    DO_GATE8(0, accR)
    DO_GATE8(1, accZ)
    DO_GATE8(2, accHN)
  }

  // ---- Phase 3: epilogue (one column per thread) ----
  {
    const int c = wave * 16 + c16;
    const float br = bih[c] + bhh[c];
    const float bz = bih[128 + c] + bhh[128 + c];
    const float bxn = bih[256 + c];
    const float bhn = bhh[256 + c];
    const int kcs = c >> 5;
    const int gs = (c >> 3) & 3;
    const int js = c & 7;
#pragma unroll
    for (int rf = 0; rf < 4; ++rf) {
#pragma unroll
      for (int reg = 0; reg < 4; ++reg) {
        const int lr = g * 4 + reg;  // local row within 16-block
        const int hoff = kcs * 2048 + rf * 512 + gs * 128 + lr * 8 + js;
        float hold = bf2f(HsH[hoff]) + bf2f(HsL[hoff]);
        float rr = sigmoidf_(accR[rf][reg] + br);
        float zz = sigmoidf_(accZ[rf][reg] + bz);
        float nn = tanh_fast(accXN[rf][reg] + bxn + rr * (accHN[rf][reg] + bhn));
        Hn[(size_t)(rowbase + rf * 16 + lr) * Hh + c] = (1.0f - zz) * nn + zz * hold;
      }
    }
  }
}

// ---- Fused max(h1..h5) + MLP ----
// Block = 64 nodes, 4 waves; wave w owns cols [16w, 16w+16) of hid (64 cols).
__global__ __launch_bounds__(256, 2) void mlp_max_mfma(
    const float* __restrict__ H1, const float* __restrict__ H2,
    const float* __restrict__ H3, const float* __restrict__ H4,
    const float* __restrict__ H5,
    const ushort* __restrict__ Bh, const ushort* __restrict__ Bl,
    const float* __restrict__ bm1, const float* __restrict__ Wm2,
    const float* __restrict__ bm2, float* __restrict__ out) {
  __shared__ float red[4][64];
  const int tid = threadIdx.x;
  const int wave = tid >> 6, lane = tid & 63;
  const int g = lane >> 4, c16 = lane & 15;
  const long rowbase = (long)blockIdx.x * 64;

  f32x4 acc[4];
#pragma unroll
  for (int rf = 0; rf < 4; ++rf) acc[rf] = (f32x4){0.f, 0.f, 0.f, 0.f};

#pragma unroll
  for (int kc = 0; kc < 4; ++kc) {
    bf16x8 aH[4], aL[4];
#pragma unroll
    for (int rf = 0; rf < 4; ++rf) {
      size_t o = (size_t)(rowbase + rf * 16 + c16) * Hh + kc * 32 + g * 8;
      f32x4 m0 = *(const f32x4*)(H1 + o);
      f32x4 m1 = *(const f32x4*)(H1 + o + 4);
      m0 = max4(m0, *(const f32x4*)(H2 + o));
      m1 = max4(m1, *(const f32x4*)(H2 + o + 4));
      m0 = max4(m0, *(const f32x4*)(H3 + o));
      m1 = max4(m1, *(const f32x4*)(H3 + o + 4));
      m0 = max4(m0, *(const f32x4*)(H4 + o));
      m1 = max4(m1, *(const f32x4*)(H4 + o + 4));
      m0 = max4(m0, *(const f32x4*)(H5 + o));
      m1 = max4(m1, *(const f32x4*)(H5 + o + 4));
      u16x8 vh, vl;
#pragma unroll
      for (int m = 0; m < 4; ++m) {
        ushort hb0 = f2bf(m0[m]);
        vh[m] = hb0;
        vl[m] = f2bf(m0[m] - bf2f(hb0));
        ushort hb1 = f2bf(m1[m]);
        vh[4 + m] = hb1;
        vl[4 + m] = f2bf(m1[m] - bf2f(hb1));
      }
      aH[rf] = (bf16x8)vh;
      aL[rf] = (bf16x8)vl;
    }
    size_t boff = (((size_t)(kc * 4 + wave) * 4 + g) * 16 + c16) * 8;
    bf16x8 bH = *(const bf16x8*)(Bh + boff);
    bf16x8 bL = *(const bf16x8*)(Bl + boff);
#pragma unroll
    for (int rf = 0; rf < 4; ++rf)
      acc[rf] = __builtin_amdgcn_mfma_f32_16x16x32_bf16(aH[rf], bH, acc[rf], 0, 0, 0);
#pragma unroll
    for (int rf = 0; rf < 4; ++rf)
      acc[rf] = __builtin_amdgcn_mfma_f32_16x16x32_bf16(aH[rf], bL, acc[rf], 0, 0, 0);
#pragma unroll
    for (int rf = 0; rf < 4; ++rf)
      acc[rf] = __builtin_amdgcn_mfma_f32_16x16x32_bf16(aL[rf], bH, acc[rf], 0, 0, 0);
  }

  const int c = wave * 16 + c16;
  const float b1 = bm1[c];
  const float w2 = Wm2[c];
#pragma unroll
  for (int rf = 0; rf < 4; ++rf) {
#pragma unroll
    for (int reg = 0; reg < 4; ++reg) {
      float v = acc[rf][reg] + b1;
      v = v > 0.f ? v : 0.01f * v;
      v *= w2;
#pragma unroll
      for (int off = 1; off < 16; off <<= 1) v += __shfl_xor(v, off);
      if (c16 == 0) red[wave][rf * 16 + g * 4 + reg] = v;
    }
  }
  __syncthreads();
  if (tid < 64) {
    long row = rowbase + tid;
    if (row < Nn)
      out[row] = red[0][tid] + red[1][tid] + red[2][tid] + red[3][tid] + bm2[0];
  }
}

extern "C" void kernel_launch(void* const* d_in, const int* in_sizes, int n_in,
                              void* d_out, int out_size, void* d_ws, size_t ws_size,
                              hipStream_t stream) {
  const float* X = (const float*)d_in[0];
  const int* ei = (const int*)d_in[1];
  const float* W0 = (const float*)d_in[2];
  const float* b0 = (const float*)d_in[3];
  const float* Wih = (const float*)d_in[4];
  const float* Whh = (const float*)d_in[5];
  const float* bih = (const float*)d_in[6];
  const float* bhh = (const float*)d_in[7];
  const float* Wm1 = (const float*)d_in[8];
  const float* bm1 = (const float*)d_in[9];
  const float* Wm2 = (const float*)d_in[10];
  const float* bm2 = (const float*)d_in[11];
  float* out = (float*)d_out;

  char* ws = (char*)d_ws;
  size_t off = 0;
  auto alloc = [&](size_t bytes) -> void* {
    void* p = ws + off;
    off = (off + bytes + 255) & ~(size_t)255;
    return p;
  };
  float* Hs[5];
  for (int i = 0; i < 5; ++i) Hs[i] = (float*)alloc((size_t)NP * Hh * 4);
  ushort* Bhi = (ushort*)alloc((size_t)8 * 24 * 4 * 16 * 8 * 2);
  ushort* Blo = (ushort*)alloc((size_t)8 * 24 * 4 * 16 * 8 * 2);
  ushort* Bmh = (ushort*)alloc((size_t)1024 * 8 * 2);
  ushort* Bml = (ushort*)alloc((size_t)1024 * 8 * 2);
  float* dis = (float*)alloc((size_t)Nn * 4);
  int* degi = (int*)alloc((size_t)Nn * 4);
  int* cnt = (int*)alloc((size_t)Nn * 4);
  int* rowptr = (int*)alloc((size_t)(Nn + 1) * 4);
  int* cursor = (int*)alloc((size_t)Nn * 4);
  int* bsum = (int*)alloc(512 * 4);
  int* bpre = (int*)alloc(512 * 4);
  int* csr_src = (int*)alloc((size_t)Ee * 4);
  float* csr_w = (float*)alloc((size_t)Ee * 4);
  (void)ws_size;
  (void)in_sizes;
  (void)n_in;
  (void)out_size;

  const int NB = (Nn + 255) / 256;  // 391
  const int EB = (Ee + 255) / 256;  // 2344

  zero_kernel<<<NB, 256, 0, stream>>>(degi, cnt, Nn);
  count_kernel<<<EB, 256, 0, stream>>>(ei, degi, cnt);
  dis_kernel<<<NB, 256, 0, stream>>>(degi, dis);
  scan_partial<<<NB, 256, 0, stream>>>(cnt, bsum);
  scan_bsums<<<1, 512, 0, stream>>>(bsum, bpre, NB);
  scan_final<<<NB, 256, 0, stream>>>(cnt, bpre, rowptr, cursor);
  fill_kernel<<<EB, 256, 0, stream>>>(ei, dis, cursor, csr_src, csr_w);
  pack_kernel<<<48, 256, 0, stream>>>(Wih, Whh, Bhi, Blo);
  pack_mlp<<<4, 256, 0, stream>>>(Wm1, Bmh, Bml);
  h0_kernel<<<(NP * Hh) / 256, 256, 0, stream>>>(X, W0, b0, Hs[0]);

  // iteration t: read Hs[(t-1)%5], write Hs[t%5]  (t=5 reuses slot 0; h0 is dead by then)
  for (int t = 1; t <= 5; ++t) {
    gcn_gru_fused<<<NT, 512, 0, stream>>>(Hs[(t - 1) % 5], Hs[t % 5], csr_src, csr_w,
                                          rowptr, Bhi, Blo, bih, bhh);
  }

  mlp_max_mfma<<<NT, 256, 0, stream>>>(Hs[1], Hs[2], Hs[3], Hs[4], Hs[0], Bmh, Bml,
                                       bm1, Wm2, bm2, out);
}

// Round 11
// 793.247 us; speedup vs baseline: 1.2714x; 1.0782x over previous
//
#include <hip/hip_runtime.h>

#define Nn 100000
#define Ee 600000
#define Hh 128
#define NP 100096  // padded node rows: multiple of 64
#define NT (NP / 64)  // 1564 tiles

typedef short bf16x8 __attribute__((ext_vector_type(8)));
typedef float f32x4 __attribute__((ext_vector_type(4)));
typedef unsigned short u16x8 __attribute__((ext_vector_type(8)));

static __device__ __forceinline__ float sigmoidf_(float x) {
  return 1.0f / (1.0f + __expf(-x));
}
static __device__ __forceinline__ float tanh_fast(float x) {
  return 1.0f - 2.0f / (__expf(2.0f * x) + 1.0f);
}
// round-to-nearest-even fp32 -> bf16 bits
static __device__ __forceinline__ ushort f2bf(float v) {
  unsigned u = __float_as_uint(v);
  unsigned r = (u + 0x7fffu + ((u >> 16) & 1u)) >> 16;
  return (ushort)r;
}
static __device__ __forceinline__ float bf2f(ushort b) {
  return __uint_as_float(((unsigned)b) << 16);
}
static __device__ __forceinline__ f32x4 max4(f32x4 a, f32x4 b) {
  f32x4 r;
  r[0] = fmaxf(a[0], b[0]);
  r[1] = fmaxf(a[1], b[1]);
  r[2] = fmaxf(a[2], b[2]);
  r[3] = fmaxf(a[3], b[3]);
  return r;
}
// LDS fragment layout (ushort idx): [kc:4][rf:4][g:4][c16:16][j:8]
// element (local row r, dim d): rf=r>>4, c16=r&15; kc=d>>5, g=(d>>3)&3, j=d&7

__global__ void zero_kernel(int* __restrict__ a, int* __restrict__ b, int n) {
  int i = blockIdx.x * 256 + threadIdx.x;
  if (i < n) { a[i] = 0; b[i] = 0; }
}

__global__ void count_kernel(const int* __restrict__ ei, int* __restrict__ degi,
                             int* __restrict__ cnt) {
  int e = blockIdx.x * 256 + threadIdx.x;
  if (e >= Ee) return;
  int r = ei[e], c = ei[Ee + e];
  atomicAdd(&degi[r], 1);
  atomicAdd(&degi[c], 1);
  atomicAdd(&cnt[c], 1);
}

__global__ void dis_kernel(const int* __restrict__ degi, float* __restrict__ dis) {
  int i = blockIdx.x * 256 + threadIdx.x;
  if (i < Nn) dis[i] = rsqrtf((float)degi[i] + 1.0f);
}

__global__ void scan_partial(const int* __restrict__ cnt, int* __restrict__ bsum) {
  __shared__ int s[256];
  int i = blockIdx.x * 256 + threadIdx.x;
  s[threadIdx.x] = (i < Nn) ? cnt[i] : 0;
  __syncthreads();
  for (int off = 128; off > 0; off >>= 1) {
    if (threadIdx.x < off) s[threadIdx.x] += s[threadIdx.x + off];
    __syncthreads();
  }
  if (threadIdx.x == 0) bsum[blockIdx.x] = s[0];
}

__global__ void scan_bsums(const int* __restrict__ bsum, int* __restrict__ bpre, int nb) {
  __shared__ int s[512];
  int t = threadIdx.x;
  s[t] = (t < nb) ? bsum[t] : 0;
  __syncthreads();
  for (int off = 1; off < 512; off <<= 1) {
    int u = (t >= off) ? s[t - off] : 0;
    __syncthreads();
    s[t] += u;
    __syncthreads();
  }
  if (t < nb) bpre[t] = (t == 0) ? 0 : s[t - 1];
}

__global__ void scan_final(const int* __restrict__ cnt, const int* __restrict__ bpre,
                           int* __restrict__ rowptr, int* __restrict__ cursor) {
  __shared__ int s[256];
  int t = threadIdx.x;
  int i = blockIdx.x * 256 + t;
  int v = (i < Nn) ? cnt[i] : 0;
  s[t] = v;
  __syncthreads();
  for (int off = 1; off < 256; off <<= 1) {
    int u = (t >= off) ? s[t - off] : 0;
    __syncthreads();
    s[t] += u;
    __syncthreads();
  }
  int excl = s[t] - v;
  int base = bpre[blockIdx.x];
  if (i < Nn) { rowptr[i] = base + excl; cursor[i] = base + excl; }
  if (i == Nn - 1) rowptr[Nn] = base + excl + v;
}

__global__ void fill_kernel(const int* __restrict__ ei, const float* __restrict__ dis,
                            int* __restrict__ cursor, int* __restrict__ csr_src,
                            float* __restrict__ csr_w) {
  int e = blockIdx.x * 256 + threadIdx.x;
  if (e >= Ee) return;
  int r = ei[e], c = ei[Ee + e];
  int p = atomicAdd(&cursor[c], 1);
  csr_src[p] = r;
  csr_w[p] = dis[r] * dis[c];
}

// Pack GRU weights into fragment-major split-bf16:
// B[kc:8][fid:24][g][c16][j], fid = gate*8+f; k = kc*32+g*8+j, col c=(fid&7)*16+c16,
// weight row = gate*128 + c. kc<4 -> Wih, kc>=4 -> Whh.
__global__ void pack_kernel(const float* __restrict__ Wih, const float* __restrict__ Whh,
                            ushort* __restrict__ Bhi, ushort* __restrict__ Blo) {
  int t = blockIdx.x * 256 + threadIdx.x;  // 8*24*4*16 = 12288 threads
  if (t >= 8 * 24 * 4 * 16) return;
  int c16 = t & 15;
  int g = (t >> 4) & 3;
  int fid = (t >> 6) % 24;
  int kc = t / (24 * 64);
  int gate = fid >> 3, f = fid & 7;
  int c = f * 16 + c16;
  int wrow = gate * 128 + c;
  size_t base = (size_t)t * 8;
#pragma unroll
  for (int j = 0; j < 8; ++j) {
    int k = kc * 32 + g * 8 + j;
    float v = (k < 128) ? Wih[wrow * 128 + k] : Whh[wrow * 128 + (k - 128)];
    ushort hi = f2bf(v);
    Bhi[base + j] = hi;
    Blo[base + j] = f2bf(v - bf2f(hi));
  }
}

// Pack MLP W1 (64 x 128): Bm[kc][cf][g][c16][j], c = cf*16+c16, k = kc*32+g*8+j
__global__ void pack_mlp(const float* __restrict__ Wm1, ushort* __restrict__ Bh,
                         ushort* __restrict__ Bl) {
  int t = blockIdx.x * 256 + threadIdx.x;  // 4*4*4*16 = 1024
  if (t >= 1024) return;
  int c16 = t & 15;
  int g = (t >> 4) & 3;
  int cf = (t >> 6) & 3;
  int kc = t >> 8;
  int c = cf * 16 + c16;
  size_t base = (size_t)t * 8;
#pragma unroll
  for (int j = 0; j < 8; ++j) {
    int k = kc * 32 + g * 8 + j;
    float v = Wm1[c * 128 + k];
    ushort hi = f2bf(v);
    Bh[base + j] = hi;
    Bl[base + j] = f2bf(v - bf2f(hi));
  }
}

// h0: leaky_relu(X @ W0^T + b0), row-major fp32.
__global__ void h0_kernel(const float* __restrict__ X, const float* __restrict__ W0,
                          const float* __restrict__ b0, float* __restrict__ H0) {
  int t = blockIdx.x * 256 + threadIdx.x;
  int i = t >> 7, d = t & 127;
  if (i >= NP) return;
  float v = 0.0f;
  if (i < Nn) {
    float x0 = X[i * 3 + 0], x1 = X[i * 3 + 1], x2 = X[i * 3 + 2];
    v = fmaf(x0, W0[d * 3 + 0], fmaf(x1, W0[d * 3 + 1], fmaf(x2, W0[d * 3 + 2], b0[d])));
    v = v > 0.0f ? v : 0.01f * v;
  }
  H0[(size_t)i * Hh + d] = v;
}

// ---- Fused GCN-aggregate + GRU cell (row-major fp32 state) ----
// Block = 64 nodes (one tile), 512 threads = 8 waves. LDS 64KB, 2 blocks/CU
// => 16 waves/CU for latency hiding.

#define DO_GATE8(GB, ACC)                                                             \
  {                                                                                   \
    size_t boff = (((size_t)(kc * 24 + (GB)*8 + wave) * 4 + g) * 16 + c16) * 8;       \
    bf16x8 bH = *(const bf16x8*)(Bhi + boff);                                         \
    bf16x8 bL = *(const bf16x8*)(Blo + boff);                                         \
    _Pragma("unroll") for (int rf = 0; rf < 4; ++rf)                                  \
        ACC[rf] = __builtin_amdgcn_mfma_f32_16x16x32_bf16(aH[rf], bH, ACC[rf], 0, 0, 0); \
    _Pragma("unroll") for (int rf = 0; rf < 4; ++rf)                                  \
        ACC[rf] = __builtin_amdgcn_mfma_f32_16x16x32_bf16(aH[rf], bL, ACC[rf], 0, 0, 0); \
    _Pragma("unroll") for (int rf = 0; rf < 4; ++rf)                                  \
        ACC[rf] = __builtin_amdgcn_mfma_f32_16x16x32_bf16(aL[rf], bH, ACC[rf], 0, 0, 0); \
  }

__global__ __launch_bounds__(512, 4) void gcn_gru_fused(
    const float* __restrict__ Hp, float* __restrict__ Hn,
    const int* __restrict__ csr_src, const float* __restrict__ csr_w,
    const int* __restrict__ rowptr,
    const ushort* __restrict__ Bhi, const ushort* __restrict__ Blo,
    const float* __restrict__ bih, const float* __restrict__ bhh) {
  __shared__ ushort AsH[8192];
  __shared__ ushort AsL[8192];
  __shared__ ushort HsH[8192];
  __shared__ ushort HsL[8192];
  const int tid = threadIdx.x;
  const int tile = blockIdx.x;
  const long rowbase = (long)tile * 64;

  const int local = tid >> 3;  // 0..63 node
  const int sub = tid & 7;
  const int eg = sub & 1;      // edge group
  const int dg = sub >> 1;     // dim group (32 dims)
  const int rf0 = local >> 4, c16l = local & 15;
  const int lwr = dg * 2048 + rf0 * 512 + c16l * 8;

  // ---- Phase 0: stage own rows (16 dims per thread) ----
  {
    const float* p = Hp + (size_t)(rowbase + local) * Hh + dg * 32 + eg * 16;
#pragma unroll
    for (int h2 = 0; h2 < 2; ++h2) {
      f32x4 v0 = *(const f32x4*)(p + h2 * 8);
      f32x4 v1 = *(const f32x4*)(p + h2 * 8 + 4);
      u16x8 vh, vl;
#pragma unroll
      for (int m = 0; m < 4; ++m) {
        ushort hb0 = f2bf(v0[m]);
        vh[m] = hb0;
        vl[m] = f2bf(v0[m] - bf2f(hb0));
        ushort hb1 = f2bf(v1[m]);
        vh[4 + m] = hb1;
        vl[4 + m] = f2bf(v1[m] - bf2f(hb1));
      }
      const int g2 = eg * 2 + h2;
      *(u16x8*)(HsH + lwr + g2 * 128) = vh;
      *(u16x8*)(HsL + lwr + g2 * 128) = vl;
    }
  }

  // ---- Phase 1: gather (edge-split x 2, unroll-2) ----
  {
    const long node = rowbase + local;
    float acc[32];
#pragma unroll
    for (int m = 0; m < 32; ++m) acc[m] = 0.0f;
    if (node < Nn) {
      const int eEnd = rowptr[node + 1];
      int e = rowptr[node] + eg;
      const float* hb = Hp + dg * 32;
      for (; e + 2 < eEnd; e += 4) {
        const int s0 = csr_src[e], s1 = csr_src[e + 2];
        const float w0 = csr_w[e], w1 = csr_w[e + 2];
        const float* p0 = hb + (size_t)s0 * Hh;
        const float* p1 = hb + (size_t)s1 * Hh;
        f32x4 va[8], vb[8];
#pragma unroll
        for (int q = 0; q < 8; ++q) va[q] = *(const f32x4*)(p0 + q * 4);
#pragma unroll
        for (int q = 0; q < 8; ++q) vb[q] = *(const f32x4*)(p1 + q * 4);
#pragma unroll
        for (int q = 0; q < 8; ++q)
#pragma unroll
          for (int m = 0; m < 4; ++m)
            acc[q * 4 + m] = fmaf(w1, vb[q][m], fmaf(w0, va[q][m], acc[q * 4 + m]));
      }
      if (e < eEnd) {
        const int s0 = csr_src[e];
        const float w0 = csr_w[e];
        const float* p0 = hb + (size_t)s0 * Hh;
        f32x4 va[8];
#pragma unroll
        for (int q = 0; q < 8; ++q) va[q] = *(const f32x4*)(p0 + q * 4);
#pragma unroll
        for (int q = 0; q < 8; ++q)
#pragma unroll
          for (int m = 0; m < 4; ++m)
            acc[q * 4 + m] = fmaf(w0, va[q][m], acc[q * 4 + m]);
      }
    }
    // combine edge groups (eg pairs are adjacent lanes)
#pragma unroll
    for (int m = 0; m < 32; ++m) acc[m] += __shfl_xor(acc[m], 1);
    if (eg == 0) {
#pragma unroll
      for (int g2 = 0; g2 < 4; ++g2) {
        u16x8 vh, vl;
#pragma unroll
        for (int j = 0; j < 8; ++j) {
          float v = acc[g2 * 8 + j];
          ushort hb2 = f2bf(v);
          vh[j] = hb2;
          vl[j] = f2bf(v - bf2f(hb2));
        }
        *(u16x8*)(AsH + lwr + g2 * 128) = vh;
        *(u16x8*)(AsL + lwr + g2 * 128) = vl;
      }
    }
  }
  __syncthreads();

  // ---- Phase 2: MFMA (8 waves, 1 col-fragment per gate each) ----
  const int wave = tid >> 6, lane = tid & 63;
  const int g = lane >> 4, c16 = lane & 15;
  const int lbase = g * 128 + c16 * 8;

  f32x4 accR[4], accZ[4], accXN[4], accHN[4];
#pragma unroll
  for (int rf = 0; rf < 4; ++rf) {
    accR[rf] = (f32x4){0.f, 0.f, 0.f, 0.f};
    accZ[rf] = (f32x4){0.f, 0.f, 0.f, 0.f};
    accXN[rf] = (f32x4){0.f, 0.f, 0.f, 0.f};
    accHN[rf] = (f32x4){0.f, 0.f, 0.f, 0.f};
  }

#pragma unroll
  for (int kc = 0; kc < 4; ++kc) {
    bf16x8 aH[4], aL[4];
#pragma unroll
    for (int rf = 0; rf < 4; ++rf) {
      int off = kc * 2048 + rf * 512 + lbase;
      aH[rf] = *(const bf16x8*)(AsH + off);
      aL[rf] = *(const bf16x8*)(AsL + off);
    }
    DO_GATE8(0, accR)
    DO_GATE8(1, accZ)
    DO_GATE8(2, accXN)
  }
#pragma unroll
  for (int kc = 4; kc < 8; ++kc) {
    bf16x8 aH[4], aL[4];
#pragma unroll
    for (int rf = 0; rf < 4; ++rf) {
      int off = (kc - 4) * 2048 + rf * 512 + lbase;
      aH[rf] = *(const bf16x8*)(HsH + off);
      aL[rf] = *(const bf16x8*)(HsL + off);
    }
    DO_GATE8(0, accR)
    DO_GATE8(1, accZ)
    DO_GATE8(2, accHN)
  }

  // ---- Phase 3: epilogue (one column per thread) ----
  {
    const int c = wave * 16 + c16;
    const float br = bih[c] + bhh[c];
    const float bz = bih[128 + c] + bhh[128 + c];
    const float bxn = bih[256 + c];
    const float bhn = bhh[256 + c];
    const int kcs = c >> 5;
    const int gs = (c >> 3) & 3;
    const int js = c & 7;
#pragma unroll
    for (int rf = 0; rf < 4; ++rf) {
#pragma unroll
      for (int reg = 0; reg < 4; ++reg) {
        const int lr = g * 4 + reg;  // local row within 16-block
        const int hoff = kcs * 2048 + rf * 512 + gs * 128 + lr * 8 + js;
        float hold = bf2f(HsH[hoff]) + bf2f(HsL[hoff]);
        float rr = sigmoidf_(accR[rf][reg] + br);
        float zz = sigmoidf_(accZ[rf][reg] + bz);
        float nn = tanh_fast(accXN[rf][reg] + bxn + rr * (accHN[rf][reg] + bhn));
        Hn[(size_t)(rowbase + rf * 16 + lr) * Hh + c] = (1.0f - zz) * nn + zz * hold;
      }
    }
  }
}

// ---- Fused max(h1..h5) + MLP (LDS-staged, 1x reads) ----
// Block = 64 nodes, 256 threads = 4 waves; wave w owns cols [16w,16w+16).
// P1: cooperative 5-way max -> split-bf16 fragments in LDS (each line read once).
// P2: MFMA from LDS. P3: leaky-relu * Wm2, reduce.
__global__ __launch_bounds__(256, 4) void mlp_max_mfma(
    const float* __restrict__ H1, const float* __restrict__ H2,
    const float* __restrict__ H3, const float* __restrict__ H4,
    const float* __restrict__ H5,
    const ushort* __restrict__ Bh, const ushort* __restrict__ Bl,
    const float* __restrict__ bm1, const float* __restrict__ Wm2,
    const float* __restrict__ bm2, float* __restrict__ out) {
  __shared__ ushort AsH[8192];
  __shared__ ushort AsL[8192];
  __shared__ float red[4][64];
  const int tid = threadIdx.x;
  const long rowbase = (long)blockIdx.x * 64;

  // ---- Phase 1: cooperative max + fragment stage ----
  {
    const int local = tid >> 2, kc4 = tid & 3;
    const int rf0 = local >> 4, c16l = local & 15;
    const int lwr = kc4 * 2048 + rf0 * 512 + c16l * 8;
    size_t o = (size_t)(rowbase + local) * Hh + kc4 * 32;
    f32x4 mx[8];
#pragma unroll
    for (int q = 0; q < 8; ++q) mx[q] = *(const f32x4*)(H1 + o + q * 4);
    const float* arrs[4] = {H2, H3, H4, H5};
#pragma unroll
    for (int a = 0; a < 4; ++a) {
      const float* p = arrs[a] + o;
#pragma unroll
      for (int q = 0; q < 8; ++q) mx[q] = max4(mx[q], *(const f32x4*)(p + q * 4));
    }
#pragma unroll
    for (int g2 = 0; g2 < 4; ++g2) {
      u16x8 vh, vl;
#pragma unroll
      for (int m = 0; m < 4; ++m) {
        float v0 = mx[g2 * 2][m], v1 = mx[g2 * 2 + 1][m];
        ushort hb0 = f2bf(v0);
        vh[m] = hb0;
        vl[m] = f2bf(v0 - bf2f(hb0));
        ushort hb1 = f2bf(v1);
        vh[4 + m] = hb1;
        vl[4 + m] = f2bf(v1 - bf2f(hb1));
      }
      *(u16x8*)(AsH + lwr + g2 * 128) = vh;
      *(u16x8*)(AsL + lwr + g2 * 128) = vl;
    }
  }
  __syncthreads();

  // ---- Phase 2: MFMA from LDS ----
  const int wave = tid >> 6, lane = tid & 63;
  const int g = lane >> 4, c16 = lane & 15;
  const int lbase = g * 128 + c16 * 8;

  f32x4 acc[4];
#pragma unroll
  for (int rf = 0; rf < 4; ++rf) acc[rf] = (f32x4){0.f, 0.f, 0.f, 0.f};

#pragma unroll
  for (int kc = 0; kc < 4; ++kc) {
    bf16x8 aH[4], aL[4];
#pragma unroll
    for (int rf = 0; rf < 4; ++rf) {
      int off = kc * 2048 + rf * 512 + lbase;
      aH[rf] = *(const bf16x8*)(AsH + off);
      aL[rf] = *(const bf16x8*)(AsL + off);
    }
    size_t boff = (((size_t)(kc * 4 + wave) * 4 + g) * 16 + c16) * 8;
    bf16x8 bH = *(const bf16x8*)(Bh + boff);
    bf16x8 bL = *(const bf16x8*)(Bl + boff);
#pragma unroll
    for (int rf = 0; rf < 4; ++rf)
      acc[rf] = __builtin_amdgcn_mfma_f32_16x16x32_bf16(aH[rf], bH, acc[rf], 0, 0, 0);
#pragma unroll
    for (int rf = 0; rf < 4; ++rf)
      acc[rf] = __builtin_amdgcn_mfma_f32_16x16x32_bf16(aH[rf], bL, acc[rf], 0, 0, 0);
#pragma unroll
    for (int rf = 0; rf < 4; ++rf)
      acc[rf] = __builtin_amdgcn_mfma_f32_16x16x32_bf16(aL[rf], bH, acc[rf], 0, 0, 0);
  }

  const int c = wave * 16 + c16;
  const float b1 = bm1[c];
  const float w2 = Wm2[c];
#pragma unroll
  for (int rf = 0; rf < 4; ++rf) {
#pragma unroll
    for (int reg = 0; reg < 4; ++reg) {
      float v = acc[rf][reg] + b1;
      v = v > 0.f ? v : 0.01f * v;
      v *= w2;
#pragma unroll
      for (int off = 1; off < 16; off <<= 1) v += __shfl_xor(v, off);
      if (c16 == 0) red[wave][rf * 16 + g * 4 + reg] = v;
    }
  }
  __syncthreads();
  if (tid < 64) {
    long row = rowbase + tid;
    if (row < Nn)
      out[row] = red[0][tid] + red[1][tid] + red[2][tid] + red[3][tid] + bm2[0];
  }
}

extern "C" void kernel_launch(void* const* d_in, const int* in_sizes, int n_in,
                              void* d_out, int out_size, void* d_ws, size_t ws_size,
                              hipStream_t stream) {
  const float* X = (const float*)d_in[0];
  const int* ei = (const int*)d_in[1];
  const float* W0 = (const float*)d_in[2];
  const float* b0 = (const float*)d_in[3];
  const float* Wih = (const float*)d_in[4];
  const float* Whh = (const float*)d_in[5];
  const float* bih = (const float*)d_in[6];
  const float* bhh = (const float*)d_in[7];
  const float* Wm1 = (const float*)d_in[8];
  const float* bm1 = (const float*)d_in[9];
  const float* Wm2 = (const float*)d_in[10];
  const float* bm2 = (const float*)d_in[11];
  float* out = (float*)d_out;

  char* ws = (char*)d_ws;
  size_t off = 0;
  auto alloc = [&](size_t bytes) -> void* {
    void* p = ws + off;
    off = (off + bytes + 255) & ~(size_t)255;
    return p;
  };
  float* Hs[5];
  for (int i = 0; i < 5; ++i) Hs[i] = (float*)alloc((size_t)NP * Hh * 4);
  ushort* Bhi = (ushort*)alloc((size_t)8 * 24 * 4 * 16 * 8 * 2);
  ushort* Blo = (ushort*)alloc((size_t)8 * 24 * 4 * 16 * 8 * 2);
  ushort* Bmh = (ushort*)alloc((size_t)1024 * 8 * 2);
  ushort* Bml = (ushort*)alloc((size_t)1024 * 8 * 2);
  float* dis = (float*)alloc((size_t)Nn * 4);
  int* degi = (int*)alloc((size_t)Nn * 4);
  int* cnt = (int*)alloc((size_t)Nn * 4);
  int* rowptr = (int*)alloc((size_t)(Nn + 1) * 4);
  int* cursor = (int*)alloc((size_t)Nn * 4);
  int* bsum = (int*)alloc(512 * 4);
  int* bpre = (int*)alloc(512 * 4);
  int* csr_src = (int*)alloc((size_t)Ee * 4);
  float* csr_w = (float*)alloc((size_t)Ee * 4);
  (void)ws_size;
  (void)in_sizes;
  (void)n_in;
  (void)out_size;

  const int NB = (Nn + 255) / 256;  // 391
  const int EB = (Ee + 255) / 256;  // 2344

  zero_kernel<<<NB, 256, 0, stream>>>(degi, cnt, Nn);
  count_kernel<<<EB, 256, 0, stream>>>(ei, degi, cnt);
  dis_kernel<<<NB, 256, 0, stream>>>(degi, dis);
  scan_partial<<<NB, 256, 0, stream>>>(cnt, bsum);
  scan_bsums<<<1, 512, 0, stream>>>(bsum, bpre, NB);
  scan_final<<<NB, 256, 0, stream>>>(cnt, bpre, rowptr, cursor);
  fill_kernel<<<EB, 256, 0, stream>>>(ei, dis, cursor, csr_src, csr_w);
  pack_kernel<<<48, 256, 0, stream>>>(Wih, Whh, Bhi, Blo);
  pack_mlp<<<4, 256, 0, stream>>>(Wm1, Bmh, Bml);
  h0_kernel<<<(NP * Hh) / 256, 256, 0, stream>>>(X, W0, b0, Hs[0]);

  // iteration t: read Hs[(t-1)%5], write Hs[t%5]  (t=5 reuses slot 0; h0 is dead by then)
  for (int t = 1; t <= 5; ++t) {
    gcn_gru_fused<<<NT, 512, 0, stream>>>(Hs[(t - 1) % 5], Hs[t % 5], csr_src, csr_w,
                                          rowptr, Bhi, Blo, bih, bhh);
  }

  mlp_max_mfma<<<NT, 256, 0, stream>>>(Hs[1], Hs[2], Hs[3], Hs[4], Hs[0], Bmh, Bml,
                                       bm1, Wm2, bm2, out);
}

// Round 12
// 784.170 us; speedup vs baseline: 1.2861x; 1.0116x over previous
//
#include <hip/hip_runtime.h>

#define Nn 100000
#define Ee 600000
#define Hh 128
#define NP 100096  // padded node rows: multiple of 64
#define NT (NP / 64)  // 1564 tiles

typedef short bf16x8 __attribute__((ext_vector_type(8)));
typedef float f32x4 __attribute__((ext_vector_type(4)));
typedef unsigned short u16x8 __attribute__((ext_vector_type(8)));

static __device__ __forceinline__ float sigmoidf_(float x) {
  return 1.0f / (1.0f + __expf(-x));
}
static __device__ __forceinline__ float tanh_fast(float x) {
  return 1.0f - 2.0f / (__expf(2.0f * x) + 1.0f);
}
// round-to-nearest-even fp32 -> bf16 bits
static __device__ __forceinline__ ushort f2bf(float v) {
  unsigned u = __float_as_uint(v);
  unsigned r = (u + 0x7fffu + ((u >> 16) & 1u)) >> 16;
  return (ushort)r;
}
static __device__ __forceinline__ float bf2f(ushort b) {
  return __uint_as_float(((unsigned)b) << 16);
}
static __device__ __forceinline__ f32x4 max4(f32x4 a, f32x4 b) {
  f32x4 r;
  r[0] = fmaxf(a[0], b[0]);
  r[1] = fmaxf(a[1], b[1]);
  r[2] = fmaxf(a[2], b[2]);
  r[3] = fmaxf(a[3], b[3]);
  return r;
}
// LDS fragment layout (ushort idx): [kc][rf:4][g:4][c16:16][j:8], bank-swizzled:
// uidx ^= ((uidx>>11)&3)<<4  (spreads kc bits into bank bits; bijective; 16B-align kept)
static __device__ __forceinline__ int swz(int u) {
  return u ^ (((u >> 11) & 3) << 4);
}

__global__ void zero_kernel(int* __restrict__ a, int* __restrict__ b, int n) {
  int i = blockIdx.x * 256 + threadIdx.x;
  if (i < n) { a[i] = 0; b[i] = 0; }
}

__global__ void count_kernel(const int* __restrict__ ei, int* __restrict__ degi,
                             int* __restrict__ cnt) {
  int e = blockIdx.x * 256 + threadIdx.x;
  if (e >= Ee) return;
  int r = ei[e], c = ei[Ee + e];
  atomicAdd(&degi[r], 1);
  atomicAdd(&degi[c], 1);
  atomicAdd(&cnt[c], 1);
}

__global__ void dis_kernel(const int* __restrict__ degi, float* __restrict__ dis) {
  int i = blockIdx.x * 256 + threadIdx.x;
  if (i < Nn) dis[i] = rsqrtf((float)degi[i] + 1.0f);
}

__global__ void scan_partial(const int* __restrict__ cnt, int* __restrict__ bsum) {
  __shared__ int s[256];
  int i = blockIdx.x * 256 + threadIdx.x;
  s[threadIdx.x] = (i < Nn) ? cnt[i] : 0;
  __syncthreads();
  for (int off = 128; off > 0; off >>= 1) {
    if (threadIdx.x < off) s[threadIdx.x] += s[threadIdx.x + off];
    __syncthreads();
  }
  if (threadIdx.x == 0) bsum[blockIdx.x] = s[0];
}

__global__ void scan_bsums(const int* __restrict__ bsum, int* __restrict__ bpre, int nb) {
  __shared__ int s[512];
  int t = threadIdx.x;
  s[t] = (t < nb) ? bsum[t] : 0;
  __syncthreads();
  for (int off = 1; off < 512; off <<= 1) {
    int u = (t >= off) ? s[t - off] : 0;
    __syncthreads();
    s[t] += u;
    __syncthreads();
  }
  if (t < nb) bpre[t] = (t == 0) ? 0 : s[t - 1];
}

__global__ void scan_final(const int* __restrict__ cnt, const int* __restrict__ bpre,
                           int* __restrict__ rowptr, int* __restrict__ cursor) {
  __shared__ int s[256];
  int t = threadIdx.x;
  int i = blockIdx.x * 256 + t;
  int v = (i < Nn) ? cnt[i] : 0;
  s[t] = v;
  __syncthreads();
  for (int off = 1; off < 256; off <<= 1) {
    int u = (t >= off) ? s[t - off] : 0;
    __syncthreads();
    s[t] += u;
    __syncthreads();
  }
  int excl = s[t] - v;
  int base = bpre[blockIdx.x];
  if (i < Nn) { rowptr[i] = base + excl; cursor[i] = base + excl; }
  if (i == Nn - 1) rowptr[Nn] = base + excl + v;
}

__global__ void fill_kernel(const int* __restrict__ ei, const float* __restrict__ dis,
                            int* __restrict__ cursor, int* __restrict__ csr_src,
                            float* __restrict__ csr_w) {
  int e = blockIdx.x * 256 + threadIdx.x;
  if (e >= Ee) return;
  int r = ei[e], c = ei[Ee + e];
  int p = atomicAdd(&cursor[c], 1);
  csr_src[p] = r;
  csr_w[p] = dis[r] * dis[c];
}

// Pack GRU weights into fragment-major split-bf16:
// B[kc:8][fid:24][g][c16][j], fid = gate*8+f; k = kc*32+g*8+j, col c=(fid&7)*16+c16,
// weight row = gate*128 + c. kc<4 -> Wih, kc>=4 -> Whh.
__global__ void pack_kernel(const float* __restrict__ Wih, const float* __restrict__ Whh,
                            ushort* __restrict__ Bhi, ushort* __restrict__ Blo) {
  int t = blockIdx.x * 256 + threadIdx.x;  // 8*24*4*16 = 12288 threads
  if (t >= 8 * 24 * 4 * 16) return;
  int c16 = t & 15;
  int g = (t >> 4) & 3;
  int fid = (t >> 6) % 24;
  int kc = t / (24 * 64);
  int gate = fid >> 3, f = fid & 7;
  int c = f * 16 + c16;
  int wrow = gate * 128 + c;
  size_t base = (size_t)t * 8;
#pragma unroll
  for (int j = 0; j < 8; ++j) {
    int k = kc * 32 + g * 8 + j;
    float v = (k < 128) ? Wih[wrow * 128 + k] : Whh[wrow * 128 + (k - 128)];
    ushort hi = f2bf(v);
    Bhi[base + j] = hi;
    Blo[base + j] = f2bf(v - bf2f(hi));
  }
}

// Pack MLP W1 (64 x 128): Bm[kc][cf][g][c16][j], c = cf*16+c16, k = kc*32+g*8+j
__global__ void pack_mlp(const float* __restrict__ Wm1, ushort* __restrict__ Bh,
                         ushort* __restrict__ Bl) {
  int t = blockIdx.x * 256 + threadIdx.x;  // 4*4*4*16 = 1024
  if (t >= 1024) return;
  int c16 = t & 15;
  int g = (t >> 4) & 3;
  int cf = (t >> 6) & 3;
  int kc = t >> 8;
  int c = cf * 16 + c16;
  size_t base = (size_t)t * 8;
#pragma unroll
  for (int j = 0; j < 8; ++j) {
    int k = kc * 32 + g * 8 + j;
    float v = Wm1[c * 128 + k];
    ushort hi = f2bf(v);
    Bh[base + j] = hi;
    Bl[base + j] = f2bf(v - bf2f(hi));
  }
}

// h0: leaky_relu(X @ W0^T + b0), row-major fp32.
__global__ void h0_kernel(const float* __restrict__ X, const float* __restrict__ W0,
                          const float* __restrict__ b0, float* __restrict__ H0) {
  int t = blockIdx.x * 256 + threadIdx.x;
  int i = t >> 7, d = t & 127;
  if (i >= NP) return;
  float v = 0.0f;
  if (i < Nn) {
    float x0 = X[i * 3 + 0], x1 = X[i * 3 + 1], x2 = X[i * 3 + 2];
    v = fmaf(x0, W0[d * 3 + 0], fmaf(x1, W0[d * 3 + 1], fmaf(x2, W0[d * 3 + 2], b0[d])));
    v = v > 0.0f ? v : 0.01f * v;
  }
  H0[(size_t)i * Hh + d] = v;
}

// ---- Fused GCN-aggregate + GRU cell (row-major fp32 state) ----
// Block = 64 nodes (one tile), 512 threads = 8 waves. LDS 32KB time-shared
// => up to 4 blocks/CU (32 waves/CU).
// P1: gather -> S (slots 0..3).  sync
// P2: MFMA kc0..3 from S.        sync
// P3: own rows -> S (overwrite). sync
// P4: MFMA kc4..7 from S; epilogue (hold from S); write Hn row-major.

#define DO_GATE8(GB, ACC)                                                             \
  {                                                                                   \
    size_t boff = (((size_t)(kc * 24 + (GB)*8 + wave) * 4 + g) * 16 + c16) * 8;       \
    bf16x8 bH = *(const bf16x8*)(Bhi + boff);                                         \
    bf16x8 bL = *(const bf16x8*)(Blo + boff);                                         \
    _Pragma("unroll") for (int rf = 0; rf < 4; ++rf)                                  \
        ACC[rf] = __builtin_amdgcn_mfma_f32_16x16x32_bf16(aH[rf], bH, ACC[rf], 0, 0, 0); \
    _Pragma("unroll") for (int rf = 0; rf < 4; ++rf)                                  \
        ACC[rf] = __builtin_amdgcn_mfma_f32_16x16x32_bf16(aH[rf], bL, ACC[rf], 0, 0, 0); \
    _Pragma("unroll") for (int rf = 0; rf < 4; ++rf)                                  \
        ACC[rf] = __builtin_amdgcn_mfma_f32_16x16x32_bf16(aL[rf], bH, ACC[rf], 0, 0, 0); \
  }

__global__ __launch_bounds__(512, 4) void gcn_gru_fused(
    const float* __restrict__ Hp, float* __restrict__ Hn,
    const int* __restrict__ csr_src, const float* __restrict__ csr_w,
    const int* __restrict__ rowptr,
    const ushort* __restrict__ Bhi, const ushort* __restrict__ Blo,
    const float* __restrict__ bih, const float* __restrict__ bhh) {
  __shared__ ushort SH[8192];
  __shared__ ushort SL[8192];
  const int tid = threadIdx.x;
  const int tile = blockIdx.x;
  const long rowbase = (long)tile * 64;

  const int local = tid >> 3;  // 0..63 node
  const int sub = tid & 7;
  const int eg = sub & 1;      // edge group
  const int dg = sub >> 1;     // dim group (32 dims)
  const int rf0 = local >> 4, c16l = local & 15;
  const int lwr = dg * 2048 + rf0 * 512 + c16l * 8;

  // ---- Phase 1: gather (edge-split x 2, unroll-2) -> S slots 0..3 ----
  {
    const long node = rowbase + local;
    float acc[32];
#pragma unroll
    for (int m = 0; m < 32; ++m) acc[m] = 0.0f;
    if (node < Nn) {
      const int eEnd = rowptr[node + 1];
      int e = rowptr[node] + eg;
      const float* hb = Hp + dg * 32;
      for (; e + 2 < eEnd; e += 4) {
        const int s0 = csr_src[e], s1 = csr_src[e + 2];
        const float w0 = csr_w[e], w1 = csr_w[e + 2];
        const float* p0 = hb + (size_t)s0 * Hh;
        const float* p1 = hb + (size_t)s1 * Hh;
        f32x4 va[8], vb[8];
#pragma unroll
        for (int q = 0; q < 8; ++q) va[q] = *(const f32x4*)(p0 + q * 4);
#pragma unroll
        for (int q = 0; q < 8; ++q) vb[q] = *(const f32x4*)(p1 + q * 4);
#pragma unroll
        for (int q = 0; q < 8; ++q)
#pragma unroll
          for (int m = 0; m < 4; ++m)
            acc[q * 4 + m] = fmaf(w1, vb[q][m], fmaf(w0, va[q][m], acc[q * 4 + m]));
      }
      if (e < eEnd) {
        const int s0 = csr_src[e];
        const float w0 = csr_w[e];
        const float* p0 = hb + (size_t)s0 * Hh;
        f32x4 va[8];
#pragma unroll
        for (int q = 0; q < 8; ++q) va[q] = *(const f32x4*)(p0 + q * 4);
#pragma unroll
        for (int q = 0; q < 8; ++q)
#pragma unroll
          for (int m = 0; m < 4; ++m)
            acc[q * 4 + m] = fmaf(w0, va[q][m], acc[q * 4 + m]);
      }
    }
    // combine edge groups (eg pairs are adjacent lanes)
#pragma unroll
    for (int m = 0; m < 32; ++m) acc[m] += __shfl_xor(acc[m], 1);
    if (eg == 0) {
#pragma unroll
      for (int g2 = 0; g2 < 4; ++g2) {
        u16x8 vh, vl;
#pragma unroll
        for (int j = 0; j < 8; ++j) {
          float v = acc[g2 * 8 + j];
          ushort hb2 = f2bf(v);
          vh[j] = hb2;
          vl[j] = f2bf(v - bf2f(hb2));
        }
        const int o = swz(lwr + g2 * 128);
        *(u16x8*)(SH + o) = vh;
        *(u16x8*)(SL + o) = vl;
      }
    }
  }
  __syncthreads();

  // ---- Phase 2: MFMA kc0..3 (aggregate half) ----
  const int wave = tid >> 6, lane = tid & 63;
  const int g = lane >> 4, c16 = lane & 15;
  const int lbase = g * 128 + c16 * 8;

  f32x4 accR[4], accZ[4], accXN[4], accHN[4];
#pragma unroll
  for (int rf = 0; rf < 4; ++rf) {
    accR[rf] = (f32x4){0.f, 0.f, 0.f, 0.f};
    accZ[rf] = (f32x4){0.f, 0.f, 0.f, 0.f};
    accXN[rf] = (f32x4){0.f, 0.f, 0.f, 0.f};
    accHN[rf] = (f32x4){0.f, 0.f, 0.f, 0.f};
  }

#pragma unroll
  for (int kc = 0; kc < 4; ++kc) {
    bf16x8 aH[4], aL[4];
#pragma unroll
    for (int rf = 0; rf < 4; ++rf) {
      int off = swz(kc * 2048 + rf * 512 + lbase);
      aH[rf] = *(const bf16x8*)(SH + off);
      aL[rf] = *(const bf16x8*)(SL + off);
    }
    DO_GATE8(0, accR)
    DO_GATE8(1, accZ)
    DO_GATE8(2, accXN)
  }
  __syncthreads();

  // ---- Phase 3: stage own rows into same LDS (slots 0..3) ----
  {
    const float* p = Hp + (size_t)(rowbase + local) * Hh + dg * 32 + eg * 16;
#pragma unroll
    for (int h2 = 0; h2 < 2; ++h2) {
      f32x4 v0 = *(const f32x4*)(p + h2 * 8);
      f32x4 v1 = *(const f32x4*)(p + h2 * 8 + 4);
      u16x8 vh, vl;
#pragma unroll
      for (int m = 0; m < 4; ++m) {
        ushort hb0 = f2bf(v0[m]);
        vh[m] = hb0;
        vl[m] = f2bf(v0[m] - bf2f(hb0));
        ushort hb1 = f2bf(v1[m]);
        vh[4 + m] = hb1;
        vl[4 + m] = f2bf(v1[m] - bf2f(hb1));
      }
      const int g2 = eg * 2 + h2;
      const int o = swz(lwr + g2 * 128);
      *(u16x8*)(SH + o) = vh;
      *(u16x8*)(SL + o) = vl;
    }
  }
  __syncthreads();

  // ---- Phase 4: MFMA kc4..7 (h half) + epilogue ----
#pragma unroll
  for (int kc = 4; kc < 8; ++kc) {
    bf16x8 aH[4], aL[4];
#pragma unroll
    for (int rf = 0; rf < 4; ++rf) {
      int off = swz((kc - 4) * 2048 + rf * 512 + lbase);
      aH[rf] = *(const bf16x8*)(SH + off);
      aL[rf] = *(const bf16x8*)(SL + off);
    }
    DO_GATE8(0, accR)
    DO_GATE8(1, accZ)
    DO_GATE8(2, accHN)
  }

  {
    const int c = wave * 16 + c16;
    const float br = bih[c] + bhh[c];
    const float bz = bih[128 + c] + bhh[128 + c];
    const float bxn = bih[256 + c];
    const float bhn = bhh[256 + c];
    const int kcs = c >> 5;
    const int gs = (c >> 3) & 3;
    const int js = c & 7;
#pragma unroll
    for (int rf = 0; rf < 4; ++rf) {
#pragma unroll
      for (int reg = 0; reg < 4; ++reg) {
        const int lr = g * 4 + reg;  // local row within 16-block
        const int hoff = swz(kcs * 2048 + rf * 512 + gs * 128 + lr * 8 + js);
        float hold = bf2f(SH[hoff]) + bf2f(SL[hoff]);
        float rr = sigmoidf_(accR[rf][reg] + br);
        float zz = sigmoidf_(accZ[rf][reg] + bz);
        float nn = tanh_fast(accXN[rf][reg] + bxn + rr * (accHN[rf][reg] + bhn));
        Hn[(size_t)(rowbase + rf * 16 + lr) * Hh + c] = (1.0f - zz) * nn + zz * hold;
      }
    }
  }
}

// ---- Fused max(h1..h5) + MLP (LDS-staged, 1x reads) ----
// Block = 64 nodes, 256 threads = 4 waves; wave w owns cols [16w,16w+16).
__global__ __launch_bounds__(256, 4) void mlp_max_mfma(
    const float* __restrict__ H1, const float* __restrict__ H2,
    const float* __restrict__ H3, const float* __restrict__ H4,
    const float* __restrict__ H5,
    const ushort* __restrict__ Bh, const ushort* __restrict__ Bl,
    const float* __restrict__ bm1, const float* __restrict__ Wm2,
    const float* __restrict__ bm2, float* __restrict__ out) {
  __shared__ ushort AsH[8192];
  __shared__ ushort AsL[8192];
  __shared__ float red[4][64];
  const int tid = threadIdx.x;
  const long rowbase = (long)blockIdx.x * 64;

  // ---- Phase 1: cooperative max + fragment stage ----
  {
    const int local = tid >> 2, kc4 = tid & 3;
    const int rf0 = local >> 4, c16l = local & 15;
    const int lwr = kc4 * 2048 + rf0 * 512 + c16l * 8;
    size_t o = (size_t)(rowbase + local) * Hh + kc4 * 32;
    f32x4 mx[8];
#pragma unroll
    for (int q = 0; q < 8; ++q) mx[q] = *(const f32x4*)(H1 + o + q * 4);
    const float* arrs[4] = {H2, H3, H4, H5};
#pragma unroll
    for (int a = 0; a < 4; ++a) {
      const float* p = arrs[a] + o;
#pragma unroll
      for (int q = 0; q < 8; ++q) mx[q] = max4(mx[q], *(const f32x4*)(p + q * 4));
    }
#pragma unroll
    for (int g2 = 0; g2 < 4; ++g2) {
      u16x8 vh, vl;
#pragma unroll
      for (int m = 0; m < 4; ++m) {
        float v0 = mx[g2 * 2][m], v1 = mx[g2 * 2 + 1][m];
        ushort hb0 = f2bf(v0);
        vh[m] = hb0;
        vl[m] = f2bf(v0 - bf2f(hb0));
        ushort hb1 = f2bf(v1);
        vh[4 + m] = hb1;
        vl[4 + m] = f2bf(v1 - bf2f(hb1));
      }
      const int oo = swz(lwr + g2 * 128);
      *(u16x8*)(AsH + oo) = vh;
      *(u16x8*)(AsL + oo) = vl;
    }
  }
  __syncthreads();

  // ---- Phase 2: MFMA from LDS ----
  const int wave = tid >> 6, lane = tid & 63;
  const int g = lane >> 4, c16 = lane & 15;
  const int lbase = g * 128 + c16 * 8;

  f32x4 acc[4];
#pragma unroll
  for (int rf = 0; rf < 4; ++rf) acc[rf] = (f32x4){0.f, 0.f, 0.f, 0.f};

#pragma unroll
  for (int kc = 0; kc < 4; ++kc) {
    bf16x8 aH[4], aL[4];
#pragma unroll
    for (int rf = 0; rf < 4; ++rf) {
      int off = swz(kc * 2048 + rf * 512 + lbase);
      aH[rf] = *(const bf16x8*)(AsH + off);
      aL[rf] = *(const bf16x8*)(AsL + off);
    }
    size_t boff = (((size_t)(kc * 4 + wave) * 4 + g) * 16 + c16) * 8;
    bf16x8 bH = *(const bf16x8*)(Bh + boff);
    bf16x8 bL = *(const bf16x8*)(Bl + boff);
#pragma unroll
    for (int rf = 0; rf < 4; ++rf)
      acc[rf] = __builtin_amdgcn_mfma_f32_16x16x32_bf16(aH[rf], bH, acc[rf], 0, 0, 0);
#pragma unroll
    for (int rf = 0; rf < 4; ++rf)
      acc[rf] = __builtin_amdgcn_mfma_f32_16x16x32_bf16(aH[rf], bL, acc[rf], 0, 0, 0);
#pragma unroll
    for (int rf = 0; rf < 4; ++rf)
      acc[rf] = __builtin_amdgcn_mfma_f32_16x16x32_bf16(aL[rf], bH, acc[rf], 0, 0, 0);
  }

  const int c = wave * 16 + c16;
  const float b1 = bm1[c];
  const float w2 = Wm2[c];
#pragma unroll
  for (int rf = 0; rf < 4; ++rf) {
#pragma unroll
    for (int reg = 0; reg < 4; ++reg) {
      float v = acc[rf][reg] + b1;
      v = v > 0.f ? v : 0.01f * v;
      v *= w2;
#pragma unroll
      for (int off = 1; off < 16; off <<= 1) v += __shfl_xor(v, off);
      if (c16 == 0) red[wave][rf * 16 + g * 4 + reg] = v;
    }
  }
  __syncthreads();
  if (tid < 64) {
    long row = rowbase + tid;
    if (row < Nn)
      out[row] = red[0][tid] + red[1][tid] + red[2][tid] + red[3][tid] + bm2[0];
  }
}

extern "C" void kernel_launch(void* const* d_in, const int* in_sizes, int n_in,
                              void* d_out, int out_size, void* d_ws, size_t ws_size,
                              hipStream_t stream) {
  const float* X = (const float*)d_in[0];
  const int* ei = (const int*)d_in[1];
  const float* W0 = (const float*)d_in[2];
  const float* b0 = (const float*)d_in[3];
  const float* Wih = (const float*)d_in[4];
  const float* Whh = (const float*)d_in[5];
  const float* bih = (const float*)d_in[6];
  const float* bhh = (const float*)d_in[7];
  const float* Wm1 = (const float*)d_in[8];
  const float* bm1 = (const float*)d_in[9];
  const float* Wm2 = (const float*)d_in[10];
  const float* bm2 = (const float*)d_in[11];
  float* out = (float*)d_out;

  char* ws = (char*)d_ws;
  size_t off = 0;
  auto alloc = [&](size_t bytes) -> void* {
    void* p = ws + off;
    off = (off + bytes + 255) & ~(size_t)255;
    return p;
  };
  float* Hs[5];
  for (int i = 0; i < 5; ++i) Hs[i] = (float*)alloc((size_t)NP * Hh * 4);
  ushort* Bhi = (ushort*)alloc((size_t)8 * 24 * 4 * 16 * 8 * 2);
  ushort* Blo = (ushort*)alloc((size_t)8 * 24 * 4 * 16 * 8 * 2);
  ushort* Bmh = (ushort*)alloc((size_t)1024 * 8 * 2);
  ushort* Bml = (ushort*)alloc((size_t)1024 * 8 * 2);
  float* dis = (float*)alloc((size_t)Nn * 4);
  int* degi = (int*)alloc((size_t)Nn * 4);
  int* cnt = (int*)alloc((size_t)Nn * 4);
  int* rowptr = (int*)alloc((size_t)(Nn + 1) * 4);
  int* cursor = (int*)alloc((size_t)Nn * 4);
  int* bsum = (int*)alloc(512 * 4);
  int* bpre = (int*)alloc(512 * 4);
  int* csr_src = (int*)alloc((size_t)Ee * 4);
  float* csr_w = (float*)alloc((size_t)Ee * 4);
  (void)ws_size;
  (void)in_sizes;
  (void)n_in;
  (void)out_size;

  const int NB = (Nn + 255) / 256;  // 391
  const int EB = (Ee + 255) / 256;  // 2344

  zero_kernel<<<NB, 256, 0, stream>>>(degi, cnt, Nn);
  count_kernel<<<EB, 256, 0, stream>>>(ei, degi, cnt);
  dis_kernel<<<NB, 256, 0, stream>>>(degi, dis);
  scan_partial<<<NB, 256, 0, stream>>>(cnt, bsum);
  scan_bsums<<<1, 512, 0, stream>>>(bsum, bpre, NB);
  scan_final<<<NB, 256, 0, stream>>>(cnt, bpre, rowptr, cursor);
  fill_kernel<<<EB, 256, 0, stream>>>(ei, dis, cursor, csr_src, csr_w);
  pack_kernel<<<48, 256, 0, stream>>>(Wih, Whh, Bhi, Blo);
  pack_mlp<<<4, 256, 0, stream>>>(Wm1, Bmh, Bml);
  h0_kernel<<<(NP * Hh) / 256, 256, 0, stream>>>(X, W0, b0, Hs[0]);

  // iteration t: read Hs[(t-1)%5], write Hs[t%5]  (t=5 reuses slot 0; h0 is dead by then)
  for (int t = 1; t <= 5; ++t) {
    gcn_gru_fused<<<NT, 512, 0, stream>>>(Hs[(t - 1) % 5], Hs[t % 5], csr_src, csr_w,
                                          rowptr, Bhi, Blo, bih, bhh);
  }

  mlp_max_mfma<<<NT, 256, 0, stream>>>(Hs[1], Hs[2], Hs[3], Hs[4], Hs[0], Bmh, Bml,
                                       bm1, Wm2, bm2, out);
}

// Round 13
// 678.278 us; speedup vs baseline: 1.4869x; 1.1561x over previous
//
#include <hip/hip_runtime.h>

#define Nn 100000
#define Ee 600000
#define Hh 128
#define NP 100096  // padded node rows: multiple of 64
#define NT (NP / 64)  // 1564 tiles

typedef short bf16x8 __attribute__((ext_vector_type(8)));
typedef float f32x4 __attribute__((ext_vector_type(4)));
typedef unsigned short u16x8 __attribute__((ext_vector_type(8)));
typedef _Float16 f16x8 __attribute__((ext_vector_type(8)));

static __device__ __forceinline__ float sigmoidf_(float x) {
  return 1.0f / (1.0f + __expf(-x));
}
static __device__ __forceinline__ float tanh_fast(float x) {
  return 1.0f - 2.0f / (__expf(2.0f * x) + 1.0f);
}
// round-to-nearest-even fp32 -> bf16 bits
static __device__ __forceinline__ ushort f2bf(float v) {
  unsigned u = __float_as_uint(v);
  unsigned r = (u + 0x7fffu + ((u >> 16) & 1u)) >> 16;
  return (ushort)r;
}
static __device__ __forceinline__ float bf2f(ushort b) {
  return __uint_as_float(((unsigned)b) << 16);
}
// LDS fragment layout (ushort idx): [kc][rf:4][g:4][c16:16][j:8], bank-swizzled.
static __device__ __forceinline__ int swz(int u) {
  return u ^ (((u >> 11) & 3) << 4);
}

__global__ void zero_kernel(int* __restrict__ a, int* __restrict__ b, int n) {
  int i = blockIdx.x * 256 + threadIdx.x;
  if (i < n) { a[i] = 0; b[i] = 0; }
}

__global__ void count_kernel(const int* __restrict__ ei, int* __restrict__ degi,
                             int* __restrict__ cnt) {
  int e = blockIdx.x * 256 + threadIdx.x;
  if (e >= Ee) return;
  int r = ei[e], c = ei[Ee + e];
  atomicAdd(&degi[r], 1);
  atomicAdd(&degi[c], 1);
  atomicAdd(&cnt[c], 1);
}

__global__ void dis_kernel(const int* __restrict__ degi, float* __restrict__ dis) {
  int i = blockIdx.x * 256 + threadIdx.x;
  if (i < Nn) dis[i] = rsqrtf((float)degi[i] + 1.0f);
}

__global__ void scan_partial(const int* __restrict__ cnt, int* __restrict__ bsum) {
  __shared__ int s[256];
  int i = blockIdx.x * 256 + threadIdx.x;
  s[threadIdx.x] = (i < Nn) ? cnt[i] : 0;
  __syncthreads();
  for (int off = 128; off > 0; off >>= 1) {
    if (threadIdx.x < off) s[threadIdx.x] += s[threadIdx.x + off];
    __syncthreads();
  }
  if (threadIdx.x == 0) bsum[blockIdx.x] = s[0];
}

__global__ void scan_bsums(const int* __restrict__ bsum, int* __restrict__ bpre, int nb) {
  __shared__ int s[512];
  int t = threadIdx.x;
  s[t] = (t < nb) ? bsum[t] : 0;
  __syncthreads();
  for (int off = 1; off < 512; off <<= 1) {
    int u = (t >= off) ? s[t - off] : 0;
    __syncthreads();
    s[t] += u;
    __syncthreads();
  }
  if (t < nb) bpre[t] = (t == 0) ? 0 : s[t - 1];
}

__global__ void scan_final(const int* __restrict__ cnt, const int* __restrict__ bpre,
                           int* __restrict__ rowptr, int* __restrict__ cursor) {
  __shared__ int s[256];
  int t = threadIdx.x;
  int i = blockIdx.x * 256 + t;
  int v = (i < Nn) ? cnt[i] : 0;
  s[t] = v;
  __syncthreads();
  for (int off = 1; off < 256; off <<= 1) {
    int u = (t >= off) ? s[t - off] : 0;
    __syncthreads();
    s[t] += u;
    __syncthreads();
  }
  int excl = s[t] - v;
  int base = bpre[blockIdx.x];
  if (i < Nn) { rowptr[i] = base + excl; cursor[i] = base + excl; }
  if (i == Nn - 1) rowptr[Nn] = base + excl + v;
}

__global__ void fill_kernel(const int* __restrict__ ei, const float* __restrict__ dis,
                            int* __restrict__ cursor, int* __restrict__ csr_src,
                            float* __restrict__ csr_w) {
  int e = blockIdx.x * 256 + threadIdx.x;
  if (e >= Ee) return;
  int r = ei[e], c = ei[Ee + e];
  int p = atomicAdd(&cursor[c], 1);
  csr_src[p] = r;
  csr_w[p] = dis[r] * dis[c];
}

// Pack GRU weights into fragment-major split-bf16:
// B[kc:8][fid:24][g][c16][j], fid = gate*8+f; k = kc*32+g*8+j, col c=(fid&7)*16+c16,
// weight row = gate*128 + c. kc<4 -> Wih, kc>=4 -> Whh.
__global__ void pack_kernel(const float* __restrict__ Wih, const float* __restrict__ Whh,
                            ushort* __restrict__ Bhi, ushort* __restrict__ Blo) {
  int t = blockIdx.x * 256 + threadIdx.x;  // 8*24*4*16 = 12288 threads
  if (t >= 8 * 24 * 4 * 16) return;
  int c16 = t & 15;
  int g = (t >> 4) & 3;
  int fid = (t >> 6) % 24;
  int kc = t / (24 * 64);
  int gate = fid >> 3, f = fid & 7;
  int c = f * 16 + c16;
  int wrow = gate * 128 + c;
  size_t base = (size_t)t * 8;
#pragma unroll
  for (int j = 0; j < 8; ++j) {
    int k = kc * 32 + g * 8 + j;
    float v = (k < 128) ? Wih[wrow * 128 + k] : Whh[wrow * 128 + (k - 128)];
    ushort hi = f2bf(v);
    Bhi[base + j] = hi;
    Blo[base + j] = f2bf(v - bf2f(hi));
  }
}

// Pack MLP W1 (64 x 128): Bm[kc][cf][g][c16][j], c = cf*16+c16, k = kc*32+g*8+j
__global__ void pack_mlp(const float* __restrict__ Wm1, ushort* __restrict__ Bh,
                         ushort* __restrict__ Bl) {
  int t = blockIdx.x * 256 + threadIdx.x;  // 4*4*4*16 = 1024
  if (t >= 1024) return;
  int c16 = t & 15;
  int g = (t >> 4) & 3;
  int cf = (t >> 6) & 3;
  int kc = t >> 8;
  int c = cf * 16 + c16;
  size_t base = (size_t)t * 8;
#pragma unroll
  for (int j = 0; j < 8; ++j) {
    int k = kc * 32 + g * 8 + j;
    float v = Wm1[c * 128 + k];
    ushort hi = f2bf(v);
    Bh[base + j] = hi;
    Bl[base + j] = f2bf(v - bf2f(hi));
  }
}

// h0: leaky_relu(X @ W0^T + b0), row-major fp16.
__global__ void h0_kernel(const float* __restrict__ X, const float* __restrict__ W0,
                          const float* __restrict__ b0, _Float16* __restrict__ H0) {
  int t = blockIdx.x * 256 + threadIdx.x;
  int i = t >> 7, d = t & 127;
  if (i >= NP) return;
  float v = 0.0f;
  if (i < Nn) {
    float x0 = X[i * 3 + 0], x1 = X[i * 3 + 1], x2 = X[i * 3 + 2];
    v = fmaf(x0, W0[d * 3 + 0], fmaf(x1, W0[d * 3 + 1], fmaf(x2, W0[d * 3 + 2], b0[d])));
    v = v > 0.0f ? v : 0.01f * v;
  }
  H0[(size_t)i * Hh + d] = (_Float16)v;
}

// ---- Fused GCN-aggregate + GRU cell (row-major fp16 state) ----
// Block = 64 nodes (one tile), 512 threads = 8 waves. LDS 32KB time-shared.
// P1: gather -> S.  P2: MFMA kc0..3.  P3: own rows -> S.  P4: MFMA kc4..7 + epilogue.
// 4-pass split-bf16 MFMA (hi*hi + hi*lo + lo*hi + lo*lo).

#define DO_GATE8(GB, ACC)                                                             \
  {                                                                                   \
    size_t boff = (((size_t)(kc * 24 + (GB)*8 + wave) * 4 + g) * 16 + c16) * 8;       \
    bf16x8 bH = *(const bf16x8*)(Bhi + boff);                                         \
    bf16x8 bL = *(const bf16x8*)(Blo + boff);                                         \
    _Pragma("unroll") for (int rf = 0; rf < 4; ++rf)                                  \
        ACC[rf] = __builtin_amdgcn_mfma_f32_16x16x32_bf16(aH[rf], bH, ACC[rf], 0, 0, 0); \
    _Pragma("unroll") for (int rf = 0; rf < 4; ++rf)                                  \
        ACC[rf] = __builtin_amdgcn_mfma_f32_16x16x32_bf16(aH[rf], bL, ACC[rf], 0, 0, 0); \
    _Pragma("unroll") for (int rf = 0; rf < 4; ++rf)                                  \
        ACC[rf] = __builtin_amdgcn_mfma_f32_16x16x32_bf16(aL[rf], bH, ACC[rf], 0, 0, 0); \
    _Pragma("unroll") for (int rf = 0; rf < 4; ++rf)                                  \
        ACC[rf] = __builtin_amdgcn_mfma_f32_16x16x32_bf16(aL[rf], bL, ACC[rf], 0, 0, 0); \
  }

__global__ __launch_bounds__(512, 4) void gcn_gru_fused(
    const _Float16* __restrict__ Hp, _Float16* __restrict__ Hn,
    const int* __restrict__ csr_src, const float* __restrict__ csr_w,
    const int* __restrict__ rowptr,
    const ushort* __restrict__ Bhi, const ushort* __restrict__ Blo,
    const float* __restrict__ bih, const float* __restrict__ bhh) {
  __shared__ ushort SH[8192];
  __shared__ ushort SL[8192];
  const int tid = threadIdx.x;
  const int tile = blockIdx.x;
  const long rowbase = (long)tile * 64;

  const int local = tid >> 3;  // 0..63 node
  const int sub = tid & 7;
  const int eg = sub & 1;      // edge group
  const int dg = sub >> 1;     // dim group (32 dims)
  const int rf0 = local >> 4, c16l = local & 15;
  const int lwr = dg * 2048 + rf0 * 512 + c16l * 8;

  // ---- Phase 1: gather (edge-split x 2, unroll-2) -> S ----
  {
    const long node = rowbase + local;
    float acc[32];
#pragma unroll
    for (int m = 0; m < 32; ++m) acc[m] = 0.0f;
    if (node < Nn) {
      const int eEnd = rowptr[node + 1];
      int e = rowptr[node] + eg;
      const _Float16* hb = Hp + dg * 32;
      for (; e + 2 < eEnd; e += 4) {
        const int s0 = csr_src[e], s1 = csr_src[e + 2];
        const float w0 = csr_w[e], w1 = csr_w[e + 2];
        const f16x8* p0 = (const f16x8*)(hb + (size_t)s0 * Hh);
        const f16x8* p1 = (const f16x8*)(hb + (size_t)s1 * Hh);
        f16x8 va[4], vb[4];
#pragma unroll
        for (int q = 0; q < 4; ++q) va[q] = p0[q];
#pragma unroll
        for (int q = 0; q < 4; ++q) vb[q] = p1[q];
#pragma unroll
        for (int q = 0; q < 4; ++q)
#pragma unroll
          for (int m = 0; m < 8; ++m)
            acc[q * 8 + m] =
                fmaf(w1, (float)vb[q][m], fmaf(w0, (float)va[q][m], acc[q * 8 + m]));
      }
      if (e < eEnd) {
        const int s0 = csr_src[e];
        const float w0 = csr_w[e];
        const f16x8* p0 = (const f16x8*)(hb + (size_t)s0 * Hh);
        f16x8 va[4];
#pragma unroll
        for (int q = 0; q < 4; ++q) va[q] = p0[q];
#pragma unroll
        for (int q = 0; q < 4; ++q)
#pragma unroll
          for (int m = 0; m < 8; ++m)
            acc[q * 8 + m] = fmaf(w0, (float)va[q][m], acc[q * 8 + m]);
      }
    }
    // combine edge groups (eg pairs are adjacent lanes)
#pragma unroll
    for (int m = 0; m < 32; ++m) acc[m] += __shfl_xor(acc[m], 1);
    if (eg == 0) {
#pragma unroll
      for (int g2 = 0; g2 < 4; ++g2) {
        u16x8 vh, vl;
#pragma unroll
        for (int j = 0; j < 8; ++j) {
          float v = acc[g2 * 8 + j];
          ushort hb2 = f2bf(v);
          vh[j] = hb2;
          vl[j] = f2bf(v - bf2f(hb2));
        }
        const int o = swz(lwr + g2 * 128);
        *(u16x8*)(SH + o) = vh;
        *(u16x8*)(SL + o) = vl;
      }
    }
  }
  __syncthreads();

  // ---- Phase 2: MFMA kc0..3 (aggregate half) ----
  const int wave = tid >> 6, lane = tid & 63;
  const int g = lane >> 4, c16 = lane & 15;
  const int lbase = g * 128 + c16 * 8;

  f32x4 accR[4], accZ[4], accXN[4], accHN[4];
#pragma unroll
  for (int rf = 0; rf < 4; ++rf) {
    accR[rf] = (f32x4){0.f, 0.f, 0.f, 0.f};
    accZ[rf] = (f32x4){0.f, 0.f, 0.f, 0.f};
    accXN[rf] = (f32x4){0.f, 0.f, 0.f, 0.f};
    accHN[rf] = (f32x4){0.f, 0.f, 0.f, 0.f};
  }

#pragma unroll
  for (int kc = 0; kc < 4; ++kc) {
    bf16x8 aH[4], aL[4];
#pragma unroll
    for (int rf = 0; rf < 4; ++rf) {
      int off = swz(kc * 2048 + rf * 512 + lbase);
      aH[rf] = *(const bf16x8*)(SH + off);
      aL[rf] = *(const bf16x8*)(SL + off);
    }
    DO_GATE8(0, accR)
    DO_GATE8(1, accZ)
    DO_GATE8(2, accXN)
  }
  __syncthreads();

  // ---- Phase 3: stage own rows (fp16 -> split-bf16, exact) ----
  {
    const _Float16* p = Hp + (size_t)(rowbase + local) * Hh + dg * 32 + eg * 16;
    f16x8 v0 = *(const f16x8*)p;
    f16x8 v1 = *(const f16x8*)(p + 8);
#pragma unroll
    for (int h2 = 0; h2 < 2; ++h2) {
      u16x8 vh, vl;
#pragma unroll
      for (int m = 0; m < 8; ++m) {
        float v = (h2 == 0) ? (float)v0[m] : (float)v1[m];
        ushort hb0 = f2bf(v);
        vh[m] = hb0;
        vl[m] = f2bf(v - bf2f(hb0));
      }
      const int g2 = eg * 2 + h2;
      const int o = swz(lwr + g2 * 128);
      *(u16x8*)(SH + o) = vh;
      *(u16x8*)(SL + o) = vl;
    }
  }
  __syncthreads();

  // ---- Phase 4: MFMA kc4..7 (h half) + epilogue ----
#pragma unroll
  for (int kc = 4; kc < 8; ++kc) {
    bf16x8 aH[4], aL[4];
#pragma unroll
    for (int rf = 0; rf < 4; ++rf) {
      int off = swz((kc - 4) * 2048 + rf * 512 + lbase);
      aH[rf] = *(const bf16x8*)(SH + off);
      aL[rf] = *(const bf16x8*)(SL + off);
    }
    DO_GATE8(0, accR)
    DO_GATE8(1, accZ)
    DO_GATE8(2, accHN)
  }

  {
    const int c = wave * 16 + c16;
    const float br = bih[c] + bhh[c];
    const float bz = bih[128 + c] + bhh[128 + c];
    const float bxn = bih[256 + c];
    const float bhn = bhh[256 + c];
    const int kcs = c >> 5;
    const int gs = (c >> 3) & 3;
    const int js = c & 7;
#pragma unroll
    for (int rf = 0; rf < 4; ++rf) {
#pragma unroll
      for (int reg = 0; reg < 4; ++reg) {
        const int lr = g * 4 + reg;  // local row within 16-block
        const int hoff = swz(kcs * 2048 + rf * 512 + gs * 128 + lr * 8 + js);
        float hold = bf2f(SH[hoff]) + bf2f(SL[hoff]);
        float rr = sigmoidf_(accR[rf][reg] + br);
        float zz = sigmoidf_(accZ[rf][reg] + bz);
        float nn = tanh_fast(accXN[rf][reg] + bxn + rr * (accHN[rf][reg] + bhn));
        Hn[(size_t)(rowbase + rf * 16 + lr) * Hh + c] =
            (_Float16)((1.0f - zz) * nn + zz * hold);
      }
    }
  }
}

// ---- Fused max(h1..h5) + MLP (LDS-staged, 1x fp16 reads) ----
__global__ __launch_bounds__(256, 4) void mlp_max_mfma(
    const _Float16* __restrict__ H1, const _Float16* __restrict__ H2,
    const _Float16* __restrict__ H3, const _Float16* __restrict__ H4,
    const _Float16* __restrict__ H5,
    const ushort* __restrict__ Bh, const ushort* __restrict__ Bl,
    const float* __restrict__ bm1, const float* __restrict__ Wm2,
    const float* __restrict__ bm2, float* __restrict__ out) {
  __shared__ ushort AsH[8192];
  __shared__ ushort AsL[8192];
  __shared__ float red[4][64];
  const int tid = threadIdx.x;
  const long rowbase = (long)blockIdx.x * 64;

  // ---- Phase 1: cooperative max + fragment stage ----
  {
    const int local = tid >> 2, kc4 = tid & 3;
    const int rf0 = local >> 4, c16l = local & 15;
    const int lwr = kc4 * 2048 + rf0 * 512 + c16l * 8;
    size_t o = (size_t)(rowbase + local) * Hh + kc4 * 32;
    float mx[32];
    {
      const f16x8* p = (const f16x8*)(H1 + o);
#pragma unroll
      for (int q = 0; q < 4; ++q) {
        f16x8 v = p[q];
#pragma unroll
        for (int m = 0; m < 8; ++m) mx[q * 8 + m] = (float)v[m];
      }
    }
    const _Float16* arrs[4] = {H2, H3, H4, H5};
#pragma unroll
    for (int a = 0; a < 4; ++a) {
      const f16x8* p = (const f16x8*)(arrs[a] + o);
#pragma unroll
      for (int q = 0; q < 4; ++q) {
        f16x8 v = p[q];
#pragma unroll
        for (int m = 0; m < 8; ++m) mx[q * 8 + m] = fmaxf(mx[q * 8 + m], (float)v[m]);
      }
    }
#pragma unroll
    for (int g2 = 0; g2 < 4; ++g2) {
      u16x8 vh, vl;
#pragma unroll
      for (int j = 0; j < 8; ++j) {
        float v = mx[g2 * 8 + j];
        ushort hb0 = f2bf(v);
        vh[j] = hb0;
        vl[j] = f2bf(v - bf2f(hb0));
      }
      const int oo = swz(lwr + g2 * 128);
      *(u16x8*)(AsH + oo) = vh;
      *(u16x8*)(AsL + oo) = vl;
    }
  }
  __syncthreads();

  // ---- Phase 2: MFMA from LDS (4-pass) ----
  const int wave = tid >> 6, lane = tid & 63;
  const int g = lane >> 4, c16 = lane & 15;
  const int lbase = g * 128 + c16 * 8;

  f32x4 acc[4];
#pragma unroll
  for (int rf = 0; rf < 4; ++rf) acc[rf] = (f32x4){0.f, 0.f, 0.f, 0.f};

#pragma unroll
  for (int kc = 0; kc < 4; ++kc) {
    bf16x8 aH[4], aL[4];
#pragma unroll
    for (int rf = 0; rf < 4; ++rf) {
      int off = swz(kc * 2048 + rf * 512 + lbase);
      aH[rf] = *(const bf16x8*)(AsH + off);
      aL[rf] = *(const bf16x8*)(AsL + off);
    }
    size_t boff = (((size_t)(kc * 4 + wave) * 4 + g) * 16 + c16) * 8;
    bf16x8 bH = *(const bf16x8*)(Bh + boff);
    bf16x8 bL = *(const bf16x8*)(Bl + boff);
#pragma unroll
    for (int rf = 0; rf < 4; ++rf)
      acc[rf] = __builtin_amdgcn_mfma_f32_16x16x32_bf16(aH[rf], bH, acc[rf], 0, 0, 0);
#pragma unroll
    for (int rf = 0; rf < 4; ++rf)
      acc[rf] = __builtin_amdgcn_mfma_f32_16x16x32_bf16(aH[rf], bL, acc[rf], 0, 0, 0);
#pragma unroll
    for (int rf = 0; rf < 4; ++rf)
      acc[rf] = __builtin_amdgcn_mfma_f32_16x16x32_bf16(aL[rf], bH, acc[rf], 0, 0, 0);
#pragma unroll
    for (int rf = 0; rf < 4; ++rf)
      acc[rf] = __builtin_amdgcn_mfma_f32_16x16x32_bf16(aL[rf], bL, acc[rf], 0, 0, 0);
  }

  const int c = wave * 16 + c16;
  const float b1 = bm1[c];
  const float w2 = Wm2[c];
#pragma unroll
  for (int rf = 0; rf < 4; ++rf) {
#pragma unroll
    for (int reg = 0; reg < 4; ++reg) {
      float v = acc[rf][reg] + b1;
      v = v > 0.f ? v : 0.01f * v;
      v *= w2;
#pragma unroll
      for (int off = 1; off < 16; off <<= 1) v += __shfl_xor(v, off);
      if (c16 == 0) red[wave][rf * 16 + g * 4 + reg] = v;
    }
  }
  __syncthreads();
  if (tid < 64) {
    long row = rowbase + tid;
    if (row < Nn)
      out[row] = red[0][tid] + red[1][tid] + red[2][tid] + red[3][tid] + bm2[0];
  }
}

extern "C" void kernel_launch(void* const* d_in, const int* in_sizes, int n_in,
                              void* d_out, int out_size, void* d_ws, size_t ws_size,
                              hipStream_t stream) {
  const float* X = (const float*)d_in[0];
  const int* ei = (const int*)d_in[1];
  const float* W0 = (const float*)d_in[2];
  const float* b0 = (const float*)d_in[3];
  const float* Wih = (const float*)d_in[4];
  const float* Whh = (const float*)d_in[5];
  const float* bih = (const float*)d_in[6];
  const float* bhh = (const float*)d_in[7];
  const float* Wm1 = (const float*)d_in[8];
  const float* bm1 = (const float*)d_in[9];
  const float* Wm2 = (const float*)d_in[10];
  const float* bm2 = (const float*)d_in[11];
  float* out = (float*)d_out;

  char* ws = (char*)d_ws;
  size_t off = 0;
  auto alloc = [&](size_t bytes) -> void* {
    void* p = ws + off;
    off = (off + bytes + 255) & ~(size_t)255;
    return p;
  };
  _Float16* Hs[5];
  for (int i = 0; i < 5; ++i) Hs[i] = (_Float16*)alloc((size_t)NP * Hh * 2);
  ushort* Bhi = (ushort*)alloc((size_t)8 * 24 * 4 * 16 * 8 * 2);
  ushort* Blo = (ushort*)alloc((size_t)8 * 24 * 4 * 16 * 8 * 2);
  ushort* Bmh = (ushort*)alloc((size_t)1024 * 8 * 2);
  ushort* Bml = (ushort*)alloc((size_t)1024 * 8 * 2);
  float* dis = (float*)alloc((size_t)Nn * 4);
  int* degi = (int*)alloc((size_t)Nn * 4);
  int* cnt = (int*)alloc((size_t)Nn * 4);
  int* rowptr = (int*)alloc((size_t)(Nn + 1) * 4);
  int* cursor = (int*)alloc((size_t)Nn * 4);
  int* bsum = (int*)alloc(512 * 4);
  int* bpre = (int*)alloc(512 * 4);
  int* csr_src = (int*)alloc((size_t)Ee * 4);
  float* csr_w = (float*)alloc((size_t)Ee * 4);
  (void)ws_size;
  (void)in_sizes;
  (void)n_in;
  (void)out_size;

  const int NB = (Nn + 255) / 256;  // 391
  const int EB = (Ee + 255) / 256;  // 2344

  zero_kernel<<<NB, 256, 0, stream>>>(degi, cnt, Nn);
  count_kernel<<<EB, 256, 0, stream>>>(ei, degi, cnt);
  dis_kernel<<<NB, 256, 0, stream>>>(degi, dis);
  scan_partial<<<NB, 256, 0, stream>>>(cnt, bsum);
  scan_bsums<<<1, 512, 0, stream>>>(bsum, bpre, NB);
  scan_final<<<NB, 256, 0, stream>>>(cnt, bpre, rowptr, cursor);
  fill_kernel<<<EB, 256, 0, stream>>>(ei, dis, cursor, csr_src, csr_w);
  pack_kernel<<<48, 256, 0, stream>>>(Wih, Whh, Bhi, Blo);
  pack_mlp<<<4, 256, 0, stream>>>(Wm1, Bmh, Bml);
  h0_kernel<<<(NP * Hh) / 256, 256, 0, stream>>>(X, W0, b0, Hs[0]);

  // iteration t: read Hs[(t-1)%5], write Hs[t%5]  (t=5 reuses slot 0; h0 is dead by then)
  for (int t = 1; t <= 5; ++t) {
    gcn_gru_fused<<<NT, 512, 0, stream>>>(Hs[(t - 1) % 5], Hs[t % 5], csr_src, csr_w,
                                          rowptr, Bhi, Blo, bih, bhh);
  }

  mlp_max_mfma<<<NT, 256, 0, stream>>>(Hs[1], Hs[2], Hs[3], Hs[4], Hs[0], Bmh, Bml,
                                       bm1, Wm2, bm2, out);
}

// Round 14
// 617.655 us; speedup vs baseline: 1.6328x; 1.0982x over previous
//
#include <hip/hip_runtime.h>

#define Nn 100000
#define Ee 600000
#define Hh 128
#define NP 100096  // padded node rows: multiple of 64
#define NT (NP / 64)  // 1564 tiles

typedef float f32x4 __attribute__((ext_vector_type(4)));
typedef unsigned short u16x8 __attribute__((ext_vector_type(8)));
typedef _Float16 f16x8 __attribute__((ext_vector_type(8)));

static __device__ __forceinline__ float sigmoidf_(float x) {
  return 1.0f / (1.0f + __expf(-x));
}
static __device__ __forceinline__ float tanh_fast(float x) {
  return 1.0f - 2.0f / (__expf(2.0f * x) + 1.0f);
}
// LDS fragment layout (ushort idx): [kc][rf:4][g:4][c16:16][j:8], bank-swizzled.
static __device__ __forceinline__ int swz(int u) {
  return u ^ (((u >> 11) & 3) << 4);
}

__global__ void zero_kernel(int* __restrict__ a, int* __restrict__ b, int n) {
  int i = blockIdx.x * 256 + threadIdx.x;
  if (i < n) { a[i] = 0; b[i] = 0; }
}

__global__ void count_kernel(const int* __restrict__ ei, int* __restrict__ degi,
                             int* __restrict__ cnt) {
  int e = blockIdx.x * 256 + threadIdx.x;
  if (e >= Ee) return;
  int r = ei[e], c = ei[Ee + e];
  atomicAdd(&degi[r], 1);
  atomicAdd(&degi[c], 1);
  atomicAdd(&cnt[c], 1);
}

__global__ void dis_kernel(const int* __restrict__ degi, float* __restrict__ dis) {
  int i = blockIdx.x * 256 + threadIdx.x;
  if (i < Nn) dis[i] = rsqrtf((float)degi[i] + 1.0f);
}

__global__ void scan_partial(const int* __restrict__ cnt, int* __restrict__ bsum) {
  __shared__ int s[256];
  int i = blockIdx.x * 256 + threadIdx.x;
  s[threadIdx.x] = (i < Nn) ? cnt[i] : 0;
  __syncthreads();
  for (int off = 128; off > 0; off >>= 1) {
    if (threadIdx.x < off) s[threadIdx.x] += s[threadIdx.x + off];
    __syncthreads();
  }
  if (threadIdx.x == 0) bsum[blockIdx.x] = s[0];
}

__global__ void scan_bsums(const int* __restrict__ bsum, int* __restrict__ bpre, int nb) {
  __shared__ int s[512];
  int t = threadIdx.x;
  s[t] = (t < nb) ? bsum[t] : 0;
  __syncthreads();
  for (int off = 1; off < 512; off <<= 1) {
    int u = (t >= off) ? s[t - off] : 0;
    __syncthreads();
    s[t] += u;
    __syncthreads();
  }
  if (t < nb) bpre[t] = (t == 0) ? 0 : s[t - 1];
}

__global__ void scan_final(const int* __restrict__ cnt, const int* __restrict__ bpre,
                           int* __restrict__ rowptr, int* __restrict__ cursor) {
  __shared__ int s[256];
  int t = threadIdx.x;
  int i = blockIdx.x * 256 + t;
  int v = (i < Nn) ? cnt[i] : 0;
  s[t] = v;
  __syncthreads();
  for (int off = 1; off < 256; off <<= 1) {
    int u = (t >= off) ? s[t - off] : 0;
    __syncthreads();
    s[t] += u;
    __syncthreads();
  }
  int excl = s[t] - v;
  int base = bpre[blockIdx.x];
  if (i < Nn) { rowptr[i] = base + excl; cursor[i] = base + excl; }
  if (i == Nn - 1) rowptr[Nn] = base + excl + v;
}

__global__ void fill_kernel(const int* __restrict__ ei, const float* __restrict__ dis,
                            int* __restrict__ cursor, int* __restrict__ csr_src,
                            float* __restrict__ csr_w) {
  int e = blockIdx.x * 256 + threadIdx.x;
  if (e >= Ee) return;
  int r = ei[e], c = ei[Ee + e];
  int p = atomicAdd(&cursor[c], 1);
  csr_src[p] = r;
  csr_w[p] = dis[r] * dis[c];
}

// Pack GRU weights into fragment-major split-fp16:
// B[kc:8][fid:24][g][c16][j], fid = gate*8+f; k = kc*32+g*8+j, col c=(fid&7)*16+c16,
// weight row = gate*128 + c. kc<4 -> Wih, kc>=4 -> Whh.
__global__ void pack_kernel(const float* __restrict__ Wih, const float* __restrict__ Whh,
                            _Float16* __restrict__ Bhi, _Float16* __restrict__ Blo) {
  int t = blockIdx.x * 256 + threadIdx.x;  // 8*24*4*16 = 12288 threads
  if (t >= 8 * 24 * 4 * 16) return;
  int c16 = t & 15;
  int g = (t >> 4) & 3;
  int fid = (t >> 6) % 24;
  int kc = t / (24 * 64);
  int gate = fid >> 3, f = fid & 7;
  int c = f * 16 + c16;
  int wrow = gate * 128 + c;
  size_t base = (size_t)t * 8;
#pragma unroll
  for (int j = 0; j < 8; ++j) {
    int k = kc * 32 + g * 8 + j;
    float v = (k < 128) ? Wih[wrow * 128 + k] : Whh[wrow * 128 + (k - 128)];
    _Float16 hi = (_Float16)v;
    Bhi[base + j] = hi;
    Blo[base + j] = (_Float16)(v - (float)hi);
  }
}

// Pack MLP W1 (64 x 128): Bm[kc][cf][g][c16][j], c = cf*16+c16, k = kc*32+g*8+j
__global__ void pack_mlp(const float* __restrict__ Wm1, _Float16* __restrict__ Bh,
                         _Float16* __restrict__ Bl) {
  int t = blockIdx.x * 256 + threadIdx.x;  // 4*4*4*16 = 1024
  if (t >= 1024) return;
  int c16 = t & 15;
  int g = (t >> 4) & 3;
  int cf = (t >> 6) & 3;
  int kc = t >> 8;
  int c = cf * 16 + c16;
  size_t base = (size_t)t * 8;
#pragma unroll
  for (int j = 0; j < 8; ++j) {
    int k = kc * 32 + g * 8 + j;
    float v = Wm1[c * 128 + k];
    _Float16 hi = (_Float16)v;
    Bh[base + j] = hi;
    Bl[base + j] = (_Float16)(v - (float)hi);
  }
}

// h0: leaky_relu(X @ W0^T + b0), row-major fp16.
__global__ void h0_kernel(const float* __restrict__ X, const float* __restrict__ W0,
                          const float* __restrict__ b0, _Float16* __restrict__ H0) {
  int t = blockIdx.x * 256 + threadIdx.x;
  int i = t >> 7, d = t & 127;
  if (i >= NP) return;
  float v = 0.0f;
  if (i < Nn) {
    float x0 = X[i * 3 + 0], x1 = X[i * 3 + 1], x2 = X[i * 3 + 2];
    v = fmaf(x0, W0[d * 3 + 0], fmaf(x1, W0[d * 3 + 1], fmaf(x2, W0[d * 3 + 2], b0[d])));
    v = v > 0.0f ? v : 0.01f * v;
  }
  H0[(size_t)i * Hh + d] = (_Float16)v;
}

// ---- Fused GCN-aggregate + GRU cell (row-major fp16 state, f16 MFMA) ----
// Block = 64 nodes (one tile), 512 threads = 8 waves. LDS 32KB time-shared.
// P1: gather -> split-fp16 SH/SL.  P2: MFMA kc0..3 (3 passes/gate).
// P3: own rows (raw fp16) -> SH.   P4: MFMA kc4..7 (2 passes/gate, A exact) + epilogue.

#define DO_GATE_AG(GB, ACC)                                                           \
  {                                                                                   \
    size_t boff = (((size_t)(kc * 24 + (GB)*8 + wave) * 4 + g) * 16 + c16) * 8;       \
    f16x8 bH = *(const f16x8*)(Bhi + boff);                                           \
    f16x8 bL = *(const f16x8*)(Blo + boff);                                           \
    _Pragma("unroll") for (int rf = 0; rf < 4; ++rf)                                  \
        ACC[rf] = __builtin_amdgcn_mfma_f32_16x16x32_f16(aH[rf], bH, ACC[rf], 0, 0, 0); \
    _Pragma("unroll") for (int rf = 0; rf < 4; ++rf)                                  \
        ACC[rf] = __builtin_amdgcn_mfma_f32_16x16x32_f16(aH[rf], bL, ACC[rf], 0, 0, 0); \
    _Pragma("unroll") for (int rf = 0; rf < 4; ++rf)                                  \
        ACC[rf] = __builtin_amdgcn_mfma_f32_16x16x32_f16(aL[rf], bH, ACC[rf], 0, 0, 0); \
  }

#define DO_GATE_H(GB, ACC)                                                            \
  {                                                                                   \
    size_t boff = (((size_t)(kc * 24 + (GB)*8 + wave) * 4 + g) * 16 + c16) * 8;       \
    f16x8 bH = *(const f16x8*)(Bhi + boff);                                           \
    f16x8 bL = *(const f16x8*)(Blo + boff);                                           \
    _Pragma("unroll") for (int rf = 0; rf < 4; ++rf)                                  \
        ACC[rf] = __builtin_amdgcn_mfma_f32_16x16x32_f16(aE[rf], bH, ACC[rf], 0, 0, 0); \
    _Pragma("unroll") for (int rf = 0; rf < 4; ++rf)                                  \
        ACC[rf] = __builtin_amdgcn_mfma_f32_16x16x32_f16(aE[rf], bL, ACC[rf], 0, 0, 0); \
  }

__global__ __launch_bounds__(512, 4) void gcn_gru_fused(
    const _Float16* __restrict__ Hp, _Float16* __restrict__ Hn,
    const int* __restrict__ csr_src, const float* __restrict__ csr_w,
    const int* __restrict__ rowptr,
    const _Float16* __restrict__ Bhi, const _Float16* __restrict__ Blo,
    const float* __restrict__ bih, const float* __restrict__ bhh) {
  __shared__ ushort SH[8192];
  __shared__ ushort SL[8192];
  const int tid = threadIdx.x;
  const int tile = blockIdx.x;
  const long rowbase = (long)tile * 64;

  const int local = tid >> 3;  // 0..63 node
  const int sub = tid & 7;
  const int eg = sub & 1;      // edge group
  const int dg = sub >> 1;     // dim group (32 dims)
  const int rf0 = local >> 4, c16l = local & 15;
  const int lwr = dg * 2048 + rf0 * 512 + c16l * 8;

  // ---- Phase 1: gather (edge-split x 2, unroll-2) -> split-fp16 S ----
  {
    const long node = rowbase + local;
    float acc[32];
#pragma unroll
    for (int m = 0; m < 32; ++m) acc[m] = 0.0f;
    if (node < Nn) {
      const int eEnd = rowptr[node + 1];
      int e = rowptr[node] + eg;
      const _Float16* hb = Hp + dg * 32;
      for (; e + 2 < eEnd; e += 4) {
        const int s0 = csr_src[e], s1 = csr_src[e + 2];
        const float w0 = csr_w[e], w1 = csr_w[e + 2];
        const f16x8* p0 = (const f16x8*)(hb + (size_t)s0 * Hh);
        const f16x8* p1 = (const f16x8*)(hb + (size_t)s1 * Hh);
        f16x8 va[4], vb[4];
#pragma unroll
        for (int q = 0; q < 4; ++q) va[q] = p0[q];
#pragma unroll
        for (int q = 0; q < 4; ++q) vb[q] = p1[q];
#pragma unroll
        for (int q = 0; q < 4; ++q)
#pragma unroll
          for (int m = 0; m < 8; ++m)
            acc[q * 8 + m] =
                fmaf(w1, (float)vb[q][m], fmaf(w0, (float)va[q][m], acc[q * 8 + m]));
      }
      if (e < eEnd) {
        const int s0 = csr_src[e];
        const float w0 = csr_w[e];
        const f16x8* p0 = (const f16x8*)(hb + (size_t)s0 * Hh);
        f16x8 va[4];
#pragma unroll
        for (int q = 0; q < 4; ++q) va[q] = p0[q];
#pragma unroll
        for (int q = 0; q < 4; ++q)
#pragma unroll
          for (int m = 0; m < 8; ++m)
            acc[q * 8 + m] = fmaf(w0, (float)va[q][m], acc[q * 8 + m]);
      }
    }
    // combine edge groups (eg pairs are adjacent lanes)
#pragma unroll
    for (int m = 0; m < 32; ++m) acc[m] += __shfl_xor(acc[m], 1);
    if (eg == 0) {
#pragma unroll
      for (int g2 = 0; g2 < 4; ++g2) {
        f16x8 vh, vl;
#pragma unroll
        for (int j = 0; j < 8; ++j) {
          float v = acc[g2 * 8 + j];
          _Float16 hi = (_Float16)v;
          vh[j] = hi;
          vl[j] = (_Float16)(v - (float)hi);
        }
        const int o = swz(lwr + g2 * 128);
        *(f16x8*)(SH + o) = vh;
        *(f16x8*)(SL + o) = vl;
      }
    }
  }
  __syncthreads();

  // ---- Phase 2: MFMA kc0..3 (aggregate half, 3 passes/gate) ----
  const int wave = tid >> 6, lane = tid & 63;
  const int g = lane >> 4, c16 = lane & 15;
  const int lbase = g * 128 + c16 * 8;

  f32x4 accR[4], accZ[4], accXN[4], accHN[4];
#pragma unroll
  for (int rf = 0; rf < 4; ++rf) {
    accR[rf] = (f32x4){0.f, 0.f, 0.f, 0.f};
    accZ[rf] = (f32x4){0.f, 0.f, 0.f, 0.f};
    accXN[rf] = (f32x4){0.f, 0.f, 0.f, 0.f};
    accHN[rf] = (f32x4){0.f, 0.f, 0.f, 0.f};
  }

#pragma unroll
  for (int kc = 0; kc < 4; ++kc) {
    f16x8 aH[4], aL[4];
#pragma unroll
    for (int rf = 0; rf < 4; ++rf) {
      int off = swz(kc * 2048 + rf * 512 + lbase);
      aH[rf] = *(const f16x8*)(SH + off);
      aL[rf] = *(const f16x8*)(SL + off);
    }
    DO_GATE_AG(0, accR)
    DO_GATE_AG(1, accZ)
    DO_GATE_AG(2, accXN)
  }
  __syncthreads();

  // ---- Phase 3: stage own rows (raw fp16 copy, no conversion) ----
  {
    const _Float16* p = Hp + (size_t)(rowbase + local) * Hh + dg * 32 + eg * 16;
    f16x8 v0 = *(const f16x8*)p;
    f16x8 v1 = *(const f16x8*)(p + 8);
    *(f16x8*)(SH + swz(lwr + (eg * 2 + 0) * 128)) = v0;
    *(f16x8*)(SH + swz(lwr + (eg * 2 + 1) * 128)) = v1;
  }
  __syncthreads();

  // ---- Phase 4: MFMA kc4..7 (h half, A exact fp16, 2 passes/gate) + epilogue ----
#pragma unroll
  for (int kc = 4; kc < 8; ++kc) {
    f16x8 aE[4];
#pragma unroll
    for (int rf = 0; rf < 4; ++rf) {
      int off = swz((kc - 4) * 2048 + rf * 512 + lbase);
      aE[rf] = *(const f16x8*)(SH + off);
    }
    DO_GATE_H(0, accR)
    DO_GATE_H(1, accZ)
    DO_GATE_H(2, accHN)
  }

  {
    const int c = wave * 16 + c16;
    const float br = bih[c] + bhh[c];
    const float bz = bih[128 + c] + bhh[128 + c];
    const float bxn = bih[256 + c];
    const float bhn = bhh[256 + c];
    const int kcs = c >> 5;
    const int gs = (c >> 3) & 3;
    const int js = c & 7;
#pragma unroll
    for (int rf = 0; rf < 4; ++rf) {
#pragma unroll
      for (int reg = 0; reg < 4; ++reg) {
        const int lr = g * 4 + reg;  // local row within 16-block
        const int hoff = swz(kcs * 2048 + rf * 512 + gs * 128 + lr * 8 + js);
        float hold = (float)*(const _Float16*)&SH[hoff];
        float rr = sigmoidf_(accR[rf][reg] + br);
        float zz = sigmoidf_(accZ[rf][reg] + bz);
        float nn = tanh_fast(accXN[rf][reg] + bxn + rr * (accHN[rf][reg] + bhn));
        Hn[(size_t)(rowbase + rf * 16 + lr) * Hh + c] =
            (_Float16)((1.0f - zz) * nn + zz * hold);
      }
    }
  }
}

// ---- Fused max(h1..h5) + MLP (LDS-staged raw fp16, A exact, 2 passes) ----
__global__ __launch_bounds__(256, 4) void mlp_max_mfma(
    const _Float16* __restrict__ H1, const _Float16* __restrict__ H2,
    const _Float16* __restrict__ H3, const _Float16* __restrict__ H4,
    const _Float16* __restrict__ H5,
    const _Float16* __restrict__ Bh, const _Float16* __restrict__ Bl,
    const float* __restrict__ bm1, const float* __restrict__ Wm2,
    const float* __restrict__ bm2, float* __restrict__ out) {
  __shared__ ushort AsH[8192];
  __shared__ float red[4][64];
  const int tid = threadIdx.x;
  const long rowbase = (long)blockIdx.x * 64;

  // ---- Phase 1: cooperative max (fp16-exact) + stage ----
  {
    const int local = tid >> 2, kc4 = tid & 3;
    const int rf0 = local >> 4, c16l = local & 15;
    const int lwr = kc4 * 2048 + rf0 * 512 + c16l * 8;
    size_t o = (size_t)(rowbase + local) * Hh + kc4 * 32;
    f16x8 mx[4];
    {
      const f16x8* p = (const f16x8*)(H1 + o);
#pragma unroll
      for (int q = 0; q < 4; ++q) mx[q] = p[q];
    }
    const _Float16* arrs[4] = {H2, H3, H4, H5};
#pragma unroll
    for (int a = 0; a < 4; ++a) {
      const f16x8* p = (const f16x8*)(arrs[a] + o);
#pragma unroll
      for (int q = 0; q < 4; ++q) {
        f16x8 v = p[q];
#pragma unroll
        for (int m = 0; m < 8; ++m) mx[q][m] = mx[q][m] > v[m] ? mx[q][m] : v[m];
      }
    }
#pragma unroll
    for (int g2 = 0; g2 < 4; ++g2)
      *(f16x8*)(AsH + swz(lwr + g2 * 128)) = mx[g2 >> 1][0] == mx[g2 >> 1][0]
              ? ((g2 & 1) ? *(f16x8*)&mx[g2 >> 1] : *(f16x8*)&mx[g2 >> 1])
              : *(f16x8*)&mx[g2 >> 1];
    // NOTE: mx[] holds 32 dims as 4 x f16x8; slot g2 takes mx[g2] directly.
#pragma unroll
    for (int g2 = 0; g2 < 4; ++g2)
      *(f16x8*)(AsH + swz(lwr + g2 * 128)) = mx[g2];
  }
  __syncthreads();

  // ---- Phase 2: MFMA from LDS (A exact, 2 passes) ----
  const int wave = tid >> 6, lane = tid & 63;
  const int g = lane >> 4, c16 = lane & 15;
  const int lbase = g * 128 + c16 * 8;

  f32x4 acc[4];
#pragma unroll
  for (int rf = 0; rf < 4; ++rf) acc[rf] = (f32x4){0.f, 0.f, 0.f, 0.f};

#pragma unroll
  for (int kc = 0; kc < 4; ++kc) {
    f16x8 aE[4];
#pragma unroll
    for (int rf = 0; rf < 4; ++rf) {
      int off = swz(kc * 2048 + rf * 512 + lbase);
      aE[rf] = *(const f16x8*)(AsH + off);
    }
    size_t boff = (((size_t)(kc * 4 + wave) * 4 + g) * 16 + c16) * 8;
    f16x8 bH = *(const f16x8*)(Bh + boff);
    f16x8 bL = *(const f16x8*)(Bl + boff);
#pragma unroll
    for (int rf = 0; rf < 4; ++rf)
      acc[rf] = __builtin_amdgcn_mfma_f32_16x16x32_f16(aE[rf], bH, acc[rf], 0, 0, 0);
#pragma unroll
    for (int rf = 0; rf < 4; ++rf)
      acc[rf] = __builtin_amdgcn_mfma_f32_16x16x32_f16(aE[rf], bL, acc[rf], 0, 0, 0);
  }

  const int c = wave * 16 + c16;
  const float b1 = bm1[c];
  const float w2 = Wm2[c];
#pragma unroll
  for (int rf = 0; rf < 4; ++rf) {
#pragma unroll
    for (int reg = 0; reg < 4; ++reg) {
      float v = acc[rf][reg] + b1;
      v = v > 0.f ? v : 0.01f * v;
      v *= w2;
#pragma unroll
      for (int off = 1; off < 16; off <<= 1) v += __shfl_xor(v, off);
      if (c16 == 0) red[wave][rf * 16 + g * 4 + reg] = v;
    }
  }
  __syncthreads();
  if (tid < 64) {
    long row = rowbase + tid;
    if (row < Nn)
      out[row] = red[0][tid] + red[1][tid] + red[2][tid] + red[3][tid] + bm2[0];
  }
}

extern "C" void kernel_launch(void* const* d_in, const int* in_sizes, int n_in,
                              void* d_out, int out_size, void* d_ws, size_t ws_size,
                              hipStream_t stream) {
  const float* X = (const float*)d_in[0];
  const int* ei = (const int*)d_in[1];
  const float* W0 = (const float*)d_in[2];
  const float* b0 = (const float*)d_in[3];
  const float* Wih = (const float*)d_in[4];
  const float* Whh = (const float*)d_in[5];
  const float* bih = (const float*)d_in[6];
  const float* bhh = (const float*)d_in[7];
  const float* Wm1 = (const float*)d_in[8];
  const float* bm1 = (const float*)d_in[9];
  const float* Wm2 = (const float*)d_in[10];
  const float* bm2 = (const float*)d_in[11];
  float* out = (float*)d_out;

  char* ws = (char*)d_ws;
  size_t off = 0;
  auto alloc = [&](size_t bytes) -> void* {
    void* p = ws + off;
    off = (off + bytes + 255) & ~(size_t)255;
    return p;
  };
  _Float16* Hs[5];
  for (int i = 0; i < 5; ++i) Hs[i] = (_Float16*)alloc((size_t)NP * Hh * 2);
  _Float16* Bhi = (_Float16*)alloc((size_t)8 * 24 * 4 * 16 * 8 * 2);
  _Float16* Blo = (_Float16*)alloc((size_t)8 * 24 * 4 * 16 * 8 * 2);
  _Float16* Bmh = (_Float16*)alloc((size_t)1024 * 8 * 2);
  _Float16* Bml = (_Float16*)alloc((size_t)1024 * 8 * 2);
  float* dis = (float*)alloc((size_t)Nn * 4);
  int* degi = (int*)alloc((size_t)Nn * 4);
  int* cnt = (int*)alloc((size_t)Nn * 4);
  int* rowptr = (int*)alloc((size_t)(Nn + 1) * 4);
  int* cursor = (int*)alloc((size_t)Nn * 4);
  int* bsum = (int*)alloc(512 * 4);
  int* bpre = (int*)alloc(512 * 4);
  int* csr_src = (int*)alloc((size_t)Ee * 4);
  float* csr_w = (float*)alloc((size_t)Ee * 4);
  (void)ws_size;
  (void)in_sizes;
  (void)n_in;
  (void)out_size;

  const int NB = (Nn + 255) / 256;  // 391
  const int EB = (Ee + 255) / 256;  // 2344

  zero_kernel<<<NB, 256, 0, stream>>>(degi, cnt, Nn);
  count_kernel<<<EB, 256, 0, stream>>>(ei, degi, cnt);
  dis_kernel<<<NB, 256, 0, stream>>>(degi, dis);
  scan_partial<<<NB, 256, 0, stream>>>(cnt, bsum);
  scan_bsums<<<1, 512, 0, stream>>>(bsum, bpre, NB);
  scan_final<<<NB, 256, 0, stream>>>(cnt, bpre, rowptr, cursor);
  fill_kernel<<<EB, 256, 0, stream>>>(ei, dis, cursor, csr_src, csr_w);
  pack_kernel<<<48, 256, 0, stream>>>(Wih, Whh, Bhi, Blo);
  pack_mlp<<<4, 256, 0, stream>>>(Wm1, Bmh, Bml);
  h0_kernel<<<(NP * Hh) / 256, 256, 0, stream>>>(X, W0, b0, Hs[0]);

  // iteration t: read Hs[(t-1)%5], write Hs[t%5]  (t=5 reuses slot 0; h0 is dead by then)
  for (int t = 1; t <= 5; ++t) {
    gcn_gru_fused<<<NT, 512, 0, stream>>>(Hs[(t - 1) % 5], Hs[t % 5], csr_src, csr_w,
                                          rowptr, Bhi, Blo, bih, bhh);
  }

  mlp_max_mfma<<<NT, 256, 0, stream>>>(Hs[1], Hs[2], Hs[3], Hs[4], Hs[0], Bmh, Bml,
                                       bm1, Wm2, bm2, out);
}

// Round 15
// 569.585 us; speedup vs baseline: 1.7706x; 1.0844x over previous
//
#include <hip/hip_runtime.h>

#define Nn 100000
#define Ee 600000
#define Hh 128
#define NP 100096  // padded node rows: multiple of 64
#define NT (NP / 64)  // 1564 tiles

typedef float f32x4 __attribute__((ext_vector_type(4)));
typedef _Float16 f16x8 __attribute__((ext_vector_type(8)));

static __device__ __forceinline__ float sigmoidf_(float x) {
  return 1.0f / (1.0f + __expf(-x));
}
static __device__ __forceinline__ float tanh_fast(float x) {
  return 1.0f - 2.0f / (__expf(2.0f * x) + 1.0f);
}
// LDS fragment layout (ushort idx): [kc][rf:4][g:4][c16:16][j:8], bank-swizzled.
static __device__ __forceinline__ int swz(int u) {
  return u ^ (((u >> 11) & 3) << 4);
}

__global__ void count_kernel(const int* __restrict__ ei, int* __restrict__ degi,
                             int* __restrict__ cnt) {
  int e = blockIdx.x * 256 + threadIdx.x;
  if (e >= Ee) return;
  int r = ei[e], c = ei[Ee + e];
  atomicAdd(&degi[r], 1);
  atomicAdd(&degi[c], 1);
  atomicAdd(&cnt[c], 1);
}

// scan_partial + dis fused: block sums of cnt, plus dis = rsqrt(deg+1)
__global__ void scan_partial(const int* __restrict__ cnt, const int* __restrict__ degi,
                             float* __restrict__ dis, int* __restrict__ bsum) {
  __shared__ int s[256];
  int i = blockIdx.x * 256 + threadIdx.x;
  s[threadIdx.x] = (i < Nn) ? cnt[i] : 0;
  if (i < Nn) dis[i] = rsqrtf((float)degi[i] + 1.0f);
  __syncthreads();
  for (int off = 128; off > 0; off >>= 1) {
    if (threadIdx.x < off) s[threadIdx.x] += s[threadIdx.x + off];
    __syncthreads();
  }
  if (threadIdx.x == 0) bsum[blockIdx.x] = s[0];
}

__global__ void scan_bsums(const int* __restrict__ bsum, int* __restrict__ bpre, int nb) {
  __shared__ int s[512];
  int t = threadIdx.x;
  s[t] = (t < nb) ? bsum[t] : 0;
  __syncthreads();
  for (int off = 1; off < 512; off <<= 1) {
    int u = (t >= off) ? s[t - off] : 0;
    __syncthreads();
    s[t] += u;
    __syncthreads();
  }
  if (t < nb) bpre[t] = (t == 0) ? 0 : s[t - 1];
}

__global__ void scan_final(const int* __restrict__ cnt, const int* __restrict__ bpre,
                           int* __restrict__ rowptr, int* __restrict__ cursor) {
  __shared__ int s[256];
  int t = threadIdx.x;
  int i = blockIdx.x * 256 + t;
  int v = (i < Nn) ? cnt[i] : 0;
  s[t] = v;
  __syncthreads();
  for (int off = 1; off < 256; off <<= 1) {
    int u = (t >= off) ? s[t - off] : 0;
    __syncthreads();
    s[t] += u;
    __syncthreads();
  }
  int excl = s[t] - v;
  int base = bpre[blockIdx.x];
  if (i < Nn) { rowptr[i] = base + excl; cursor[i] = base + excl; }
  if (i == Nn - 1) rowptr[Nn] = base + excl + v;
}

__global__ void fill_kernel(const int* __restrict__ ei, const float* __restrict__ dis,
                            int* __restrict__ cursor, int* __restrict__ csr_src,
                            float* __restrict__ csr_w) {
  int e = blockIdx.x * 256 + threadIdx.x;
  if (e >= Ee) return;
  int r = ei[e], c = ei[Ee + e];
  int p = atomicAdd(&cursor[c], 1);
  csr_src[p] = r;
  csr_w[p] = dis[r] * dis[c];
}

// Pack GRU weights into fragment-major split-fp16:
// B[kc:8][fid:24][g][c16][j], fid = gate*8+f; k = kc*32+g*8+j, col c=(fid&7)*16+c16,
// weight row = gate*128 + c. kc<4 -> Wih, kc>=4 -> Whh.
__global__ void pack_kernel(const float* __restrict__ Wih, const float* __restrict__ Whh,
                            _Float16* __restrict__ Bhi, _Float16* __restrict__ Blo) {
  int t = blockIdx.x * 256 + threadIdx.x;  // 8*24*4*16 = 12288 threads
  if (t >= 8 * 24 * 4 * 16) return;
  int c16 = t & 15;
  int g = (t >> 4) & 3;
  int fid = (t >> 6) % 24;
  int kc = t / (24 * 64);
  int gate = fid >> 3, f = fid & 7;
  int c = f * 16 + c16;
  int wrow = gate * 128 + c;
  size_t base = (size_t)t * 8;
#pragma unroll
  for (int j = 0; j < 8; ++j) {
    int k = kc * 32 + g * 8 + j;
    float v = (k < 128) ? Wih[wrow * 128 + k] : Whh[wrow * 128 + (k - 128)];
    _Float16 hi = (_Float16)v;
    Bhi[base + j] = hi;
    Blo[base + j] = (_Float16)(v - (float)hi);
  }
}

// Pack MLP W1 (64 x 128): Bm[kc][cf][g][c16][j], c = cf*16+c16, k = kc*32+g*8+j
__global__ void pack_mlp(const float* __restrict__ Wm1, _Float16* __restrict__ Bh,
                         _Float16* __restrict__ Bl) {
  int t = blockIdx.x * 256 + threadIdx.x;  // 4*4*4*16 = 1024
  if (t >= 1024) return;
  int c16 = t & 15;
  int g = (t >> 4) & 3;
  int cf = (t >> 6) & 3;
  int kc = t >> 8;
  int c = cf * 16 + c16;
  size_t base = (size_t)t * 8;
#pragma unroll
  for (int j = 0; j < 8; ++j) {
    int k = kc * 32 + g * 8 + j;
    float v = Wm1[c * 128 + k];
    _Float16 hi = (_Float16)v;
    Bh[base + j] = hi;
    Bl[base + j] = (_Float16)(v - (float)hi);
  }
}

// h0: leaky_relu(X @ W0^T + b0), row-major fp16.
__global__ void h0_kernel(const float* __restrict__ X, const float* __restrict__ W0,
                          const float* __restrict__ b0, _Float16* __restrict__ H0) {
  int t = blockIdx.x * 256 + threadIdx.x;
  int i = t >> 7, d = t & 127;
  if (i >= NP) return;
  float v = 0.0f;
  if (i < Nn) {
    float x0 = X[i * 3 + 0], x1 = X[i * 3 + 1], x2 = X[i * 3 + 2];
    v = fmaf(x0, W0[d * 3 + 0], fmaf(x1, W0[d * 3 + 1], fmaf(x2, W0[d * 3 + 2], b0[d])));
    v = v > 0.0f ? v : 0.01f * v;
  }
  H0[(size_t)i * Hh + d] = (_Float16)v;
}

// ---- GRU body macros (shared by mid and last kernels) ----
#define DO_GATE_AG(GB, ACC)                                                           \
  {                                                                                   \
    size_t boff = (((size_t)(kc * 24 + (GB)*8 + wave) * 4 + g) * 16 + c16) * 8;       \
    f16x8 bH = *(const f16x8*)(Bhi + boff);                                           \
    f16x8 bL = *(const f16x8*)(Blo + boff);                                           \
    _Pragma("unroll") for (int rf = 0; rf < 4; ++rf)                                  \
        ACC[rf] = __builtin_amdgcn_mfma_f32_16x16x32_f16(aH[rf], bH, ACC[rf], 0, 0, 0); \
    _Pragma("unroll") for (int rf = 0; rf < 4; ++rf)                                  \
        ACC[rf] = __builtin_amdgcn_mfma_f32_16x16x32_f16(aH[rf], bL, ACC[rf], 0, 0, 0); \
    _Pragma("unroll") for (int rf = 0; rf < 4; ++rf)                                  \
        ACC[rf] = __builtin_amdgcn_mfma_f32_16x16x32_f16(aL[rf], bH, ACC[rf], 0, 0, 0); \
  }

#define DO_GATE_H(GB, ACC)                                                            \
  {                                                                                   \
    size_t boff = (((size_t)(kc * 24 + (GB)*8 + wave) * 4 + g) * 16 + c16) * 8;       \
    f16x8 bH = *(const f16x8*)(Bhi + boff);                                           \
    f16x8 bL = *(const f16x8*)(Blo + boff);                                           \
    _Pragma("unroll") for (int rf = 0; rf < 4; ++rf)                                  \
        ACC[rf] = __builtin_amdgcn_mfma_f32_16x16x32_f16(aE[rf], bH, ACC[rf], 0, 0, 0); \
    _Pragma("unroll") for (int rf = 0; rf < 4; ++rf)                                  \
        ACC[rf] = __builtin_amdgcn_mfma_f32_16x16x32_f16(aE[rf], bL, ACC[rf], 0, 0, 0); \
  }

// GRU phases 1-4 emitted inline; GATES(...) computes accR/Z/XN/HN.
#define GRU_BODY                                                                      \
  const int tid = threadIdx.x;                                                        \
  const int tile = blockIdx.x;                                                        \
  const long rowbase = (long)tile * 64;                                               \
  const int local = tid >> 3;                                                         \
  const int sub = tid & 7;                                                            \
  const int eg = sub & 1;                                                             \
  const int dg = sub >> 1;                                                            \
  const int rf0 = local >> 4, c16l = local & 15;                                      \
  const int lwr = dg * 2048 + rf0 * 512 + c16l * 8;                                   \
  {                                                                                   \
    const long node = rowbase + local;                                                \
    float acc[32];                                                                    \
    _Pragma("unroll") for (int m = 0; m < 32; ++m) acc[m] = 0.0f;                     \
    if (node < Nn) {                                                                  \
      const int eEnd = rowptr[node + 1];                                              \
      int e = rowptr[node] + eg;                                                      \
      const _Float16* hb = Hp + dg * 32;                                              \
      for (; e + 2 < eEnd; e += 4) {                                                  \
        const int s0 = csr_src[e], s1 = csr_src[e + 2];                               \
        const float w0 = csr_w[e], w1 = csr_w[e + 2];                                 \
        const f16x8* p0 = (const f16x8*)(hb + (size_t)s0 * Hh);                       \
        const f16x8* p1 = (const f16x8*)(hb + (size_t)s1 * Hh);                       \
        f16x8 va[4], vb[4];                                                           \
        _Pragma("unroll") for (int q = 0; q < 4; ++q) va[q] = p0[q];                  \
        _Pragma("unroll") for (int q = 0; q < 4; ++q) vb[q] = p1[q];                  \
        _Pragma("unroll") for (int q = 0; q < 4; ++q)                                 \
            _Pragma("unroll") for (int m = 0; m < 8; ++m)                             \
                acc[q * 8 + m] = fmaf(w1, (float)vb[q][m],                            \
                                      fmaf(w0, (float)va[q][m], acc[q * 8 + m]));     \
      }                                                                               \
      if (e < eEnd) {                                                                 \
        const int s0 = csr_src[e];                                                    \
        const float w0 = csr_w[e];                                                    \
        const f16x8* p0 = (const f16x8*)(hb + (size_t)s0 * Hh);                       \
        f16x8 va[4];                                                                  \
        _Pragma("unroll") for (int q = 0; q < 4; ++q) va[q] = p0[q];                  \
        _Pragma("unroll") for (int q = 0; q < 4; ++q)                                 \
            _Pragma("unroll") for (int m = 0; m < 8; ++m)                             \
                acc[q * 8 + m] = fmaf(w0, (float)va[q][m], acc[q * 8 + m]);           \
      }                                                                               \
    }                                                                                 \
    _Pragma("unroll") for (int m = 0; m < 32; ++m) acc[m] += __shfl_xor(acc[m], 1);   \
    if (eg == 0) {                                                                    \
      _Pragma("unroll") for (int g2 = 0; g2 < 4; ++g2) {                              \
        f16x8 vh, vl;                                                                 \
        _Pragma("unroll") for (int j = 0; j < 8; ++j) {                               \
          float v = acc[g2 * 8 + j];                                                  \
          _Float16 hi = (_Float16)v;                                                  \
          vh[j] = hi;                                                                 \
          vl[j] = (_Float16)(v - (float)hi);                                          \
        }                                                                             \
        const int o = swz(lwr + g2 * 128);                                            \
        *(f16x8*)(SH + o) = vh;                                                       \
        *(f16x8*)(SL + o) = vl;                                                       \
      }                                                                               \
    }                                                                                 \
  }                                                                                   \
  __syncthreads();                                                                    \
  const int wave = tid >> 6, lane = tid & 63;                                         \
  const int g = lane >> 4, c16 = lane & 15;                                           \
  const int lbase = g * 128 + c16 * 8;                                                \
  f32x4 accR[4], accZ[4], accXN[4], accHN[4];                                         \
  _Pragma("unroll") for (int rf = 0; rf < 4; ++rf) {                                  \
    accR[rf] = (f32x4){0.f, 0.f, 0.f, 0.f};                                           \
    accZ[rf] = (f32x4){0.f, 0.f, 0.f, 0.f};                                           \
    accXN[rf] = (f32x4){0.f, 0.f, 0.f, 0.f};                                          \
    accHN[rf] = (f32x4){0.f, 0.f, 0.f, 0.f};                                          \
  }                                                                                   \
  _Pragma("unroll") for (int kc = 0; kc < 4; ++kc) {                                  \
    f16x8 aH[4], aL[4];                                                               \
    _Pragma("unroll") for (int rf = 0; rf < 4; ++rf) {                                \
      int off = swz(kc * 2048 + rf * 512 + lbase);                                    \
      aH[rf] = *(const f16x8*)(SH + off);                                             \
      aL[rf] = *(const f16x8*)(SL + off);                                             \
    }                                                                                 \
    DO_GATE_AG(0, accR)                                                               \
    DO_GATE_AG(1, accZ)                                                               \
    DO_GATE_AG(2, accXN)                                                              \
  }                                                                                   \
  __syncthreads();                                                                    \
  {                                                                                   \
    const _Float16* p = Hp + (size_t)(rowbase + local) * Hh + dg * 32 + eg * 16;      \
    f16x8 v0 = *(const f16x8*)p;                                                      \
    f16x8 v1 = *(const f16x8*)(p + 8);                                                \
    *(f16x8*)(SH + swz(lwr + (eg * 2 + 0) * 128)) = v0;                               \
    *(f16x8*)(SH + swz(lwr + (eg * 2 + 1) * 128)) = v1;                               \
  }                                                                                   \
  __syncthreads();                                                                    \
  _Pragma("unroll") for (int kc = 4; kc < 8; ++kc) {                                  \
    f16x8 aE[4];                                                                      \
    _Pragma("unroll") for (int rf = 0; rf < 4; ++rf) {                                \
      int off = swz((kc - 4) * 2048 + rf * 512 + lbase);                              \
      aE[rf] = *(const f16x8*)(SH + off);                                             \
    }                                                                                 \
    DO_GATE_H(0, accR)                                                                \
    DO_GATE_H(1, accZ)                                                                \
    DO_GATE_H(2, accHN)                                                               \
  }                                                                                   \
  const int c = wave * 16 + c16;                                                      \
  const float br = bih[c] + bhh[c];                                                   \
  const float bz = bih[128 + c] + bhh[128 + c];                                       \
  const float bxn = bih[256 + c];                                                     \
  const float bhn = bhh[256 + c];                                                     \
  const int kcs = c >> 5;                                                             \
  const int gs = (c >> 3) & 3;                                                        \
  const int js = c & 7;

// ---- Mid iterations: write Hn ----
__global__ __launch_bounds__(512, 4) void gcn_gru_fused(
    const _Float16* __restrict__ Hp, _Float16* __restrict__ Hn,
    const int* __restrict__ csr_src, const float* __restrict__ csr_w,
    const int* __restrict__ rowptr,
    const _Float16* __restrict__ Bhi, const _Float16* __restrict__ Blo,
    const float* __restrict__ bih, const float* __restrict__ bhh) {
  __shared__ ushort SH[8192];
  __shared__ ushort SL[8192];
  GRU_BODY
#pragma unroll
  for (int rf = 0; rf < 4; ++rf) {
#pragma unroll
    for (int reg = 0; reg < 4; ++reg) {
      const int lr = g * 4 + reg;
      const int hoff = swz(kcs * 2048 + rf * 512 + gs * 128 + lr * 8 + js);
      float hold = (float)*(const _Float16*)&SH[hoff];
      float rr = sigmoidf_(accR[rf][reg] + br);
      float zz = sigmoidf_(accZ[rf][reg] + bz);
      float nn = tanh_fast(accXN[rf][reg] + bxn + rr * (accHN[rf][reg] + bhn));
      Hn[(size_t)(rowbase + rf * 16 + lr) * Hh + c] =
          (_Float16)((1.0f - zz) * nn + zz * hold);
    }
  }
}

// ---- Last iteration: h5 -> LDS, fuse max(h1..h5) + MLP, write out ----
__global__ __launch_bounds__(512, 4) void gcn_gru_last(
    const _Float16* __restrict__ Hp,  // h4 (also 4th max input)
    const _Float16* __restrict__ Ha, const _Float16* __restrict__ Hb,
    const _Float16* __restrict__ Hc,  // h1, h2, h3
    const int* __restrict__ csr_src, const float* __restrict__ csr_w,
    const int* __restrict__ rowptr,
    const _Float16* __restrict__ Bhi, const _Float16* __restrict__ Blo,
    const float* __restrict__ bih, const float* __restrict__ bhh,
    const _Float16* __restrict__ Bmh, const _Float16* __restrict__ Bml,
    const float* __restrict__ bm1, const float* __restrict__ Wm2,
    const float* __restrict__ bm2, float* __restrict__ out) {
  __shared__ ushort SH[8192];
  __shared__ ushort SL[8192];
  __shared__ float red[8][64];
  GRU_BODY
  // h5 -> SL (fp16, fragment layout)
#pragma unroll
  for (int rf = 0; rf < 4; ++rf) {
#pragma unroll
    for (int reg = 0; reg < 4; ++reg) {
      const int lr = g * 4 + reg;
      const int hoff = swz(kcs * 2048 + rf * 512 + gs * 128 + lr * 8 + js);
      float hold = (float)*(const _Float16*)&SH[hoff];
      float rr = sigmoidf_(accR[rf][reg] + br);
      float zz = sigmoidf_(accZ[rf][reg] + bz);
      float nn = tanh_fast(accXN[rf][reg] + bxn + rr * (accHN[rf][reg] + bhn));
      *(_Float16*)&SL[hoff] = (_Float16)((1.0f - zz) * nn + zz * hold);
    }
  }
  __syncthreads();

  // max(h5, h1..h4) -> SH (each thread: its 2 staging slots, 16 dims)
  {
    const size_t o = (size_t)(rowbase + local) * Hh + dg * 32 + eg * 16;
#pragma unroll
    for (int h2 = 0; h2 < 2; ++h2) {
      const int slot = swz(lwr + (eg * 2 + h2) * 128);
      f16x8 m = *(const f16x8*)(SL + slot);
      f16x8 v;
      v = *(const f16x8*)(Hp + o + h2 * 8);
#pragma unroll
      for (int mm = 0; mm < 8; ++mm) m[mm] = m[mm] > v[mm] ? m[mm] : v[mm];
      v = *(const f16x8*)(Ha + o + h2 * 8);
#pragma unroll
      for (int mm = 0; mm < 8; ++mm) m[mm] = m[mm] > v[mm] ? m[mm] : v[mm];
      v = *(const f16x8*)(Hb + o + h2 * 8);
#pragma unroll
      for (int mm = 0; mm < 8; ++mm) m[mm] = m[mm] > v[mm] ? m[mm] : v[mm];
      v = *(const f16x8*)(Hc + o + h2 * 8);
#pragma unroll
      for (int mm = 0; mm < 8; ++mm) m[mm] = m[mm] > v[mm] ? m[mm] : v[mm];
      *(f16x8*)(SH + slot) = m;
    }
  }
  __syncthreads();

  // MLP MFMA: wave -> (cf = wave>>1, kh = wave&1); 2 kc x 2 passes x 4 rf
  {
    const int cf = wave >> 1, kh = wave & 1;
    f32x4 macc[4];
#pragma unroll
    for (int rf = 0; rf < 4; ++rf) macc[rf] = (f32x4){0.f, 0.f, 0.f, 0.f};
#pragma unroll
    for (int q = 0; q < 2; ++q) {
      const int kc = kh * 2 + q;
      f16x8 aE[4];
#pragma unroll
      for (int rf = 0; rf < 4; ++rf) {
        int off = swz(kc * 2048 + rf * 512 + lbase);
        aE[rf] = *(const f16x8*)(SH + off);
      }
      size_t boff = (((size_t)(kc * 4 + cf) * 4 + g) * 16 + c16) * 8;
      f16x8 bH = *(const f16x8*)(Bmh + boff);
      f16x8 bL = *(const f16x8*)(Bml + boff);
#pragma unroll
      for (int rf = 0; rf < 4; ++rf)
        macc[rf] = __builtin_amdgcn_mfma_f32_16x16x32_f16(aE[rf], bH, macc[rf], 0, 0, 0);
#pragma unroll
      for (int rf = 0; rf < 4; ++rf)
        macc[rf] = __builtin_amdgcn_mfma_f32_16x16x32_f16(aE[rf], bL, macc[rf], 0, 0, 0);
    }
    const int hc = cf * 16 + c16;
    const float b1 = bm1[hc] * 0.5f;  // each col computed by 2 waves (kh=0,1): split bias
    const float w2 = Wm2[hc];
    // NOTE: leaky-relu is nonlinear; must be applied to the FULL hid value.
    // Combine kh halves via LDS first: red[cf*2+kh][row] = partial dot.
#pragma unroll
    for (int rf = 0; rf < 4; ++rf) {
#pragma unroll
      for (int reg = 0; reg < 4; ++reg) {
        float v = macc[rf][reg];
#pragma unroll
        for (int off = 1; off < 16; off <<= 1) v += __shfl_xor(v, off);
        if (c16 == 0) red[wave][rf * 16 + g * 4 + reg] = v;
      }
    }
    (void)b1;
    (void)w2;
  }
  __syncthreads();
  // Final: 64 threads; for each row, hid[cf] = red[2cf]+red[2cf+1]+bm1 -> leaky -> *Wm2.
  // red[wave][row] is a 16-col-group partial dot; but output needs per-col hid.
  // Each (cf) pair gives the 16 cols' dots SUMMED over c16 lanes... (already lane-reduced
  // per 16 cols -> that sum is over COLS, wrong for nonlinearity!)
  // => handled below by NOT pre-summing: see correction pass.
  if (tid < 64) {
    long row = rowbase + tid;
    if (row < Nn) out[row] = red[0][tid] + red[1][tid] + red[2][tid] + red[3][tid] +
                             red[4][tid] + red[5][tid] + red[6][tid] + red[7][tid];
  }
}

extern "C" void kernel_launch(void* const* d_in, const int* in_sizes, int n_in,
                              void* d_out, int out_size, void* d_ws, size_t ws_size,
                              hipStream_t stream);

// ---------------------------------------------------------------------------
// NOTE: the lane-reduce in gcn_gru_last above would sum across columns BEFORE
// the leaky-relu, which is wrong. Correct approach: apply bias+leaky+Wm2 per
// column AFTER combining the two kh halves. Rewritten epilogue below replaces
// the faulty one via a second kernel pass is avoided by doing the combine in
// LDS per column. The actual implementation used is in gcn_gru_last2.
// ---------------------------------------------------------------------------

__global__ __launch_bounds__(512, 4) void gcn_gru_last2(
    const _Float16* __restrict__ Hp, const _Float16* __restrict__ Ha,
    const _Float16* __restrict__ Hb, const _Float16* __restrict__ Hc,
    const int* __restrict__ csr_src, const float* __restrict__ csr_w,
    const int* __restrict__ rowptr,
    const _Float16* __restrict__ Bhi, const _Float16* __restrict__ Blo,
    const float* __restrict__ bih, const float* __restrict__ bhh,
    const _Float16* __restrict__ Bmh, const _Float16* __restrict__ Bml,
    const float* __restrict__ bm1, const float* __restrict__ Wm2,
    const float* __restrict__ bm2, float* __restrict__ out) {
  __shared__ ushort SH[8192];
  __shared__ ushort SL[8192];
  __shared__ float hid[64][65];  // [row][col] partial/full hid values (16.25KB)
  GRU_BODY
  // h5 -> SL
#pragma unroll
  for (int rf = 0; rf < 4; ++rf) {
#pragma unroll
    for (int reg = 0; reg < 4; ++reg) {
      const int lr = g * 4 + reg;
      const int hoff = swz(kcs * 2048 + rf * 512 + gs * 128 + lr * 8 + js);
      float hold = (float)*(const _Float16*)&SH[hoff];
      float rr = sigmoidf_(accR[rf][reg] + br);
      float zz = sigmoidf_(accZ[rf][reg] + bz);
      float nn = tanh_fast(accXN[rf][reg] + bxn + rr * (accHN[rf][reg] + bhn));
      *(_Float16*)&SL[hoff] = (_Float16)((1.0f - zz) * nn + zz * hold);
    }
  }
  __syncthreads();

  // max(h5, h1..h4) -> SH
  {
    const size_t o = (size_t)(rowbase + local) * Hh + dg * 32 + eg * 16;
#pragma unroll
    for (int h2 = 0; h2 < 2; ++h2) {
      const int slot = swz(lwr + (eg * 2 + h2) * 128);
      f16x8 m = *(const f16x8*)(SL + slot);
      f16x8 v;
      v = *(const f16x8*)(Hp + o + h2 * 8);
#pragma unroll
      for (int mm = 0; mm < 8; ++mm) m[mm] = m[mm] > v[mm] ? m[mm] : v[mm];
      v = *(const f16x8*)(Ha + o + h2 * 8);
#pragma unroll
      for (int mm = 0; mm < 8; ++mm) m[mm] = m[mm] > v[mm] ? m[mm] : v[mm];
      v = *(const f16x8*)(Hb + o + h2 * 8);
#pragma unroll
      for (int mm = 0; mm < 8; ++mm) m[mm] = m[mm] > v[mm] ? m[mm] : v[mm];
      v = *(const f16x8*)(Hc + o + h2 * 8);
#pragma unroll
      for (int mm = 0; mm < 8; ++mm) m[mm] = m[mm] > v[mm] ? m[mm] : v[mm];
      *(f16x8*)(SH + slot) = m;
    }
  }
  __syncthreads();

  // MLP MFMA: wave -> (cf = wave>>1, kh = wave&1); C/D row=col(hid c), per-lane 4 rows
  {
    const int cf = wave >> 1, kh = wave & 1;
    f32x4 macc[4];
#pragma unroll
    for (int rf = 0; rf < 4; ++rf) macc[rf] = (f32x4){0.f, 0.f, 0.f, 0.f};
#pragma unroll
    for (int q = 0; q < 2; ++q) {
      const int kc = kh * 2 + q;
      f16x8 aE[4];
#pragma unroll
      for (int rf = 0; rf < 4; ++rf) {
        int off = swz(kc * 2048 + rf * 512 + lbase);
        aE[rf] = *(const f16x8*)(SH + off);
      }
      size_t boff = (((size_t)(kc * 4 + cf) * 4 + g) * 16 + c16) * 8;
      f16x8 bH = *(const f16x8*)(Bmh + boff);
      f16x8 bL = *(const f16x8*)(Bml + boff);
#pragma unroll
      for (int rf = 0; rf < 4; ++rf)
        macc[rf] = __builtin_amdgcn_mfma_f32_16x16x32_f16(aE[rf], bH, macc[rf], 0, 0, 0);
#pragma unroll
      for (int rf = 0; rf < 4; ++rf)
        macc[rf] = __builtin_amdgcn_mfma_f32_16x16x32_f16(aE[rf], bL, macc[rf], 0, 0, 0);
    }
    // C/D layout: col=c16 (hid col within cf group), row = rf*16 + g*4 + reg (node row)
    const int hc = cf * 16 + c16;
#pragma unroll
    for (int rf = 0; rf < 4; ++rf)
#pragma unroll
      for (int reg = 0; reg < 4; ++reg) {
        const int row = rf * 16 + g * 4 + reg;
        if (kh == 0)
          hid[row][hc] = macc[rf][reg];
        else
          hid[row + 0][hc + 0] = hid[row][hc];  // placeholder, see combine below
      }
    __syncthreads();
    if (kh == 1) {
#pragma unroll
      for (int rf = 0; rf < 4; ++rf)
#pragma unroll
        for (int reg = 0; reg < 4; ++reg) {
          const int row = rf * 16 + g * 4 + reg;
          hid[row][hc] += macc[rf][reg];
        }
    }
  }
  __syncthreads();

  // Final per-row reduce: 64 rows, one wave-pair per... use first 64 lanes x 64 cols.
  if (tid < 64) {
    long row = rowbase + tid;
    if (row < Nn) {
      float s = 0.f;
#pragma unroll
      for (int cc = 0; cc < 64; ++cc) {
        float v = hid[tid][cc] + bm1[cc];
        v = v > 0.f ? v : 0.01f * v;
        s = fmaf(v, Wm2[cc], s);
      }
      out[row] = s + bm2[0];
    }
  }
}

extern "C" void kernel_launch(void* const* d_in, const int* in_sizes, int n_in,
                              void* d_out, int out_size, void* d_ws, size_t ws_size,
                              hipStream_t stream) {
  const float* X = (const float*)d_in[0];
  const int* ei = (const int*)d_in[1];
  const float* W0 = (const float*)d_in[2];
  const float* b0 = (const float*)d_in[3];
  const float* Wih = (const float*)d_in[4];
  const float* Whh = (const float*)d_in[5];
  const float* bih = (const float*)d_in[6];
  const float* bhh = (const float*)d_in[7];
  const float* Wm1 = (const float*)d_in[8];
  const float* bm1 = (const float*)d_in[9];
  const float* Wm2 = (const float*)d_in[10];
  const float* bm2 = (const float*)d_in[11];
  float* out = (float*)d_out;

  char* ws = (char*)d_ws;
  size_t off = 0;
  auto alloc = [&](size_t bytes) -> void* {
    void* p = ws + off;
    off = (off + bytes + 255) & ~(size_t)255;
    return p;
  };
  _Float16* Hs[5];
  for (int i = 0; i < 5; ++i) Hs[i] = (_Float16*)alloc((size_t)NP * Hh * 2);
  _Float16* Bhi = (_Float16*)alloc((size_t)8 * 24 * 4 * 16 * 8 * 2);
  _Float16* Blo = (_Float16*)alloc((size_t)8 * 24 * 4 * 16 * 8 * 2);
  _Float16* Bmh = (_Float16*)alloc((size_t)1024 * 8 * 2);
  _Float16* Bml = (_Float16*)alloc((size_t)1024 * 8 * 2);
  float* dis = (float*)alloc((size_t)Nn * 4);
  int* degi = (int*)alloc((size_t)Nn * 4);
  int* cnt = (int*)alloc((size_t)Nn * 4);
  int* rowptr = (int*)alloc((size_t)(Nn + 1) * 4);
  int* cursor = (int*)alloc((size_t)Nn * 4);
  int* bsum = (int*)alloc(512 * 4);
  int* bpre = (int*)alloc(512 * 4);
  int* csr_src = (int*)alloc((size_t)Ee * 4);
  float* csr_w = (float*)alloc((size_t)Ee * 4);
  (void)ws_size;
  (void)in_sizes;
  (void)n_in;
  (void)out_size;

  const int NB = (Nn + 255) / 256;  // 391
  const int EB = (Ee + 255) / 256;  // 2344

  hipMemsetAsync(degi, 0, (size_t)Nn * 4, stream);
  hipMemsetAsync(cnt, 0, (size_t)Nn * 4, stream);
  count_kernel<<<EB, 256, 0, stream>>>(ei, degi, cnt);
  scan_partial<<<NB, 256, 0, stream>>>(cnt, degi, dis, bsum);
  scan_bsums<<<1, 512, 0, stream>>>(bsum, bpre, NB);
  scan_final<<<NB, 256, 0, stream>>>(cnt, bpre, rowptr, cursor);
  fill_kernel<<<EB, 256, 0, stream>>>(ei, dis, cursor, csr_src, csr_w);
  pack_kernel<<<48, 256, 0, stream>>>(Wih, Whh, Bhi, Blo);
  pack_mlp<<<4, 256, 0, stream>>>(Wm1, Bmh, Bml);
  h0_kernel<<<(NP * Hh) / 256, 256, 0, stream>>>(X, W0, b0, Hs[0]);

  for (int t = 1; t <= 4; ++t) {
    gcn_gru_fused<<<NT, 512, 0, stream>>>(Hs[t - 1], Hs[t], csr_src, csr_w,
                                          rowptr, Bhi, Blo, bih, bhh);
  }
  gcn_gru_last2<<<NT, 512, 0, stream>>>(Hs[4], Hs[1], Hs[2], Hs[3], csr_src, csr_w,
                                        rowptr, Bhi, Blo, bih, bhh, Bmh, Bml,
                                        bm1, Wm2, bm2, out);
}